// Round 1
// baseline (676.702 us; speedup 1.0000x reference)
//
#include <hip/hip_runtime.h>
#include <math.h>

#define TT 2048
#define NH 16
#define HD 64
#define NB 32
#define HIDDEN 1024

// ---------------- wave reductions ----------------
__device__ __forceinline__ float rmax64(float v){
#pragma unroll
  for(int o=32;o>0;o>>=1) v = fmaxf(v, __shfl_xor(v,o,64));
  return v;
}
__device__ __forceinline__ float rsum64(float v){
#pragma unroll
  for(int o=32;o>0;o>>=1) v += __shfl_xor(v,o,64);
  return v;
}
__device__ __forceinline__ float rmax32(float v){
#pragma unroll
  for(int o=16;o>0;o>>=1) v = fmaxf(v, __shfl_xor(v,o,32));
  return v;
}
__device__ __forceinline__ float rsum32(float v){
#pragma unroll
  for(int o=16;o>0;o>>=1) v += __shfl_xor(v,o,32);
  return v;
}

// ---------------- QKV projection GEMM: hs(2048x1024) @ W(1024x1024), scatter to [h][t][d] ----------------
__global__ __launch_bounds__(256) void sgemm_qkv(
    const float* __restrict__ A,
    const float* __restrict__ B0, const float* __restrict__ B1, const float* __restrict__ B2,
    float* __restrict__ C0, float* __restrict__ C1, float* __restrict__ C2)
{
  __shared__ float As[8][128];   // As[k][m]
  __shared__ float Bs[8][128];   // Bs[k][n]
  int z = blockIdx.z;
  const float* B = (z==0)?B0:((z==1)?B1:B2);
  float* C = (z==0)?C0:((z==1)?C1:C2);
  int tid = threadIdx.x;
  int tx = tid & 15, ty = tid >> 4;
  int bm = blockIdx.y*128, bn = blockIdx.x*128;
  int ar = tid>>1, ac = (tid&1)*4;    // A tile 128x8
  int br = tid>>5, bc = (tid&31)*4;   // B tile 8x128
  const float* Ap = A + (size_t)(bm+ar)*HIDDEN + ac;
  const float* Bp = B + (size_t)br*HIDDEN + bn + bc;
  float acc[8][8];
#pragma unroll
  for(int i=0;i<8;i++)
#pragma unroll
    for(int j=0;j<8;j++) acc[i][j]=0.f;
  for(int k0=0;k0<HIDDEN;k0+=8){
    float4 a4 = *(const float4*)(Ap + k0);
    float4 b4 = *(const float4*)(Bp + (size_t)k0*HIDDEN);
    __syncthreads();
    As[ac+0][ar]=a4.x; As[ac+1][ar]=a4.y; As[ac+2][ar]=a4.z; As[ac+3][ar]=a4.w;
    *(float4*)&Bs[br][bc] = b4;
    __syncthreads();
#pragma unroll
    for(int kk=0;kk<8;kk++){
      float4 am0 = *(float4*)&As[kk][ty*8];
      float4 am1 = *(float4*)&As[kk][ty*8+4];
      float4 bq0 = *(float4*)&Bs[kk][tx*8];
      float4 bq1 = *(float4*)&Bs[kk][tx*8+4];
      float am[8] = {am0.x,am0.y,am0.z,am0.w,am1.x,am1.y,am1.z,am1.w};
      float bb[8] = {bq0.x,bq0.y,bq0.z,bq0.w,bq1.x,bq1.y,bq1.z,bq1.w};
#pragma unroll
      for(int i=0;i<8;i++)
#pragma unroll
        for(int j=0;j<8;j++) acc[i][j] += am[i]*bb[j];
    }
  }
  // scatter: column n -> head n>>6, d = n&63 ; layout [h][t][d]
  int n0 = bn + tx*8;
  int head = n0 >> 6;
  int dcol = n0 & 63;
#pragma unroll
  for(int i=0;i<8;i++){
    int m = bm + ty*8 + i;
    float* dst = C + ((size_t)head*TT + m)*HD + dcol;
    *(float4*)(dst)   = make_float4(acc[i][0],acc[i][1],acc[i][2],acc[i][3]);
    *(float4*)(dst+4) = make_float4(acc[i][4],acc[i][5],acc[i][6],acc[i][7]);
  }
}

// ---------------- output projection GEMM: merged(2048x1024) @ Wo(1024x1024) -> out ----------------
__global__ __launch_bounds__(256) void sgemm_proj(
    const float* __restrict__ A, const float* __restrict__ B, float* __restrict__ C)
{
  __shared__ float As[8][64];
  __shared__ float Bs[8][128];
  int tid = threadIdx.x;
  int tx = tid & 15, ty = tid >> 4;
  int bm = blockIdx.y*64, bn = blockIdx.x*128;
  int ar = tid>>2, ac = (tid&3)*2;    // A tile 64x8
  int br = tid>>5, bc = (tid&31)*4;   // B tile 8x128
  const float* Ap = A + (size_t)(bm+ar)*HIDDEN + ac;
  const float* Bp = B + (size_t)br*HIDDEN + bn + bc;
  float acc[4][8];
#pragma unroll
  for(int i=0;i<4;i++)
#pragma unroll
    for(int j=0;j<8;j++) acc[i][j]=0.f;
  for(int k0=0;k0<HIDDEN;k0+=8){
    float2 a2 = *(const float2*)(Ap + k0);
    float4 b4 = *(const float4*)(Bp + (size_t)k0*HIDDEN);
    __syncthreads();
    As[ac+0][ar]=a2.x; As[ac+1][ar]=a2.y;
    *(float4*)&Bs[br][bc] = b4;
    __syncthreads();
#pragma unroll
    for(int kk=0;kk<8;kk++){
      float4 am0 = *(float4*)&As[kk][ty*4];
      float4 bq0 = *(float4*)&Bs[kk][tx*8];
      float4 bq1 = *(float4*)&Bs[kk][tx*8+4];
      float am[4] = {am0.x,am0.y,am0.z,am0.w};
      float bb[8] = {bq0.x,bq0.y,bq0.z,bq0.w,bq1.x,bq1.y,bq1.z,bq1.w};
#pragma unroll
      for(int i=0;i<4;i++)
#pragma unroll
        for(int j=0;j<8;j++) acc[i][j] += am[i]*bb[j];
    }
  }
#pragma unroll
  for(int i=0;i<4;i++){
    int m = bm + ty*4 + i;
    float* dst = C + (size_t)m*HIDDEN + bn + tx*8;
    *(float4*)(dst)   = make_float4(acc[i][0],acc[i][1],acc[i][2],acc[i][3]);
    *(float4*)(dst+4) = make_float4(acc[i][4],acc[i][5],acc[i][6],acc[i][7]);
  }
}

// ---------------- gate: sigmoid(hs @ Wg + bg), (2048 x 48) ----------------
__global__ __launch_bounds__(256) void gate_kernel(
    const float* __restrict__ hs, const float* __restrict__ Wg, const float* __restrict__ bg,
    float* __restrict__ gatep)
{
  int t = blockIdx.x;
  __shared__ float row[1024];
  __shared__ float red[4][64];
  int tid = threadIdx.x;
  *(float4*)(row + tid*4) = *(const float4*)(hs + (size_t)t*HIDDEN + tid*4);
  __syncthreads();
  int n = tid & 63, part = tid>>6;
  float s = 0.f;
  if(n < 48){
    const float* w = Wg + n;
    for(int kx = part*256; kx < part*256+256; kx++)
      s += row[kx]*w[(size_t)kx*48];
  }
  red[part][n] = s;
  __syncthreads();
  if(part==0 && n<48){
    float x = red[0][n]+red[1][n]+red[2][n]+red[3][n] + bg[n];
    gatep[(size_t)t*48 + n] = 1.f/(1.f+expf(-x));
  }
}

// ---------------- compress MLP: gelu(k_blk @ Wc + bc) for k and v (shared weights) ----------------
__global__ __launch_bounds__(256) void compress_kernel(
    const float* __restrict__ kbuf, const float* __restrict__ vbuf,
    const float* __restrict__ Wc, const float* __restrict__ bcp,
    float* __restrict__ kc, float* __restrict__ vc)
{
  int hb = blockIdx.x; int h = hb>>5, i = hb&31;
  __shared__ float inK[4096], inV[4096];
  int tid = threadIdx.x;
  const float4* sk = (const float4*)(kbuf + ((size_t)h*TT + i*64)*HD);
  const float4* sv = (const float4*)(vbuf + ((size_t)h*TT + i*64)*HD);
  float4* dK=(float4*)inK; float4* dV=(float4*)inV;
#pragma unroll
  for(int u=0;u<4;u++){ dK[tid+256*u]=sk[tid+256*u]; dV[tid+256*u]=sv[tid+256*u]; }
  __syncthreads();
  int d = tid&63, part = tid>>6;
  float sK=0.f, sV=0.f;
  const float* w = Wc + d;
  for(int idx = part*1024; idx < part*1024+1024; idx++){
    float wv = w[(size_t)idx*HD];
    sK += inK[idx]*wv; sV += inV[idx]*wv;
  }
  __shared__ float redK[4][64], redV[4][64];
  redK[part][d]=sK; redV[part][d]=sV;
  __syncthreads();
  if(part==0){
    float xK = redK[0][d]+redK[1][d]+redK[2][d]+redK[3][d] + bcp[d];
    float xV = redV[0][d]+redV[1][d]+redV[2][d]+redV[3][d] + bcp[d];
    kc[((size_t)h*NB+i)*HD + d] = 0.5f*xK*(1.f+erff(xK*0.70710678118654752f));
    vc[((size_t)h*NB+i)*HD + d] = 0.5f*xV*(1.f+erff(xV*0.70710678118654752f));
  }
}

// ---------------- compressed attention: importance + softmax + comp_out ----------------
__global__ __launch_bounds__(256) void comp_attn(
    const float* __restrict__ q, const float* __restrict__ kc, const float* __restrict__ vc,
    float* __restrict__ imp, float* __restrict__ comp)
{
  __shared__ float qls[4][64];
  __shared__ float pls[4][64];
  int tid=threadIdx.x;
  int wave = tid>>6, lane = tid&63;
  int idx = blockIdx.x*4 + wave;    // (h,t)
  int h = idx>>11, t = idx & 2047;
  qls[wave][lane] = q[((size_t)h*TT + t)*HD + lane];
  __syncthreads();
  if(lane<32){
    const float* kr = kc + ((size_t)h*NB + lane)*HD;
    float s=0.f;
#pragma unroll
    for(int d=0; d<64; d++) s += qls[wave][d]*kr[d];
    s *= 0.125f;
    imp[((size_t)h*TT + t)*NB + lane] = s;
    float m = rmax32(s);
    float e = __expf(s-m);
    float l = rsum32(e);
    pls[wave][lane] = e/l;
  }
  __syncthreads();
  const float* vbh = vc + (size_t)h*NB*HD;
  float o=0.f;
#pragma unroll
  for(int j=0;j<32;j++) o += pls[wave][j]*vbh[j*HD + lane];
  comp[((size_t)h*TT + t)*HD + lane] = o;
}

// ---------------- block scores -> entropy -> dynamic_k -> top-k mask ----------------
__global__ __launch_bounds__(256) void block_stats(
    const float* __restrict__ imp, const float* __restrict__ ksc, const float* __restrict__ kbi,
    unsigned* __restrict__ maskb, float* __restrict__ dkf,
    float* __restrict__ out_kratio, float* __restrict__ out_nent)
{
  int hb = blockIdx.x; int h = hb>>5, i = hb&31;
  int tid = threadIdx.x; int j = tid&31, p = tid>>5;
  const float* base = imp + ((size_t)h*TT + i*64)*NB;
  float s = 0.f;
  for(int t2=p*8; t2<p*8+8; t2++) s += base[(size_t)t2*NB + j];
  __shared__ float red[8][32];
  red[p][j] = s;
  __syncthreads();
  if(tid < 32){
    float bs = 0.f;
#pragma unroll
    for(int pp=0; pp<8; pp++) bs += red[pp][j];
    bs *= (1.f/64.f);
    // softmax + entropy (precise math: discrete decisions downstream)
    float m = rmax32(bs);
    float e = expf(bs - m);
    float se = rsum32(e);
    float prob = e/se;
    float ent = rsum32(-prob * logf(prob + 1e-9f));
    float nent = ent / (3.4657359027997265f + 1e-9f);  // log(32)
    float kl = ksc[h]*nent + kbi[h];
    float kr = 1.f/(1.f + expf(-kl));
    float dkfl = fminf(fmaxf(8.f*kr, 1.f), 8.f);
    int dk = (int)dkfl;                                 // trunc like astype(int32)
    // iterative top-dk selection, ties -> lowest index (matches lax.top_k)
    unsigned sel = 0u;
    for(int r=0;r<dk;r++){
      bool unpicked = ((sel>>j)&1u)==0u;
      float cand = unpicked ? bs : -3.4e38f;
      float mx = rmax32(cand);
      unsigned long long b = __ballot(cand == mx);
      int idxsel = __ffsll(b & 0xffffffffull) - 1;
      sel |= (1u<<idxsel);
    }
    sel |= (1u<<i);   // | eye
    if(j==0){
      maskb[hb] = sel;
      dkf[hb] = (float)dk;
      out_kratio[hb] = kr;
      out_nent[hb] = nent;
    }
  }
}

// ---------------- avg_k reduction ----------------
__global__ __launch_bounds__(256) void avgk_kernel(const float* __restrict__ dkf, float* __restrict__ outp){
  __shared__ float red[256];
  int tid=threadIdx.x;
  red[tid] = dkf[tid] + dkf[tid+256];
  __syncthreads();
  for(int s=128;s>0;s>>=1){ if(tid<s) red[tid]+=red[tid+s]; __syncthreads(); }
  if(tid==0) outp[0] = red[0] * (1.f/512.f);
}

// ---------------- block-sparse flash attention (used for both sliding-window and fine) ----------------
// causal_local=1: blocks {i-1 (full), i (triangular)}; causal_local=0: blocks from maskb, no mask.
// K row per lane in VGPRs, V column per lane in VGPRs (transposed once per block via LDS);
// online-softmax state (m,l,acc) in LDS so the query loop stays compact.
__global__ __launch_bounds__(256) void attn_blocks(
    const float* __restrict__ q, const float* __restrict__ k, const float* __restrict__ v,
    const unsigned* __restrict__ maskb, float* __restrict__ outp, int causal_local)
{
  __shared__ float Vt[64*65];        // V tile, padded rows (transpose staging)
  __shared__ float accL[64*64];      // acc[qi][d]
  __shared__ float mL[64], lL[64];
  __shared__ float pls[4][64];
  int tid = threadIdx.x;
  int wave = __builtin_amdgcn_readfirstlane(tid>>6);
  int lane = tid & 63;
  int hb = blockIdx.x; int h = hb>>5, i = hb&31;
  for(int x=tid; x<64*64; x+=256) accL[x]=0.f;
  if(tid<64){ mL[tid]=-3.4e38f; lL[tid]=0.f; }
  unsigned mb = causal_local ? ((1u<<i) | (i ? (1u<<(i-1)) : 0u)) : maskb[hb];
  const size_t base_hk = (size_t)h*TT*HD;
  float Kreg[64];
  float Vcol[64];
  __syncthreads();
  for(int j=0;j<NB;j++){
    if(!((mb>>j)&1u)) continue;
    if(wave==0){
      const float* vsrc = v + base_hk + (size_t)(j*64+lane)*HD;
#pragma unroll
      for(int d4=0; d4<64; d4+=4){
        float4 t4 = *(const float4*)(vsrc + d4);
        Vt[lane*65 + d4+0]=t4.x; Vt[lane*65+d4+1]=t4.y; Vt[lane*65+d4+2]=t4.z; Vt[lane*65+d4+3]=t4.w;
      }
    }
    {
      const float* ksrc = k + base_hk + (size_t)(j*64+lane)*HD;
#pragma unroll
      for(int d4=0; d4<64; d4+=4){
        float4 t4 = *(const float4*)(ksrc + d4);
        Kreg[d4]=t4.x; Kreg[d4+1]=t4.y; Kreg[d4+2]=t4.z; Kreg[d4+3]=t4.w;
      }
    }
    __syncthreads();                  // Vt store visible to all waves
#pragma unroll
    for(int kk=0;kk<64;kk++) Vcol[kk] = Vt[kk*65 + lane];
    __syncthreads();                  // everyone read Vt before next overwrite
    bool diag = (causal_local!=0) && (j==i);
    for(int u=0; u<16; u++){
      int qi = wave*16 + u;
      const float* __restrict__ qrow = q + base_hk + (size_t)(i*64+qi)*HD;  // wave-uniform
      float s=0.f;
#pragma unroll
      for(int d=0; d<64; d++) s += qrow[d]*Kreg[d];
      s *= 0.125f;
      if(diag && lane>qi) s = -3.4e38f;
      float smax = rmax64(s);
      float mold = mL[qi];
      float lold = lL[qi];
      float mn = fmaxf(mold, smax);
      float pv = __expf(s - mn);
      float sp = rsum64(pv);
      float alpha = __expf(mold - mn);
      if(lane==0){ mL[qi]=mn; lL[qi]=lold*alpha+sp; }
      pls[wave][lane] = pv;
      float outd = 0.f;
#pragma unroll
      for(int kk=0;kk<64;kk++) outd += pls[wave][kk]*Vcol[kk];
      accL[qi*64+lane] = accL[qi*64+lane]*alpha + outd;
    }
  }
  __syncthreads();
  for(int u=0;u<16;u++){
    int qi = wave*16 + u;
    outp[base_hk + (size_t)(i*64+qi)*HD + lane] = accL[qi*64+lane] / lL[qi];
  }
}

// ---------------- gated combine -> merged (t, h*64+d) ----------------
__global__ __launch_bounds__(256) void combine_kernel(
    const float* __restrict__ swo, const float* __restrict__ comp, const float* __restrict__ fino,
    const float* __restrict__ gatep, float* __restrict__ merged)
{
  int idx = blockIdx.x*256 + threadIdx.x;
  int t = idx>>10, c = idx & 1023;
  int h = c>>6, d = c&63;
  const float* g = gatep + (size_t)t*48 + h*3;
  size_t a = ((size_t)h*TT + t)*HD + d;
  merged[idx] = g[0]*swo[a] + g[1]*comp[a] + g[2]*fino[a];
}

extern "C" void kernel_launch(void* const* d_in, const int* in_sizes, int n_in,
                              void* d_out, int out_size, void* d_ws, size_t ws_size,
                              hipStream_t stream) {
  (void)in_sizes; (void)n_in; (void)out_size; (void)ws_size;
  const float* hs  = (const float*)d_in[0];
  const float* Wq  = (const float*)d_in[1];
  const float* Wk  = (const float*)d_in[2];
  const float* Wv  = (const float*)d_in[3];
  const float* Wo  = (const float*)d_in[4];
  const float* Wc  = (const float*)d_in[5];
  const float* bcp = (const float*)d_in[6];
  const float* ksc = (const float*)d_in[7];
  const float* kbi = (const float*)d_in[8];
  const float* Wg  = (const float*)d_in[9];
  const float* bg  = (const float*)d_in[10];
  float* out = (float*)d_out;

  float* ws = (float*)d_ws;
  float* qb     = ws;                  // 16*2048*64
  float* kb     = qb + 2097152;
  float* vb     = kb + 2097152;
  float* gatep  = vb + 2097152;        // 2048*48
  float* kc     = gatep + 98304;       // 16*32*64
  float* vc     = kc + 32768;
  float* imp    = vc + 32768;          // 16*2048*32
  float* comp   = imp + 1048576;       // 16*2048*64
  float* swo    = comp + 2097152;
  float* fino   = swo + 2097152;
  float* merged = fino + 2097152;      // 2048*1024
  float* dkf    = merged + 2097152;    // 512
  unsigned* maskb = (unsigned*)(dkf + 512);

  float* out_avgk   = out + 2097152;
  float* out_kratio = out + 2097153;
  float* out_nent   = out + 2097665;

  sgemm_qkv<<<dim3(8,16,3), 256, 0, stream>>>(hs, Wq, Wk, Wv, qb, kb, vb);
  gate_kernel<<<dim3(2048), 256, 0, stream>>>(hs, Wg, bg, gatep);
  compress_kernel<<<dim3(512), 256, 0, stream>>>(kb, vb, Wc, bcp, kc, vc);
  comp_attn<<<dim3(8192), 256, 0, stream>>>(qb, kc, vc, imp, comp);
  block_stats<<<dim3(512), 256, 0, stream>>>(imp, ksc, kbi, maskb, dkf, out_kratio, out_nent);
  avgk_kernel<<<dim3(1), 256, 0, stream>>>(dkf, out_avgk);
  attn_blocks<<<dim3(512), 256, 0, stream>>>(qb, kb, vb, maskb, swo, 1);   // sliding window
  attn_blocks<<<dim3(512), 256, 0, stream>>>(qb, kb, vb, maskb, fino, 0);  // fine sparse
  combine_kernel<<<dim3(8192), 256, 0, stream>>>(swo, comp, fino, gatep, merged);
  sgemm_proj<<<dim3(8,32), 256, 0, stream>>>(merged, Wo, out);
}

// Round 2
// 458.246 us; speedup vs baseline: 1.4767x; 1.4767x over previous
//
#include <hip/hip_runtime.h>
#include <math.h>

#define TT 2048
#define NH 16
#define HD 64
#define NB 32
#define HIDDEN 1024

typedef short s8v __attribute__((ext_vector_type(8)));
typedef float f4v __attribute__((ext_vector_type(4)));

// ---------------- bf16 helpers (header-independent, RNE) ----------------
__device__ __forceinline__ unsigned short f2bf(float x){
  unsigned u = __float_as_uint(x);
  unsigned r = (u + 0x7fffu + ((u>>16)&1u)) >> 16;
  return (unsigned short)r;
}
__device__ __forceinline__ float bf2f(unsigned short b){
  return __uint_as_float(((unsigned)b)<<16);
}
__device__ __forceinline__ void bsplit(float x, unsigned short& h, unsigned short& l){
  h = f2bf(x);
  l = f2bf(x - bf2f(h));
}

// ---------------- wave reductions ----------------
__device__ __forceinline__ float rmax64(float v){
#pragma unroll
  for(int o=32;o>0;o>>=1) v = fmaxf(v, __shfl_xor(v,o,64));
  return v;
}
__device__ __forceinline__ float rsum64(float v){
#pragma unroll
  for(int o=32;o>0;o>>=1) v += __shfl_xor(v,o,64);
  return v;
}
__device__ __forceinline__ float rmax32(float v){
#pragma unroll
  for(int o=16;o>0;o>>=1) v = fmaxf(v, __shfl_xor(v,o,32));
  return v;
}
__device__ __forceinline__ float rsum32(float v){
#pragma unroll
  for(int o=16;o>0;o>>=1) v += __shfl_xor(v,o,32);
  return v;
}

// ---------------- split hs -> bf16 hi/lo ----------------
__global__ __launch_bounds__(256) void split_hs_k(
    const float* __restrict__ hs, unsigned short* __restrict__ hh, unsigned short* __restrict__ hl)
{
  int i = (blockIdx.x*256 + threadIdx.x)*4;
  float4 x = *(const float4*)(hs + i);
  ushort4 hv, lv;
  bsplit(x.x, hv.x, lv.x); bsplit(x.y, hv.y, lv.y);
  bsplit(x.z, hv.z, lv.z); bsplit(x.w, hv.w, lv.w);
  *(ushort4*)(hh + i) = hv;
  *(ushort4*)(hl + i) = lv;
}

// ---------------- transpose + split weights: W[k][n] -> WT[n][k] bf16 hi/lo ----------------
// z=0..2: Wq/Wk/Wv -> wth/wtl rows z*1024+n ; z=3: Wo -> woth (hi only)
__global__ __launch_bounds__(256) void prep_w_k(
    const float* __restrict__ Wq, const float* __restrict__ Wk,
    const float* __restrict__ Wv, const float* __restrict__ Wo,
    unsigned short* __restrict__ wth, unsigned short* __restrict__ wtl,
    unsigned short* __restrict__ woth)
{
  int z = blockIdx.z;
  const float* W = (z==0)?Wq:((z==1)?Wk:((z==2)?Wv:Wo));
  int k0 = blockIdx.y*64, n0 = blockIdx.x*64;
  __shared__ float L[64][68];   // row stride 68 floats (272 B, 16B-aligned)
  int t = threadIdx.x;
  int rr = t>>2, cg = t&3;
  const float* src = W + (size_t)(k0+rr)*1024 + n0 + cg*16;
  float4 a = *(const float4*)(src);
  float4 b = *(const float4*)(src+4);
  float4 c = *(const float4*)(src+8);
  float4 d = *(const float4*)(src+12);
  *(float4*)&L[rr][cg*16+0]  = a;
  *(float4*)&L[rr][cg*16+4]  = b;
  *(float4*)&L[rr][cg*16+8]  = c;
  *(float4*)&L[rr][cg*16+12] = d;
  __syncthreads();
  int nr = t>>2, kg = t&3;
  unsigned short hb[16], lb[16];
#pragma unroll
  for(int j=0;j<16;j++){
    float v = L[kg*16+j][nr];
    bsplit(v, hb[j], lb[j]);
  }
  if(z<3){
    size_t orow = ((size_t)z*1024 + n0 + nr)*1024 + k0 + kg*16;
    *(ushort4*)(wth+orow+0)  = make_ushort4(hb[0],hb[1],hb[2],hb[3]);
    *(ushort4*)(wth+orow+4)  = make_ushort4(hb[4],hb[5],hb[6],hb[7]);
    *(ushort4*)(wth+orow+8)  = make_ushort4(hb[8],hb[9],hb[10],hb[11]);
    *(ushort4*)(wth+orow+12) = make_ushort4(hb[12],hb[13],hb[14],hb[15]);
    *(ushort4*)(wtl+orow+0)  = make_ushort4(lb[0],lb[1],lb[2],lb[3]);
    *(ushort4*)(wtl+orow+4)  = make_ushort4(lb[4],lb[5],lb[6],lb[7]);
    *(ushort4*)(wtl+orow+8)  = make_ushort4(lb[8],lb[9],lb[10],lb[11]);
    *(ushort4*)(wtl+orow+12) = make_ushort4(lb[12],lb[13],lb[14],lb[15]);
  }else{
    size_t orow = ((size_t)n0 + nr)*1024 + k0 + kg*16;
    *(ushort4*)(woth+orow+0)  = make_ushort4(hb[0],hb[1],hb[2],hb[3]);
    *(ushort4*)(woth+orow+4)  = make_ushort4(hb[4],hb[5],hb[6],hb[7]);
    *(ushort4*)(woth+orow+8)  = make_ushort4(hb[8],hb[9],hb[10],hb[11]);
    *(ushort4*)(woth+orow+12) = make_ushort4(hb[12],hb[13],hb[14],hb[15]);
  }
}

// ---------------- QKV MFMA GEMM: (2048x1024) x (1024x3072) split-bf16 ----------------
// 128x128 tile, 4 waves each 64x64 (4x4 of 16x16x32). 3-pass for Q,K tiles (bx<16), 1-pass for V.
// Scatter C columns: n -> z=n>>10, head=(n&1023)>>6, d=n&63, layout [h][t][d].
#define LROW 40
__global__ __launch_bounds__(256) void mfma_qkv_k(
    const unsigned short* __restrict__ ahg, const unsigned short* __restrict__ alg,
    const unsigned short* __restrict__ bhg, const unsigned short* __restrict__ blg,
    float* __restrict__ C0, float* __restrict__ C1, float* __restrict__ C2)
{
  __shared__ unsigned short Ah[128*LROW], Al[128*LROW], Bh[128*LROW], Bl[128*LROW];
  int tid = threadIdx.x;
  int bn = blockIdx.x*128, bm = blockIdx.y*128;
  bool tp = (blockIdx.x < 16);
  int sr = tid>>2, skg = tid&3;
  const unsigned short* gA  = ahg + (size_t)(bm+sr)*HIDDEN + skg*8;
  const unsigned short* gAl = alg + (size_t)(bm+sr)*HIDDEN + skg*8;
  const unsigned short* gB  = bhg + (size_t)(bn+sr)*HIDDEN + skg*8;
  const unsigned short* gBl = blg + (size_t)(bn+sr)*HIDDEN + skg*8;
  int wv = tid>>6, ln = tid&63;
  int wm = (wv&1)*64, wn = (wv>>1)*64;
  int fr = ln&15, fq = ln>>4;
  int wlds = sr*LROW + skg*8;
  f4v acc[4][4] = {};
  for(int k0=0;k0<HIDDEN;k0+=32){
    s8v a0 = *(const s8v*)(gA + k0);
    s8v a1 = *(const s8v*)(gA + 65536 + k0);
    s8v b0 = *(const s8v*)(gB + k0);
    s8v b1 = *(const s8v*)(gB + 65536 + k0);
    s8v a0l, a1l, b0l, b1l;
    if(tp){
      a0l = *(const s8v*)(gAl + k0);
      a1l = *(const s8v*)(gAl + 65536 + k0);
      b0l = *(const s8v*)(gBl + k0);
      b1l = *(const s8v*)(gBl + 65536 + k0);
    }
    __syncthreads();
    *(s8v*)&Ah[wlds] = a0; *(s8v*)&Ah[wlds + 64*LROW] = a1;
    *(s8v*)&Bh[wlds] = b0; *(s8v*)&Bh[wlds + 64*LROW] = b1;
    if(tp){
      *(s8v*)&Al[wlds] = a0l; *(s8v*)&Al[wlds + 64*LROW] = a1l;
      *(s8v*)&Bl[wlds] = b0l; *(s8v*)&Bl[wlds + 64*LROW] = b1l;
    }
    __syncthreads();
    s8v af[4], bf[4], tf;
#pragma unroll
    for(int i=0;i<4;i++) af[i] = *(const s8v*)&Ah[(wm+i*16+fr)*LROW + fq*8];
#pragma unroll
    for(int i=0;i<4;i++) bf[i] = *(const s8v*)&Bh[(wn+i*16+fr)*LROW + fq*8];
#pragma unroll
    for(int i=0;i<4;i++)
#pragma unroll
      for(int j=0;j<4;j++)
        acc[i][j] = __builtin_amdgcn_mfma_f32_16x16x32_bf16(af[i], bf[j], acc[i][j], 0,0,0);
    if(tp){
#pragma unroll
      for(int i=0;i<4;i++){
        tf = *(const s8v*)&Al[(wm+i*16+fr)*LROW + fq*8];
#pragma unroll
        for(int j=0;j<4;j++)
          acc[i][j] = __builtin_amdgcn_mfma_f32_16x16x32_bf16(tf, bf[j], acc[i][j], 0,0,0);
      }
#pragma unroll
      for(int j=0;j<4;j++){
        tf = *(const s8v*)&Bl[(wn+j*16+fr)*LROW + fq*8];
#pragma unroll
        for(int i=0;i<4;i++)
          acc[i][j] = __builtin_amdgcn_mfma_f32_16x16x32_bf16(af[i], tf, acc[i][j], 0,0,0);
      }
    }
  }
  int z = bn >> 10;
  float* C = (z==0)?C0:((z==1)?C1:C2);
#pragma unroll
  for(int i=0;i<4;i++){
    int mb = bm + wm + i*16 + fq*4;
#pragma unroll
    for(int j=0;j<4;j++){
      int n = bn + wn + j*16 + fr;
      int n1 = n & 1023, hd = n1>>6, d = n1&63;
      float* dst = C + ((size_t)hd*TT + mb)*HD + d;
#pragma unroll
      for(int r=0;r<4;r++) dst[(size_t)r*HD] = acc[i][j][r];
    }
  }
}

// ---------------- output projection MFMA GEMM: merged_bf16(2048x1024) x WoT(1024x1024) ----------------
__global__ __launch_bounds__(256) void mfma_proj_k(
    const unsigned short* __restrict__ ahg, const unsigned short* __restrict__ bhg,
    float* __restrict__ C)
{
  __shared__ unsigned short Ah[128*LROW], Bh[128*LROW];
  int tid = threadIdx.x;
  int bn = blockIdx.x*128, bm = blockIdx.y*128;
  int sr = tid>>2, skg = tid&3;
  const unsigned short* gA = ahg + (size_t)(bm+sr)*HIDDEN + skg*8;
  const unsigned short* gB = bhg + (size_t)(bn+sr)*HIDDEN + skg*8;
  int wv = tid>>6, ln = tid&63;
  int wm = (wv&1)*64, wn = (wv>>1)*64;
  int fr = ln&15, fq = ln>>4;
  int wlds = sr*LROW + skg*8;
  f4v acc[4][4] = {};
  for(int k0=0;k0<HIDDEN;k0+=32){
    s8v a0 = *(const s8v*)(gA + k0);
    s8v a1 = *(const s8v*)(gA + 65536 + k0);
    s8v b0 = *(const s8v*)(gB + k0);
    s8v b1 = *(const s8v*)(gB + 65536 + k0);
    __syncthreads();
    *(s8v*)&Ah[wlds] = a0; *(s8v*)&Ah[wlds + 64*LROW] = a1;
    *(s8v*)&Bh[wlds] = b0; *(s8v*)&Bh[wlds + 64*LROW] = b1;
    __syncthreads();
    s8v af[4], bf[4];
#pragma unroll
    for(int i=0;i<4;i++) af[i] = *(const s8v*)&Ah[(wm+i*16+fr)*LROW + fq*8];
#pragma unroll
    for(int i=0;i<4;i++) bf[i] = *(const s8v*)&Bh[(wn+i*16+fr)*LROW + fq*8];
#pragma unroll
    for(int i=0;i<4;i++)
#pragma unroll
      for(int j=0;j<4;j++)
        acc[i][j] = __builtin_amdgcn_mfma_f32_16x16x32_bf16(af[i], bf[j], acc[i][j], 0,0,0);
  }
#pragma unroll
  for(int i=0;i<4;i++){
    int mb = bm + wm + i*16 + fq*4;
#pragma unroll
    for(int j=0;j<4;j++){
      int n = bn + wn + j*16 + fr;
      float* dst = C + (size_t)mb*HIDDEN + n;
#pragma unroll
      for(int r=0;r<4;r++) dst[(size_t)r*HIDDEN] = acc[i][j][r];
    }
  }
}

// ---------------- gate: sigmoid(hs @ Wg + bg), (2048 x 48) ----------------
__global__ __launch_bounds__(256) void gate_kernel(
    const float* __restrict__ hs, const float* __restrict__ Wg, const float* __restrict__ bg,
    float* __restrict__ gatep)
{
  int t = blockIdx.x;
  __shared__ float row[1024];
  __shared__ float red[4][64];
  int tid = threadIdx.x;
  *(float4*)(row + tid*4) = *(const float4*)(hs + (size_t)t*HIDDEN + tid*4);
  __syncthreads();
  int n = tid & 63, part = tid>>6;
  float s = 0.f;
  if(n < 48){
    const float* w = Wg + n;
    for(int kx = part*256; kx < part*256+256; kx++)
      s += row[kx]*w[(size_t)kx*48];
  }
  red[part][n] = s;
  __syncthreads();
  if(part==0 && n<48){
    float x = red[0][n]+red[1][n]+red[2][n]+red[3][n] + bg[n];
    gatep[(size_t)t*48 + n] = 1.f/(1.f+expf(-x));
  }
}

// ---------------- compress MLP: gelu(k_blk @ Wc + bc) for k and v (shared weights) ----------------
__global__ __launch_bounds__(256) void compress_kernel(
    const float* __restrict__ kbuf, const float* __restrict__ vbuf,
    const float* __restrict__ Wc, const float* __restrict__ bcp,
    float* __restrict__ kc, float* __restrict__ vc)
{
  int hb = blockIdx.x; int h = hb>>5, i = hb&31;
  __shared__ float inK[4096], inV[4096];
  int tid = threadIdx.x;
  const float4* sk = (const float4*)(kbuf + ((size_t)h*TT + i*64)*HD);
  const float4* sv = (const float4*)(vbuf + ((size_t)h*TT + i*64)*HD);
  float4* dK=(float4*)inK; float4* dV=(float4*)inV;
#pragma unroll
  for(int u=0;u<4;u++){ dK[tid+256*u]=sk[tid+256*u]; dV[tid+256*u]=sv[tid+256*u]; }
  __syncthreads();
  int d = tid&63, part = tid>>6;
  float sK=0.f, sV=0.f;
  const float* w = Wc + d;
  for(int idx = part*1024; idx < part*1024+1024; idx++){
    float wv = w[(size_t)idx*HD];
    sK += inK[idx]*wv; sV += inV[idx]*wv;
  }
  __shared__ float redK[4][64], redV[4][64];
  redK[part][d]=sK; redV[part][d]=sV;
  __syncthreads();
  if(part==0){
    float xK = redK[0][d]+redK[1][d]+redK[2][d]+redK[3][d] + bcp[d];
    float xV = redV[0][d]+redV[1][d]+redV[2][d]+redV[3][d] + bcp[d];
    kc[((size_t)h*NB+i)*HD + d] = 0.5f*xK*(1.f+erff(xK*0.70710678118654752f));
    vc[((size_t)h*NB+i)*HD + d] = 0.5f*xV*(1.f+erff(xV*0.70710678118654752f));
  }
}

// ---------------- compressed attention: importance + softmax + comp_out ----------------
__global__ __launch_bounds__(256) void comp_attn(
    const float* __restrict__ q, const float* __restrict__ kcb, const float* __restrict__ vcb,
    float* __restrict__ imp, float* __restrict__ comp)
{
  __shared__ float qls[4][64];
  __shared__ float pls[4][64];
  int tid=threadIdx.x;
  int wave = tid>>6, lane = tid&63;
  int idx = blockIdx.x*4 + wave;    // (h,t)
  int h = idx>>11, t = idx & 2047;
  qls[wave][lane] = q[((size_t)h*TT + t)*HD + lane];
  __syncthreads();
  if(lane<32){
    const float* kr = kcb + ((size_t)h*NB + lane)*HD;
    float s=0.f;
#pragma unroll
    for(int d=0; d<64; d++) s += qls[wave][d]*kr[d];
    s *= 0.125f;
    imp[((size_t)h*TT + t)*NB + lane] = s;
    float m = rmax32(s);
    float e = __expf(s-m);
    float l = rsum32(e);
    pls[wave][lane] = e/l;
  }
  __syncthreads();
  const float* vbh = vcb + (size_t)h*NB*HD;
  float o=0.f;
#pragma unroll
  for(int j=0;j<32;j++) o += pls[wave][j]*vbh[j*HD + lane];
  comp[((size_t)h*TT + t)*HD + lane] = o;
}

// ---------------- block scores -> entropy -> dynamic_k -> top-k mask ----------------
__global__ __launch_bounds__(256) void block_stats(
    const float* __restrict__ imp, const float* __restrict__ ksc, const float* __restrict__ kbi,
    unsigned* __restrict__ maskb, float* __restrict__ dkf,
    float* __restrict__ out_kratio, float* __restrict__ out_nent)
{
  int hb = blockIdx.x; int h = hb>>5, i = hb&31;
  int tid = threadIdx.x; int j = tid&31, p = tid>>5;
  const float* base = imp + ((size_t)h*TT + i*64)*NB;
  float s = 0.f;
  for(int t2=p*8; t2<p*8+8; t2++) s += base[(size_t)t2*NB + j];
  __shared__ float red[8][32];
  red[p][j] = s;
  __syncthreads();
  if(tid < 32){
    float bs = 0.f;
#pragma unroll
    for(int pp=0; pp<8; pp++) bs += red[pp][j];
    bs *= (1.f/64.f);
    float m = rmax32(bs);
    float e = expf(bs - m);
    float se = rsum32(e);
    float prob = e/se;
    float ent = rsum32(-prob * logf(prob + 1e-9f));
    float nent = ent / (3.4657359027997265f + 1e-9f);  // log(32)
    float kl = ksc[h]*nent + kbi[h];
    float kr = 1.f/(1.f + expf(-kl));
    float dkfl = fminf(fmaxf(8.f*kr, 1.f), 8.f);
    int dk = (int)dkfl;
    unsigned sel = 0u;
    for(int r=0;r<dk;r++){
      bool unpicked = ((sel>>j)&1u)==0u;
      float cand = unpicked ? bs : -3.4e38f;
      float mx = rmax32(cand);
      unsigned long long b = __ballot(cand == mx);
      int idxsel = __ffsll(b & 0xffffffffull) - 1;
      sel |= (1u<<idxsel);
    }
    sel |= (1u<<i);
    if(j==0){
      maskb[hb] = sel;
      dkf[hb] = (float)dk;
      out_kratio[hb] = kr;
      out_nent[hb] = nent;
    }
  }
}

// ---------------- avg_k reduction ----------------
__global__ __launch_bounds__(256) void avgk_kernel(const float* __restrict__ dkf, float* __restrict__ outp){
  __shared__ float red[256];
  int tid=threadIdx.x;
  red[tid] = dkf[tid] + dkf[tid+256];
  __syncthreads();
  for(int s=128;s>0;s>>=1){ if(tid<s) red[tid]+=red[tid+s]; __syncthreads(); }
  if(tid==0) outp[0] = red[0] * (1.f/512.f);
}

// ---------------- block-sparse flash attention ----------------
__global__ __launch_bounds__(256) void attn_blocks(
    const float* __restrict__ q, const float* __restrict__ k, const float* __restrict__ v,
    const unsigned* __restrict__ maskb, float* __restrict__ outp, int causal_local)
{
  __shared__ float Vt[64*65];
  __shared__ float accL[64*64];
  __shared__ float mL[64], lL[64];
  __shared__ float pls[4][64];
  int tid = threadIdx.x;
  int wave = __builtin_amdgcn_readfirstlane(tid>>6);
  int lane = tid & 63;
  int hb = blockIdx.x; int h = hb>>5, i = hb&31;
  for(int x=tid; x<64*64; x+=256) accL[x]=0.f;
  if(tid<64){ mL[tid]=-3.4e38f; lL[tid]=0.f; }
  unsigned mb = causal_local ? ((1u<<i) | (i ? (1u<<(i-1)) : 0u)) : maskb[hb];
  const size_t base_hk = (size_t)h*TT*HD;
  float Kreg[64];
  float Vcol[64];
  __syncthreads();
  for(int j=0;j<NB;j++){
    if(!((mb>>j)&1u)) continue;
    if(wave==0){
      const float* vsrc = v + base_hk + (size_t)(j*64+lane)*HD;
#pragma unroll
      for(int d4=0; d4<64; d4+=4){
        float4 t4 = *(const float4*)(vsrc + d4);
        Vt[lane*65 + d4+0]=t4.x; Vt[lane*65+d4+1]=t4.y; Vt[lane*65+d4+2]=t4.z; Vt[lane*65+d4+3]=t4.w;
      }
    }
    {
      const float* ksrc = k + base_hk + (size_t)(j*64+lane)*HD;
#pragma unroll
      for(int d4=0; d4<64; d4+=4){
        float4 t4 = *(const float4*)(ksrc + d4);
        Kreg[d4]=t4.x; Kreg[d4+1]=t4.y; Kreg[d4+2]=t4.z; Kreg[d4+3]=t4.w;
      }
    }
    __syncthreads();
#pragma unroll
    for(int kk=0;kk<64;kk++) Vcol[kk] = Vt[kk*65 + lane];
    __syncthreads();
    bool diag = (causal_local!=0) && (j==i);
    for(int u=0; u<16; u++){
      int qi = wave*16 + u;
      const float* __restrict__ qrow = q + base_hk + (size_t)(i*64+qi)*HD;
      float s=0.f;
#pragma unroll
      for(int d=0; d<64; d++) s += qrow[d]*Kreg[d];
      s *= 0.125f;
      if(diag && lane>qi) s = -3.4e38f;
      float smax = rmax64(s);
      float mold = mL[qi];
      float lold = lL[qi];
      float mn = fmaxf(mold, smax);
      float pv = __expf(s - mn);
      float sp = rsum64(pv);
      float alpha = __expf(mold - mn);
      if(lane==0){ mL[qi]=mn; lL[qi]=lold*alpha+sp; }
      pls[wave][lane] = pv;
      float outd = 0.f;
#pragma unroll
      for(int kk=0;kk<64;kk++) outd += pls[wave][kk]*Vcol[kk];
      accL[qi*64+lane] = accL[qi*64+lane]*alpha + outd;
    }
  }
  __syncthreads();
  for(int u=0;u<16;u++){
    int qi = wave*16 + u;
    outp[base_hk + (size_t)(i*64+qi)*HD + lane] = accL[qi*64+lane] / lL[qi];
  }
}

// ---------------- gated combine -> merged bf16 (t, h*64+d) ----------------
__global__ __launch_bounds__(256) void combine_kernel(
    const float* __restrict__ swo, const float* __restrict__ comp, const float* __restrict__ fino,
    const float* __restrict__ gatep, unsigned short* __restrict__ mergedh)
{
  int idx = blockIdx.x*256 + threadIdx.x;
  int t = idx>>10, c = idx & 1023;
  int h = c>>6, d = c&63;
  const float* g = gatep + (size_t)t*48 + h*3;
  size_t a = ((size_t)h*TT + t)*HD + d;
  mergedh[idx] = f2bf(g[0]*swo[a] + g[1]*comp[a] + g[2]*fino[a]);
}

extern "C" void kernel_launch(void* const* d_in, const int* in_sizes, int n_in,
                              void* d_out, int out_size, void* d_ws, size_t ws_size,
                              hipStream_t stream) {
  (void)in_sizes; (void)n_in; (void)out_size; (void)ws_size;
  const float* hs  = (const float*)d_in[0];
  const float* Wq  = (const float*)d_in[1];
  const float* Wk  = (const float*)d_in[2];
  const float* Wv  = (const float*)d_in[3];
  const float* Wo  = (const float*)d_in[4];
  const float* Wc  = (const float*)d_in[5];
  const float* bcp = (const float*)d_in[6];
  const float* ksc = (const float*)d_in[7];
  const float* kbi = (const float*)d_in[8];
  const float* Wg  = (const float*)d_in[9];
  const float* bg  = (const float*)d_in[10];
  float* out = (float*)d_out;

  float* ws = (float*)d_ws;
  float* qb     = ws;                   // 2097152
  float* kb     = qb + 2097152;
  float* vb     = kb + 2097152;
  float* gatep  = vb + 2097152;         // 98304
  float* kc     = gatep + 98304;        // 32768
  float* vc     = kc + 32768;           // 32768
  float* imp    = vc + 32768;           // 1048576
  float* comp   = imp + 1048576;        // 2097152  (also hsh/hsl alias region)
  float* swo    = comp + 2097152;       // 2097152  (also wth alias region)
  float* fino   = swo + 2097152;        // 2097152  (also wtl alias region)
  unsigned short* mergedh = (unsigned short*)(fino + 2097152);   // 2M shorts = 1048576 floats
  float* dkf    = fino + 2097152 + 1048576;   // 512
  unsigned* maskb = (unsigned*)(dkf + 512);   // 512 ints
  unsigned short* woth = (unsigned short*)(dkf + 1024);          // 1M shorts = 524288 floats

  // bf16 staging buffers, aliased over comp/swo/fino (dead until after mfma_qkv)
  unsigned short* hsh = (unsigned short*)comp;                   // 2M shorts
  unsigned short* hsl = (unsigned short*)(comp + 1048576);       // 2M shorts
  unsigned short* wth = (unsigned short*)swo;                    // 3M shorts
  unsigned short* wtl = (unsigned short*)(swo + 1572864);        // 3M shorts (ends before mergedh)

  float* out_avgk   = out + 2097152;
  float* out_kratio = out + 2097153;
  float* out_nent   = out + 2097665;

  split_hs_k<<<dim3(2048), 256, 0, stream>>>(hs, hsh, hsl);
  prep_w_k<<<dim3(16,16,4), 256, 0, stream>>>(Wq, Wk, Wv, Wo, wth, wtl, woth);
  mfma_qkv_k<<<dim3(24,16), 256, 0, stream>>>(hsh, hsl, wth, wtl, qb, kb, vb);
  gate_kernel<<<dim3(2048), 256, 0, stream>>>(hs, Wg, bg, gatep);
  compress_kernel<<<dim3(512), 256, 0, stream>>>(kb, vb, Wc, bcp, kc, vc);
  comp_attn<<<dim3(8192), 256, 0, stream>>>(qb, kc, vc, imp, comp);
  block_stats<<<dim3(512), 256, 0, stream>>>(imp, ksc, kbi, maskb, dkf, out_kratio, out_nent);
  avgk_kernel<<<dim3(1), 256, 0, stream>>>(dkf, out_avgk);
  attn_blocks<<<dim3(512), 256, 0, stream>>>(qb, kb, vb, maskb, swo, 1);
  attn_blocks<<<dim3(512), 256, 0, stream>>>(qb, kb, vb, maskb, fino, 0);
  combine_kernel<<<dim3(8192), 256, 0, stream>>>(swo, comp, fino, gatep, mergedh);
  mfma_proj_k<<<dim3(8,16), 256, 0, stream>>>(mergedh, woth, out);
}

// Round 3
// 315.228 us; speedup vs baseline: 2.1467x; 1.4537x over previous
//
#include <hip/hip_runtime.h>
#include <math.h>

#define TT 2048
#define NH 16
#define HD 64
#define NB 32
#define HIDDEN 1024

typedef short s8v __attribute__((ext_vector_type(8)));
typedef float f4v __attribute__((ext_vector_type(4)));

// ---------------- bf16 helpers (header-independent, RNE) ----------------
__device__ __forceinline__ unsigned short f2bf(float x){
  unsigned u = __float_as_uint(x);
  unsigned r = (u + 0x7fffu + ((u>>16)&1u)) >> 16;
  return (unsigned short)r;
}
__device__ __forceinline__ float bf2f(unsigned short b){
  return __uint_as_float(((unsigned)b)<<16);
}
__device__ __forceinline__ void bsplit(float x, unsigned short& h, unsigned short& l){
  h = f2bf(x);
  l = f2bf(x - bf2f(h));
}

// ---------------- wave reductions ----------------
__device__ __forceinline__ float rmax32(float v){
#pragma unroll
  for(int o=16;o>0;o>>=1) v = fmaxf(v, __shfl_xor(v,o,32));
  return v;
}
__device__ __forceinline__ float rsum32(float v){
#pragma unroll
  for(int o=16;o>0;o>>=1) v += __shfl_xor(v,o,32);
  return v;
}

// ---------------- split hs -> bf16 hi/lo ----------------
__global__ __launch_bounds__(256) void split_hs_k(
    const float* __restrict__ hs, unsigned short* __restrict__ hh, unsigned short* __restrict__ hl)
{
  int i = (blockIdx.x*256 + threadIdx.x)*4;
  float4 x = *(const float4*)(hs + i);
  ushort4 hv, lv;
  bsplit(x.x, hv.x, lv.x); bsplit(x.y, hv.y, lv.y);
  bsplit(x.z, hv.z, lv.z); bsplit(x.w, hv.w, lv.w);
  *(ushort4*)(hh + i) = hv;
  *(ushort4*)(hl + i) = lv;
}

// ---------------- transpose + split weights: W[k][n] -> WT[n][k] bf16 hi/lo ----------------
__global__ __launch_bounds__(256) void prep_w_k(
    const float* __restrict__ Wq, const float* __restrict__ Wk,
    const float* __restrict__ Wv, const float* __restrict__ Wo,
    unsigned short* __restrict__ wth, unsigned short* __restrict__ wtl,
    unsigned short* __restrict__ woth)
{
  int z = blockIdx.z;
  const float* W = (z==0)?Wq:((z==1)?Wk:((z==2)?Wv:Wo));
  int k0 = blockIdx.y*64, n0 = blockIdx.x*64;
  __shared__ float L[64][68];
  int t = threadIdx.x;
  int rr = t>>2, cg = t&3;
  const float* src = W + (size_t)(k0+rr)*1024 + n0 + cg*16;
  float4 a = *(const float4*)(src);
  float4 b = *(const float4*)(src+4);
  float4 c = *(const float4*)(src+8);
  float4 d = *(const float4*)(src+12);
  *(float4*)&L[rr][cg*16+0]  = a;
  *(float4*)&L[rr][cg*16+4]  = b;
  *(float4*)&L[rr][cg*16+8]  = c;
  *(float4*)&L[rr][cg*16+12] = d;
  __syncthreads();
  int nr = t>>2, kg = t&3;
  unsigned short hb[16], lb[16];
#pragma unroll
  for(int j=0;j<16;j++){
    float v = L[kg*16+j][nr];
    bsplit(v, hb[j], lb[j]);
  }
  if(z<3){
    size_t orow = ((size_t)z*1024 + n0 + nr)*1024 + k0 + kg*16;
    *(ushort4*)(wth+orow+0)  = make_ushort4(hb[0],hb[1],hb[2],hb[3]);
    *(ushort4*)(wth+orow+4)  = make_ushort4(hb[4],hb[5],hb[6],hb[7]);
    *(ushort4*)(wth+orow+8)  = make_ushort4(hb[8],hb[9],hb[10],hb[11]);
    *(ushort4*)(wth+orow+12) = make_ushort4(hb[12],hb[13],hb[14],hb[15]);
    *(ushort4*)(wtl+orow+0)  = make_ushort4(lb[0],lb[1],lb[2],lb[3]);
    *(ushort4*)(wtl+orow+4)  = make_ushort4(lb[4],lb[5],lb[6],lb[7]);
    *(ushort4*)(wtl+orow+8)  = make_ushort4(lb[8],lb[9],lb[10],lb[11]);
    *(ushort4*)(wtl+orow+12) = make_ushort4(lb[12],lb[13],lb[14],lb[15]);
  }else{
    size_t orow = ((size_t)n0 + nr)*1024 + k0 + kg*16;
    *(ushort4*)(woth+orow+0)  = make_ushort4(hb[0],hb[1],hb[2],hb[3]);
    *(ushort4*)(woth+orow+4)  = make_ushort4(hb[4],hb[5],hb[6],hb[7]);
    *(ushort4*)(woth+orow+8)  = make_ushort4(hb[8],hb[9],hb[10],hb[11]);
    *(ushort4*)(woth+orow+12) = make_ushort4(hb[12],hb[13],hb[14],hb[15]);
  }
}

// ---------------- QKV MFMA GEMM (split-bf16 3-pass for Q,K; 1-pass for V) ----------------
#define LROW 40
__global__ __launch_bounds__(256) void mfma_qkv_k(
    const unsigned short* __restrict__ ahg, const unsigned short* __restrict__ alg,
    const unsigned short* __restrict__ bhg, const unsigned short* __restrict__ blg,
    float* __restrict__ C0, float* __restrict__ C1, float* __restrict__ C2)
{
  __shared__ unsigned short Ah[128*LROW], Al[128*LROW], Bh[128*LROW], Bl[128*LROW];
  int tid = threadIdx.x;
  int bn = blockIdx.x*128, bm = blockIdx.y*128;
  bool tp = (blockIdx.x < 16);
  int sr = tid>>2, skg = tid&3;
  const unsigned short* gA  = ahg + (size_t)(bm+sr)*HIDDEN + skg*8;
  const unsigned short* gAl = alg + (size_t)(bm+sr)*HIDDEN + skg*8;
  const unsigned short* gB  = bhg + (size_t)(bn+sr)*HIDDEN + skg*8;
  const unsigned short* gBl = blg + (size_t)(bn+sr)*HIDDEN + skg*8;
  int wv = tid>>6, ln = tid&63;
  int wm = (wv&1)*64, wn = (wv>>1)*64;
  int fr = ln&15, fq = ln>>4;
  int wlds = sr*LROW + skg*8;
  f4v acc[4][4] = {};
  for(int k0=0;k0<HIDDEN;k0+=32){
    s8v a0 = *(const s8v*)(gA + k0);
    s8v a1 = *(const s8v*)(gA + 65536 + k0);
    s8v b0 = *(const s8v*)(gB + k0);
    s8v b1 = *(const s8v*)(gB + 65536 + k0);
    s8v a0l, a1l, b0l, b1l;
    if(tp){
      a0l = *(const s8v*)(gAl + k0);
      a1l = *(const s8v*)(gAl + 65536 + k0);
      b0l = *(const s8v*)(gBl + k0);
      b1l = *(const s8v*)(gBl + 65536 + k0);
    }
    __syncthreads();
    *(s8v*)&Ah[wlds] = a0; *(s8v*)&Ah[wlds + 64*LROW] = a1;
    *(s8v*)&Bh[wlds] = b0; *(s8v*)&Bh[wlds + 64*LROW] = b1;
    if(tp){
      *(s8v*)&Al[wlds] = a0l; *(s8v*)&Al[wlds + 64*LROW] = a1l;
      *(s8v*)&Bl[wlds] = b0l; *(s8v*)&Bl[wlds + 64*LROW] = b1l;
    }
    __syncthreads();
    s8v af[4], bf[4], tf;
#pragma unroll
    for(int i=0;i<4;i++) af[i] = *(const s8v*)&Ah[(wm+i*16+fr)*LROW + fq*8];
#pragma unroll
    for(int i=0;i<4;i++) bf[i] = *(const s8v*)&Bh[(wn+i*16+fr)*LROW + fq*8];
#pragma unroll
    for(int i=0;i<4;i++)
#pragma unroll
      for(int j=0;j<4;j++)
        acc[i][j] = __builtin_amdgcn_mfma_f32_16x16x32_bf16(af[i], bf[j], acc[i][j], 0,0,0);
    if(tp){
#pragma unroll
      for(int i=0;i<4;i++){
        tf = *(const s8v*)&Al[(wm+i*16+fr)*LROW + fq*8];
#pragma unroll
        for(int j=0;j<4;j++)
          acc[i][j] = __builtin_amdgcn_mfma_f32_16x16x32_bf16(tf, bf[j], acc[i][j], 0,0,0);
      }
#pragma unroll
      for(int j=0;j<4;j++){
        tf = *(const s8v*)&Bl[(wn+j*16+fr)*LROW + fq*8];
#pragma unroll
        for(int i=0;i<4;i++)
          acc[i][j] = __builtin_amdgcn_mfma_f32_16x16x32_bf16(af[i], tf, acc[i][j], 0,0,0);
      }
    }
  }
  int z = bn >> 10;
  float* C = (z==0)?C0:((z==1)?C1:C2);
#pragma unroll
  for(int i=0;i<4;i++){
    int mb = bm + wm + i*16 + fq*4;
#pragma unroll
    for(int j=0;j<4;j++){
      int n = bn + wn + j*16 + fr;
      int n1 = n & 1023, hd = n1>>6, d = n1&63;
      float* dst = C + ((size_t)hd*TT + mb)*HD + d;
#pragma unroll
      for(int r=0;r<4;r++) dst[(size_t)r*HD] = acc[i][j][r];
    }
  }
}

// ---------------- fp32 q/k -> bf16 [h][t][d] ----------------
__global__ __launch_bounds__(256) void conv_qk(
    const float* __restrict__ qb, const float* __restrict__ kb,
    unsigned short* __restrict__ qbh, unsigned short* __restrict__ kbh)
{
  const float* s = blockIdx.y ? kb : qb;
  unsigned short* d = blockIdx.y ? kbh : qbh;
  size_t i = ((size_t)blockIdx.x*256 + threadIdx.x)*8;
  float4 a = *(const float4*)(s+i);
  float4 b = *(const float4*)(s+i+4);
  s8v r;
  r[0]=(short)f2bf(a.x); r[1]=(short)f2bf(a.y); r[2]=(short)f2bf(a.z); r[3]=(short)f2bf(a.w);
  r[4]=(short)f2bf(b.x); r[5]=(short)f2bf(b.y); r[6]=(short)f2bf(b.z); r[7]=(short)f2bf(b.w);
  *(s8v*)(d+i) = r;
}

// ---------------- fp32 v [h][t][d] -> bf16 v^T [h][d][t] ----------------
__global__ __launch_bounds__(256) void conv_vt(
    const float* __restrict__ vb, unsigned short* __restrict__ vth)
{
  int tt = blockIdx.x, h = blockIdx.y;
  __shared__ float L[64][68];
  int t = threadIdx.x;
  int row = t>>2, dg = (t&3)*16;
  const float* src = vb + ((size_t)h*TT + tt*64 + row)*HD + dg;
  float4 a = *(const float4*)(src);
  float4 b = *(const float4*)(src+4);
  float4 c = *(const float4*)(src+8);
  float4 e = *(const float4*)(src+12);
  *(float4*)&L[row][dg+0]  = a;
  *(float4*)&L[row][dg+4]  = b;
  *(float4*)&L[row][dg+8]  = c;
  *(float4*)&L[row][dg+12] = e;
  __syncthreads();
  int d = t>>2, kg = (t&3)*16;
  s8v r0, r1;
#pragma unroll
  for(int u=0;u<8;u++)  r0[u] = (short)f2bf(L[kg+u][d]);
#pragma unroll
  for(int u=0;u<8;u++)  r1[u] = (short)f2bf(L[kg+8+u][d]);
  unsigned short* dst = vth + ((size_t)h*HD + d)*TT + tt*64 + kg;
  *(s8v*)(dst)   = r0;
  *(s8v*)(dst+8) = r1;
}

// ---------------- output projection MFMA GEMM ----------------
__global__ __launch_bounds__(256) void mfma_proj_k(
    const unsigned short* __restrict__ ahg, const unsigned short* __restrict__ bhg,
    float* __restrict__ C)
{
  __shared__ unsigned short Ah[128*LROW], Bh[128*LROW];
  int tid = threadIdx.x;
  int bn = blockIdx.x*128, bm = blockIdx.y*128;
  int sr = tid>>2, skg = tid&3;
  const unsigned short* gA = ahg + (size_t)(bm+sr)*HIDDEN + skg*8;
  const unsigned short* gB = bhg + (size_t)(bn+sr)*HIDDEN + skg*8;
  int wv = tid>>6, ln = tid&63;
  int wm = (wv&1)*64, wn = (wv>>1)*64;
  int fr = ln&15, fq = ln>>4;
  int wlds = sr*LROW + skg*8;
  f4v acc[4][4] = {};
  for(int k0=0;k0<HIDDEN;k0+=32){
    s8v a0 = *(const s8v*)(gA + k0);
    s8v a1 = *(const s8v*)(gA + 65536 + k0);
    s8v b0 = *(const s8v*)(gB + k0);
    s8v b1 = *(const s8v*)(gB + 65536 + k0);
    __syncthreads();
    *(s8v*)&Ah[wlds] = a0; *(s8v*)&Ah[wlds + 64*LROW] = a1;
    *(s8v*)&Bh[wlds] = b0; *(s8v*)&Bh[wlds + 64*LROW] = b1;
    __syncthreads();
    s8v af[4], bf[4];
#pragma unroll
    for(int i=0;i<4;i++) af[i] = *(const s8v*)&Ah[(wm+i*16+fr)*LROW + fq*8];
#pragma unroll
    for(int i=0;i<4;i++) bf[i] = *(const s8v*)&Bh[(wn+i*16+fr)*LROW + fq*8];
#pragma unroll
    for(int i=0;i<4;i++)
#pragma unroll
      for(int j=0;j<4;j++)
        acc[i][j] = __builtin_amdgcn_mfma_f32_16x16x32_bf16(af[i], bf[j], acc[i][j], 0,0,0);
  }
#pragma unroll
  for(int i=0;i<4;i++){
    int mb = bm + wm + i*16 + fq*4;
#pragma unroll
    for(int j=0;j<4;j++){
      int n = bn + wn + j*16 + fr;
      float* dst = C + (size_t)mb*HIDDEN + n;
#pragma unroll
      for(int r=0;r<4;r++) dst[(size_t)r*HIDDEN] = acc[i][j][r];
    }
  }
}

// ---------------- gate: sigmoid(hs @ Wg + bg), (2048 x 48) ----------------
__global__ __launch_bounds__(256) void gate_kernel(
    const float* __restrict__ hs, const float* __restrict__ Wg, const float* __restrict__ bg,
    float* __restrict__ gatep)
{
  int t = blockIdx.x;
  __shared__ float row[1024];
  __shared__ float red[4][64];
  int tid = threadIdx.x;
  *(float4*)(row + tid*4) = *(const float4*)(hs + (size_t)t*HIDDEN + tid*4);
  __syncthreads();
  int n = tid & 63, part = tid>>6;
  float s = 0.f;
  if(n < 48){
    const float* w = Wg + n;
    for(int kx = part*256; kx < part*256+256; kx++)
      s += row[kx]*w[(size_t)kx*48];
  }
  red[part][n] = s;
  __syncthreads();
  if(part==0 && n<48){
    float x = red[0][n]+red[1][n]+red[2][n]+red[3][n] + bg[n];
    gatep[(size_t)t*48 + n] = 1.f/(1.f+expf(-x));
  }
}

// ---------------- compress MLP: gelu(k_blk @ Wc + bc) ----------------
__global__ __launch_bounds__(256) void compress_kernel(
    const float* __restrict__ kbuf, const float* __restrict__ vbuf,
    const float* __restrict__ Wc, const float* __restrict__ bcp,
    float* __restrict__ kc, float* __restrict__ vc)
{
  int hb = blockIdx.x; int h = hb>>5, i = hb&31;
  __shared__ float inK[4096], inV[4096];
  int tid = threadIdx.x;
  const float4* sk = (const float4*)(kbuf + ((size_t)h*TT + i*64)*HD);
  const float4* sv = (const float4*)(vbuf + ((size_t)h*TT + i*64)*HD);
  float4* dK=(float4*)inK; float4* dV=(float4*)inV;
#pragma unroll
  for(int u=0;u<4;u++){ dK[tid+256*u]=sk[tid+256*u]; dV[tid+256*u]=sv[tid+256*u]; }
  __syncthreads();
  int d = tid&63, part = tid>>6;
  float sK=0.f, sV=0.f;
  const float* w = Wc + d;
  for(int idx = part*1024; idx < part*1024+1024; idx++){
    float wv = w[(size_t)idx*HD];
    sK += inK[idx]*wv; sV += inV[idx]*wv;
  }
  __shared__ float redK[4][64], redV[4][64];
  redK[part][d]=sK; redV[part][d]=sV;
  __syncthreads();
  if(part==0){
    float xK = redK[0][d]+redK[1][d]+redK[2][d]+redK[3][d] + bcp[d];
    float xV = redV[0][d]+redV[1][d]+redV[2][d]+redV[3][d] + bcp[d];
    kc[((size_t)h*NB+i)*HD + d] = 0.5f*xK*(1.f+erff(xK*0.70710678118654752f));
    vc[((size_t)h*NB+i)*HD + d] = 0.5f*xV*(1.f+erff(xV*0.70710678118654752f));
  }
}

// ---------------- compressed attention: importance + softmax + comp_out ----------------
__global__ __launch_bounds__(256) void comp_attn(
    const float* __restrict__ q, const float* __restrict__ kcb, const float* __restrict__ vcb,
    float* __restrict__ imp, float* __restrict__ comp)
{
  __shared__ float qls[4][64];
  __shared__ float pls[4][64];
  int tid=threadIdx.x;
  int wave = tid>>6, lane = tid&63;
  int idx = blockIdx.x*4 + wave;
  int h = idx>>11, t = idx & 2047;
  qls[wave][lane] = q[((size_t)h*TT + t)*HD + lane];
  __syncthreads();
  if(lane<32){
    const float* kr = kcb + ((size_t)h*NB + lane)*HD;
    float s=0.f;
#pragma unroll
    for(int d=0; d<64; d++) s += qls[wave][d]*kr[d];
    s *= 0.125f;
    imp[((size_t)h*TT + t)*NB + lane] = s;
    float m = rmax32(s);
    float e = __expf(s-m);
    float l = rsum32(e);
    pls[wave][lane] = e/l;
  }
  __syncthreads();
  const float* vbh = vcb + (size_t)h*NB*HD;
  float o=0.f;
#pragma unroll
  for(int j=0;j<32;j++) o += pls[wave][j]*vbh[j*HD + lane];
  comp[((size_t)h*TT + t)*HD + lane] = o;
}

// ---------------- block scores -> entropy -> dynamic_k -> top-k mask ----------------
__global__ __launch_bounds__(256) void block_stats(
    const float* __restrict__ imp, const float* __restrict__ ksc, const float* __restrict__ kbi,
    unsigned* __restrict__ maskb, float* __restrict__ dkf,
    float* __restrict__ out_kratio, float* __restrict__ out_nent)
{
  int hb = blockIdx.x; int h = hb>>5, i = hb&31;
  int tid = threadIdx.x; int j = tid&31, p = tid>>5;
  const float* base = imp + ((size_t)h*TT + i*64)*NB;
  float s = 0.f;
  for(int t2=p*8; t2<p*8+8; t2++) s += base[(size_t)t2*NB + j];
  __shared__ float red[8][32];
  red[p][j] = s;
  __syncthreads();
  if(tid < 32){
    float bs = 0.f;
#pragma unroll
    for(int pp=0; pp<8; pp++) bs += red[pp][j];
    bs *= (1.f/64.f);
    float m = rmax32(bs);
    float e = expf(bs - m);
    float se = rsum32(e);
    float prob = e/se;
    float ent = rsum32(-prob * logf(prob + 1e-9f));
    float nent = ent / (3.4657359027997265f + 1e-9f);
    float kl = ksc[h]*nent + kbi[h];
    float kr = 1.f/(1.f + expf(-kl));
    float dkfl = fminf(fmaxf(8.f*kr, 1.f), 8.f);
    int dk = (int)dkfl;
    unsigned sel = 0u;
    for(int r=0;r<dk;r++){
      bool unpicked = ((sel>>j)&1u)==0u;
      float cand = unpicked ? bs : -3.4e38f;
      float mx = rmax32(cand);
      unsigned long long b = __ballot(cand == mx);
      int idxsel = __ffsll(b & 0xffffffffull) - 1;
      sel |= (1u<<idxsel);
    }
    sel |= (1u<<i);
    if(j==0){
      maskb[hb] = sel;
      dkf[hb] = (float)dk;
      out_kratio[hb] = kr;
      out_nent[hb] = nent;
    }
  }
}

// ---------------- avg_k reduction ----------------
__global__ __launch_bounds__(256) void avgk_kernel(const float* __restrict__ dkf, float* __restrict__ outp){
  __shared__ float red[256];
  int tid=threadIdx.x;
  red[tid] = dkf[tid] + dkf[tid+256];
  __syncthreads();
  for(int s=128;s>0;s>>=1){ if(tid<s) red[tid]+=red[tid+s]; __syncthreads(); }
  if(tid==0) outp[0] = red[0] * (1.f/512.f);
}

// ---------------- MFMA block-sparse flash attention ----------------
// S^T = K·Q^T per wave (A=K[m=key][k=d], B=Q[n=query][k=d]); softmax over keys
// reduces over M (in-register + shfl_xor 16/32). P^T(C-layout) -> P(A-layout)
// transpose happens in the scalar LDS writes. PV: A=P[m=q][k=key], B=V^T[d][key].
__global__ __launch_bounds__(256) void attn_mfma(
    const unsigned short* __restrict__ qbh, const unsigned short* __restrict__ kbh,
    const unsigned short* __restrict__ vth,
    const unsigned* __restrict__ maskb, float* __restrict__ outp, int causal_local)
{
  __shared__ unsigned short Kb[64*72];   // [key][d], row stride 72 shorts (2-way bank = free)
  __shared__ unsigned short Vt[64*72];   // [d][key]
  __shared__ unsigned short Pl[4*16*72]; // per-wave P[q][key]
  int tid = threadIdx.x;
  int wave = __builtin_amdgcn_readfirstlane(tid>>6);
  int ln = tid & 63;
  int fr = ln & 15, fq = ln >> 4;
  int hb = blockIdx.x; int h = hb>>5, i = hb&31;
  unsigned mb = causal_local ? ((1u<<i) | (i ? (1u<<(i-1)) : 0u)) : maskb[hb];

  // Q fragment (B operand): n=query=fr, k=d=fq*8+j (+32*ks)
  const unsigned short* qrow = qbh + ((size_t)h*TT + i*64 + wave*16 + fr)*HD + fq*8;
  s8v bq0 = *(const s8v*)(qrow);
  s8v bq1 = *(const s8v*)(qrow + 32);

  f4v acc_o[4] = {};      // O[q][d] C-layout: row=query=fq*4+r, col=d=nt*16+fr
  float m_run = -3.4e38f; // softmax state for query q=fr (replicated over fq)
  float l_run = 0.f;

  int srow = tid>>2, sg = (tid&3)*16;   // staging split
  unsigned short* Pw = Pl + wave*16*72;

  for(int j=0;j<NB;j++){
    if(!((mb>>j)&1u)) continue;
    __syncthreads();   // prior iteration's LDS reads done
    {
      const unsigned short* ks_ = kbh + ((size_t)h*TT + j*64 + srow)*HD + sg;
      *(s8v*)&Kb[srow*72 + sg]     = *(const s8v*)(ks_);
      *(s8v*)&Kb[srow*72 + sg + 8] = *(const s8v*)(ks_ + 8);
      const unsigned short* vs_ = vth + ((size_t)h*HD + srow)*TT + j*64 + sg;
      *(s8v*)&Vt[srow*72 + sg]     = *(const s8v*)(vs_);
      *(s8v*)&Vt[srow*72 + sg + 8] = *(const s8v*)(vs_ + 8);
    }
    __syncthreads();   // staging visible

    // S^T: per wave 4 m-tiles (keys) x 16 queries, K contraction over d
    f4v sv[4] = {};
#pragma unroll
    for(int mt=0;mt<4;mt++){
      s8v ak0 = *(const s8v*)&Kb[(mt*16+fr)*72 + fq*8];
      s8v ak1 = *(const s8v*)&Kb[(mt*16+fr)*72 + fq*8 + 32];
      sv[mt] = __builtin_amdgcn_mfma_f32_16x16x32_bf16(ak0, bq0, sv[mt], 0,0,0);
      sv[mt] = __builtin_amdgcn_mfma_f32_16x16x32_bf16(ak1, bq1, sv[mt], 0,0,0);
    }
    bool diag = (causal_local!=0) && (j==i);
    int qpos = wave*16 + fr;
#pragma unroll
    for(int mt=0;mt<4;mt++){
#pragma unroll
      for(int r=0;r<4;r++){
        float s = sv[mt][r]*0.125f;
        if(diag && (mt*16 + fq*4 + r) > qpos) s = -3.4e38f;
        sv[mt][r] = s;
      }
    }
    // column(=query) softmax: reduce over keys (regs + fq groups)
    float mx = -3.4e38f;
#pragma unroll
    for(int mt=0;mt<4;mt++)
#pragma unroll
      for(int r=0;r<4;r++) mx = fmaxf(mx, sv[mt][r]);
    mx = fmaxf(mx, __shfl_xor(mx,16,64));
    mx = fmaxf(mx, __shfl_xor(mx,32,64));
    float mnew = fmaxf(m_run, mx);
    float es = 0.f;
#pragma unroll
    for(int mt=0;mt<4;mt++)
#pragma unroll
      for(int r=0;r<4;r++){
        float p = __expf(sv[mt][r] - mnew);
        es += p;
        Pw[fr*72 + mt*16 + fq*4 + r] = f2bf(p);   // transpose to P[q][key]
      }
    es += __shfl_xor(es,16,64);
    es += __shfl_xor(es,32,64);
    float alpha = __expf(m_run - mnew);
    l_run = l_run*alpha + es;
    m_run = mnew;
    // broadcast alpha (fr-indexed) to O rows (fq*4+r indexed)
    float av[4];
#pragma unroll
    for(int r=0;r<4;r++) av[r] = __shfl(alpha, fq*4+r, 64);
#pragma unroll
    for(int nt=0;nt<4;nt++)
#pragma unroll
      for(int r=0;r<4;r++) acc_o[nt][r] *= av[r];
    __syncthreads();   // P writes drained

    // PV: A=P[m=q][k=key] from LDS, B=V^T[n=d][k=key]
    s8v ap0 = *(const s8v*)&Pw[fr*72 + fq*8];
    s8v ap1 = *(const s8v*)&Pw[fr*72 + fq*8 + 32];
#pragma unroll
    for(int nt=0;nt<4;nt++){
      s8v bv0 = *(const s8v*)&Vt[(nt*16+fr)*72 + fq*8];
      s8v bv1 = *(const s8v*)&Vt[(nt*16+fr)*72 + fq*8 + 32];
      acc_o[nt] = __builtin_amdgcn_mfma_f32_16x16x32_bf16(ap0, bv0, acc_o[nt], 0,0,0);
      acc_o[nt] = __builtin_amdgcn_mfma_f32_16x16x32_bf16(ap1, bv1, acc_o[nt], 0,0,0);
    }
  }
  float lv[4];
#pragma unroll
  for(int r=0;r<4;r++) lv[r] = __shfl(l_run, fq*4+r, 64);
#pragma unroll
  for(int nt=0;nt<4;nt++){
#pragma unroll
    for(int r=0;r<4;r++){
      int t = i*64 + wave*16 + fq*4 + r;
      int d = nt*16 + fr;
      outp[((size_t)h*TT + t)*HD + d] = acc_o[nt][r] / lv[r];
    }
  }
}

// ---------------- gated combine -> merged bf16 (t, h*64+d) ----------------
__global__ __launch_bounds__(256) void combine_kernel(
    const float* __restrict__ swo, const float* __restrict__ comp, const float* __restrict__ fino,
    const float* __restrict__ gatep, unsigned short* __restrict__ mergedh)
{
  int idx = blockIdx.x*256 + threadIdx.x;
  int t = idx>>10, c = idx & 1023;
  int h = c>>6, d = c&63;
  const float* g = gatep + (size_t)t*48 + h*3;
  size_t a = ((size_t)h*TT + t)*HD + d;
  mergedh[idx] = f2bf(g[0]*swo[a] + g[1]*comp[a] + g[2]*fino[a]);
}

extern "C" void kernel_launch(void* const* d_in, const int* in_sizes, int n_in,
                              void* d_out, int out_size, void* d_ws, size_t ws_size,
                              hipStream_t stream) {
  (void)in_sizes; (void)n_in; (void)out_size; (void)ws_size;
  const float* hs  = (const float*)d_in[0];
  const float* Wq  = (const float*)d_in[1];
  const float* Wk  = (const float*)d_in[2];
  const float* Wv  = (const float*)d_in[3];
  const float* Wo  = (const float*)d_in[4];
  const float* Wc  = (const float*)d_in[5];
  const float* bcp = (const float*)d_in[6];
  const float* ksc = (const float*)d_in[7];
  const float* kbi = (const float*)d_in[8];
  const float* Wg  = (const float*)d_in[9];
  const float* bg  = (const float*)d_in[10];
  float* out = (float*)d_out;

  float* ws = (float*)d_ws;
  float* qb     = ws;                   // 2097152
  float* kb     = qb + 2097152;
  float* vb     = kb + 2097152;
  float* gatep  = vb + 2097152;         // 98304
  float* kc     = gatep + 98304;        // 32768
  float* vc     = kc + 32768;           // 32768
  float* imp    = vc + 32768;           // 1048576
  float* comp   = imp + 1048576;        // 2097152  (hsh/hsl alias)
  float* swo    = comp + 2097152;       // 2097152  (wth alias)
  float* fino   = swo + 2097152;        // 2097152  (wtl alias)
  unsigned short* mergedh = (unsigned short*)(fino + 2097152);   // 1048576 floats
  float* dkf    = fino + 2097152 + 1048576;   // 512
  unsigned* maskb = (unsigned*)(dkf + 512);   // 512
  unsigned short* woth = (unsigned short*)(dkf + 1024);          // 524288 floats
  unsigned short* qbh = (unsigned short*)(dkf + 1024 + 524288);  // 1048576 floats
  unsigned short* kbh = qbh + 2097152;                           // 1048576 floats
  unsigned short* vth = kbh + 2097152;                           // 1048576 floats

  unsigned short* hsh = (unsigned short*)comp;
  unsigned short* hsl = (unsigned short*)(comp + 1048576);
  unsigned short* wth = (unsigned short*)swo;
  unsigned short* wtl = (unsigned short*)(swo + 1572864);

  float* out_avgk   = out + 2097152;
  float* out_kratio = out + 2097153;
  float* out_nent   = out + 2097665;

  split_hs_k<<<dim3(2048), 256, 0, stream>>>(hs, hsh, hsl);
  prep_w_k<<<dim3(16,16,4), 256, 0, stream>>>(Wq, Wk, Wv, Wo, wth, wtl, woth);
  mfma_qkv_k<<<dim3(24,16), 256, 0, stream>>>(hsh, hsl, wth, wtl, qb, kb, vb);
  conv_qk<<<dim3(1024,2), 256, 0, stream>>>(qb, kb, qbh, kbh);
  conv_vt<<<dim3(32,16), 256, 0, stream>>>(vb, vth);
  gate_kernel<<<dim3(2048), 256, 0, stream>>>(hs, Wg, bg, gatep);
  compress_kernel<<<dim3(512), 256, 0, stream>>>(kb, vb, Wc, bcp, kc, vc);
  comp_attn<<<dim3(8192), 256, 0, stream>>>(qb, kc, vc, imp, comp);
  block_stats<<<dim3(512), 256, 0, stream>>>(imp, ksc, kbi, maskb, dkf, out_kratio, out_nent);
  avgk_kernel<<<dim3(1), 256, 0, stream>>>(dkf, out_avgk);
  attn_mfma<<<dim3(512), 256, 0, stream>>>(qbh, kbh, vth, maskb, swo, 1);
  attn_mfma<<<dim3(512), 256, 0, stream>>>(qbh, kbh, vth, maskb, fino, 0);
  combine_kernel<<<dim3(8192), 256, 0, stream>>>(swo, comp, fino, gatep, mergedh);
  mfma_proj_k<<<dim3(8,16), 256, 0, stream>>>(mergedh, woth, out);
}

// Round 4
// 259.308 us; speedup vs baseline: 2.6096x; 1.2157x over previous
//
#include <hip/hip_runtime.h>
#include <math.h>

#define TT 2048
#define NH 16
#define HD 64
#define NB 32
#define HIDDEN 1024

typedef short s8v __attribute__((ext_vector_type(8)));
typedef float f4v __attribute__((ext_vector_type(4)));

// ---------------- bf16 helpers (header-independent, RNE) ----------------
__device__ __forceinline__ unsigned short f2bf(float x){
  unsigned u = __float_as_uint(x);
  unsigned r = (u + 0x7fffu + ((u>>16)&1u)) >> 16;
  return (unsigned short)r;
}
__device__ __forceinline__ float bf2f(unsigned short b){
  return __uint_as_float(((unsigned)b)<<16);
}
__device__ __forceinline__ void bsplit(float x, unsigned short& h, unsigned short& l){
  h = f2bf(x);
  l = f2bf(x - bf2f(h));
}

// ---------------- wave reductions ----------------
__device__ __forceinline__ float rmax32(float v){
#pragma unroll
  for(int o=16;o>0;o>>=1) v = fmaxf(v, __shfl_xor(v,o,32));
  return v;
}
__device__ __forceinline__ float rsum32(float v){
#pragma unroll
  for(int o=16;o>0;o>>=1) v += __shfl_xor(v,o,32);
  return v;
}

// ---------------- split hs -> bf16 hi/lo ----------------
__global__ __launch_bounds__(256) void split_hs_k(
    const float* __restrict__ hs, unsigned short* __restrict__ hh, unsigned short* __restrict__ hl)
{
  int i = (blockIdx.x*256 + threadIdx.x)*4;
  float4 x = *(const float4*)(hs + i);
  ushort4 hv, lv;
  bsplit(x.x, hv.x, lv.x); bsplit(x.y, hv.y, lv.y);
  bsplit(x.z, hv.z, lv.z); bsplit(x.w, hv.w, lv.w);
  *(ushort4*)(hh + i) = hv;
  *(ushort4*)(hl + i) = lv;
}

// ---------------- transpose + split weights: W[k][n] -> WT[n][k] bf16 hi/lo ----------------
__global__ __launch_bounds__(256) void prep_w_k(
    const float* __restrict__ Wq, const float* __restrict__ Wk,
    const float* __restrict__ Wv, const float* __restrict__ Wo,
    unsigned short* __restrict__ wth, unsigned short* __restrict__ wtl,
    unsigned short* __restrict__ woth)
{
  int z = blockIdx.z;
  const float* W = (z==0)?Wq:((z==1)?Wk:((z==2)?Wv:Wo));
  int k0 = blockIdx.y*64, n0 = blockIdx.x*64;
  __shared__ float L[64][68];
  int t = threadIdx.x;
  int rr = t>>2, cg = t&3;
  const float* src = W + (size_t)(k0+rr)*1024 + n0 + cg*16;
  float4 a = *(const float4*)(src);
  float4 b = *(const float4*)(src+4);
  float4 c = *(const float4*)(src+8);
  float4 d = *(const float4*)(src+12);
  *(float4*)&L[rr][cg*16+0]  = a;
  *(float4*)&L[rr][cg*16+4]  = b;
  *(float4*)&L[rr][cg*16+8]  = c;
  *(float4*)&L[rr][cg*16+12] = d;
  __syncthreads();
  int nr = t>>2, kg = t&3;
  unsigned short hb[16], lb[16];
#pragma unroll
  for(int j=0;j<16;j++){
    float v = L[kg*16+j][nr];
    bsplit(v, hb[j], lb[j]);
  }
  if(z<3){
    size_t orow = ((size_t)z*1024 + n0 + nr)*1024 + k0 + kg*16;
    *(ushort4*)(wth+orow+0)  = make_ushort4(hb[0],hb[1],hb[2],hb[3]);
    *(ushort4*)(wth+orow+4)  = make_ushort4(hb[4],hb[5],hb[6],hb[7]);
    *(ushort4*)(wth+orow+8)  = make_ushort4(hb[8],hb[9],hb[10],hb[11]);
    *(ushort4*)(wth+orow+12) = make_ushort4(hb[12],hb[13],hb[14],hb[15]);
    *(ushort4*)(wtl+orow+0)  = make_ushort4(lb[0],lb[1],lb[2],lb[3]);
    *(ushort4*)(wtl+orow+4)  = make_ushort4(lb[4],lb[5],lb[6],lb[7]);
    *(ushort4*)(wtl+orow+8)  = make_ushort4(lb[8],lb[9],lb[10],lb[11]);
    *(ushort4*)(wtl+orow+12) = make_ushort4(lb[12],lb[13],lb[14],lb[15]);
  }else{
    size_t orow = ((size_t)n0 + nr)*1024 + k0 + kg*16;
    *(ushort4*)(woth+orow+0)  = make_ushort4(hb[0],hb[1],hb[2],hb[3]);
    *(ushort4*)(woth+orow+4)  = make_ushort4(hb[4],hb[5],hb[6],hb[7]);
    *(ushort4*)(woth+orow+8)  = make_ushort4(hb[8],hb[9],hb[10],hb[11]);
    *(ushort4*)(woth+orow+12) = make_ushort4(hb[12],hb[13],hb[14],hb[15]);
  }
}

// ---------------- transpose + split Wc: [4096][64] -> [64][4096] bf16 hi/lo ----------------
__global__ __launch_bounds__(256) void prep_wc_k(
    const float* __restrict__ Wc, unsigned short* __restrict__ wcth, unsigned short* __restrict__ wctl)
{
  int k0 = blockIdx.x*64;
  __shared__ float L[64][68];
  int t = threadIdx.x;
  int rr = t>>2, cg = t&3;
  const float* src = Wc + (size_t)(k0+rr)*64 + cg*16;
  float4 a = *(const float4*)(src);
  float4 b = *(const float4*)(src+4);
  float4 c = *(const float4*)(src+8);
  float4 d = *(const float4*)(src+12);
  *(float4*)&L[rr][cg*16+0]  = a;
  *(float4*)&L[rr][cg*16+4]  = b;
  *(float4*)&L[rr][cg*16+8]  = c;
  *(float4*)&L[rr][cg*16+12] = d;
  __syncthreads();
  int nr = t>>2, kg = t&3;
  unsigned short hb[16], lb[16];
#pragma unroll
  for(int j=0;j<16;j++){
    float v = L[kg*16+j][nr];
    bsplit(v, hb[j], lb[j]);
  }
  size_t orow = (size_t)nr*4096 + k0 + kg*16;
  *(ushort4*)(wcth+orow+0)  = make_ushort4(hb[0],hb[1],hb[2],hb[3]);
  *(ushort4*)(wcth+orow+4)  = make_ushort4(hb[4],hb[5],hb[6],hb[7]);
  *(ushort4*)(wcth+orow+8)  = make_ushort4(hb[8],hb[9],hb[10],hb[11]);
  *(ushort4*)(wcth+orow+12) = make_ushort4(hb[12],hb[13],hb[14],hb[15]);
  *(ushort4*)(wctl+orow+0)  = make_ushort4(lb[0],lb[1],lb[2],lb[3]);
  *(ushort4*)(wctl+orow+4)  = make_ushort4(lb[4],lb[5],lb[6],lb[7]);
  *(ushort4*)(wctl+orow+8)  = make_ushort4(lb[8],lb[9],lb[10],lb[11]);
  *(ushort4*)(wctl+orow+12) = make_ushort4(lb[12],lb[13],lb[14],lb[15]);
}

// ---------------- QKV MFMA GEMM (split-bf16 3-pass for Q,K; 1-pass for V) ----------------
#define LROW 40
__global__ __launch_bounds__(256) void mfma_qkv_k(
    const unsigned short* __restrict__ ahg, const unsigned short* __restrict__ alg,
    const unsigned short* __restrict__ bhg, const unsigned short* __restrict__ blg,
    float* __restrict__ C0, float* __restrict__ C1, float* __restrict__ C2)
{
  __shared__ unsigned short Ah[128*LROW], Al[128*LROW], Bh[128*LROW], Bl[128*LROW];
  int tid = threadIdx.x;
  int bn = blockIdx.x*128, bm = blockIdx.y*128;
  bool tp = (blockIdx.x < 16);
  int sr = tid>>2, skg = tid&3;
  const unsigned short* gA  = ahg + (size_t)(bm+sr)*HIDDEN + skg*8;
  const unsigned short* gAl = alg + (size_t)(bm+sr)*HIDDEN + skg*8;
  const unsigned short* gB  = bhg + (size_t)(bn+sr)*HIDDEN + skg*8;
  const unsigned short* gBl = blg + (size_t)(bn+sr)*HIDDEN + skg*8;
  int wv = tid>>6, ln = tid&63;
  int wm = (wv&1)*64, wn = (wv>>1)*64;
  int fr = ln&15, fq = ln>>4;
  int wlds = sr*LROW + skg*8;
  f4v acc[4][4] = {};
  for(int k0=0;k0<HIDDEN;k0+=32){
    s8v a0 = *(const s8v*)(gA + k0);
    s8v a1 = *(const s8v*)(gA + 65536 + k0);
    s8v b0 = *(const s8v*)(gB + k0);
    s8v b1 = *(const s8v*)(gB + 65536 + k0);
    s8v a0l, a1l, b0l, b1l;
    if(tp){
      a0l = *(const s8v*)(gAl + k0);
      a1l = *(const s8v*)(gAl + 65536 + k0);
      b0l = *(const s8v*)(gBl + k0);
      b1l = *(const s8v*)(gBl + 65536 + k0);
    }
    __syncthreads();
    *(s8v*)&Ah[wlds] = a0; *(s8v*)&Ah[wlds + 64*LROW] = a1;
    *(s8v*)&Bh[wlds] = b0; *(s8v*)&Bh[wlds + 64*LROW] = b1;
    if(tp){
      *(s8v*)&Al[wlds] = a0l; *(s8v*)&Al[wlds + 64*LROW] = a1l;
      *(s8v*)&Bl[wlds] = b0l; *(s8v*)&Bl[wlds + 64*LROW] = b1l;
    }
    __syncthreads();
    s8v af[4], bf[4], tf;
#pragma unroll
    for(int i=0;i<4;i++) af[i] = *(const s8v*)&Ah[(wm+i*16+fr)*LROW + fq*8];
#pragma unroll
    for(int i=0;i<4;i++) bf[i] = *(const s8v*)&Bh[(wn+i*16+fr)*LROW + fq*8];
#pragma unroll
    for(int i=0;i<4;i++)
#pragma unroll
      for(int j=0;j<4;j++)
        acc[i][j] = __builtin_amdgcn_mfma_f32_16x16x32_bf16(af[i], bf[j], acc[i][j], 0,0,0);
    if(tp){
#pragma unroll
      for(int i=0;i<4;i++){
        tf = *(const s8v*)&Al[(wm+i*16+fr)*LROW + fq*8];
#pragma unroll
        for(int j=0;j<4;j++)
          acc[i][j] = __builtin_amdgcn_mfma_f32_16x16x32_bf16(tf, bf[j], acc[i][j], 0,0,0);
      }
#pragma unroll
      for(int j=0;j<4;j++){
        tf = *(const s8v*)&Bl[(wn+j*16+fr)*LROW + fq*8];
#pragma unroll
        for(int i=0;i<4;i++)
          acc[i][j] = __builtin_amdgcn_mfma_f32_16x16x32_bf16(af[i], tf, acc[i][j], 0,0,0);
      }
    }
  }
  int z = bn >> 10;
  float* C = (z==0)?C0:((z==1)?C1:C2);
#pragma unroll
  for(int i=0;i<4;i++){
    int mb = bm + wm + i*16 + fq*4;
#pragma unroll
    for(int j=0;j<4;j++){
      int n = bn + wn + j*16 + fr;
      int n1 = n & 1023, hd = n1>>6, d = n1&63;
      float* dst = C + ((size_t)hd*TT + mb)*HD + d;
#pragma unroll
      for(int r=0;r<4;r++) dst[(size_t)r*HD] = acc[i][j][r];
    }
  }
}

// ---------------- fp32 q/k/v -> bf16 [h][t][d]; lo parts for q,k ----------------
__global__ __launch_bounds__(256) void conv_qkv(
    const float* __restrict__ qb, const float* __restrict__ kb, const float* __restrict__ vb,
    unsigned short* __restrict__ qbh, unsigned short* __restrict__ qbl,
    unsigned short* __restrict__ kbh, unsigned short* __restrict__ kbl,
    unsigned short* __restrict__ vbh)
{
  int z = blockIdx.y;
  const float* s = (z==0)?qb:((z==1)?kb:vb);
  unsigned short* dh = (z==0)?qbh:((z==1)?kbh:vbh);
  unsigned short* dl = (z==0)?qbl:kbl;
  size_t i = ((size_t)blockIdx.x*256 + threadIdx.x)*8;
  float4 a = *(const float4*)(s+i);
  float4 b = *(const float4*)(s+i+4);
  float xs[8] = {a.x,a.y,a.z,a.w,b.x,b.y,b.z,b.w};
  s8v rh, rl;
#pragma unroll
  for(int u=0;u<8;u++){
    unsigned short h = f2bf(xs[u]);
    rh[u] = (short)h;
    rl[u] = (short)f2bf(xs[u] - bf2f(h));
  }
  *(s8v*)(dh+i) = rh;
  if(z<2) *(s8v*)(dl+i) = rl;
}

// ---------------- fp32 v [h][t][d] -> bf16 v^T [h][d][t] ----------------
__global__ __launch_bounds__(256) void conv_vt(
    const float* __restrict__ vb, unsigned short* __restrict__ vth)
{
  int tt = blockIdx.x, h = blockIdx.y;
  __shared__ float L[64][68];
  int t = threadIdx.x;
  int row = t>>2, dg = (t&3)*16;
  const float* src = vb + ((size_t)h*TT + tt*64 + row)*HD + dg;
  float4 a = *(const float4*)(src);
  float4 b = *(const float4*)(src+4);
  float4 c = *(const float4*)(src+8);
  float4 e = *(const float4*)(src+12);
  *(float4*)&L[row][dg+0]  = a;
  *(float4*)&L[row][dg+4]  = b;
  *(float4*)&L[row][dg+8]  = c;
  *(float4*)&L[row][dg+12] = e;
  __syncthreads();
  int d = t>>2, kg = (t&3)*16;
  s8v r0, r1;
#pragma unroll
  for(int u=0;u<8;u++)  r0[u] = (short)f2bf(L[kg+u][d]);
#pragma unroll
  for(int u=0;u<8;u++)  r1[u] = (short)f2bf(L[kg+8+u][d]);
  unsigned short* dst = vth + ((size_t)h*HD + d)*TT + tt*64 + kg;
  *(s8v*)(dst)   = r0;
  *(s8v*)(dst+8) = r1;
}

// ---------------- compress MFMA GEMM: [kblk;vblk](1024x4096) @ WcT, split-K ----------------
// grid (8 kchunks, 16 mtiles); mt<8 = k rows (3-pass), else v rows (2-pass).
#define CROW 40
__global__ __launch_bounds__(256) void mfma_compress_k(
    const unsigned short* __restrict__ kbh, const unsigned short* __restrict__ kbl,
    const unsigned short* __restrict__ vbh,
    const unsigned short* __restrict__ wcth, const unsigned short* __restrict__ wctl,
    float* __restrict__ ccpart)
{
  __shared__ unsigned short As[64*CROW], Al[64*CROW], Bs[64*CROW], Bl[64*CROW];
  int chunk = blockIdx.x;
  int mt = blockIdx.y;
  bool isK = (mt < 8);
  const unsigned short* Ag  = isK ? (kbh + (size_t)mt*262144) : (vbh + (size_t)(mt-8)*262144);
  const unsigned short* Agl = kbl + (size_t)(isK ? mt : 0)*262144;
  int tid = threadIdx.x;
  int sr = tid>>2, skg = (tid&3)*8;
  int k0b = chunk*512;
  const unsigned short* gA  = Ag  + (size_t)sr*4096 + k0b + skg;
  const unsigned short* gAl = Agl + (size_t)sr*4096 + k0b + skg;
  const unsigned short* gB  = wcth + (size_t)sr*4096 + k0b + skg;
  const unsigned short* gBl = wctl + (size_t)sr*4096 + k0b + skg;
  int wv = tid>>6, ln = tid&63;
  int fr = ln&15, fq = ln>>4;
  int wlds = sr*CROW + skg;
  f4v acc[4] = {};
  for(int ks=0; ks<512; ks+=32){
    s8v a0 = *(const s8v*)(gA + ks);
    s8v b0 = *(const s8v*)(gB + ks);
    s8v b1 = *(const s8v*)(gBl + ks);
    s8v a1 = {};
    if(isK) a1 = *(const s8v*)(gAl + ks);
    __syncthreads();
    *(s8v*)&As[wlds] = a0;
    *(s8v*)&Bs[wlds] = b0;
    *(s8v*)&Bl[wlds] = b1;
    if(isK) *(s8v*)&Al[wlds] = a1;
    __syncthreads();
    s8v bfh = *(const s8v*)&Bs[(wv*16+fr)*CROW + fq*8];
    s8v bfl = *(const s8v*)&Bl[(wv*16+fr)*CROW + fq*8];
#pragma unroll
    for(int m=0;m<4;m++){
      s8v af = *(const s8v*)&As[(m*16+fr)*CROW + fq*8];
      acc[m] = __builtin_amdgcn_mfma_f32_16x16x32_bf16(af, bfh, acc[m], 0,0,0);
      acc[m] = __builtin_amdgcn_mfma_f32_16x16x32_bf16(af, bfl, acc[m], 0,0,0);
      if(isK){
        s8v afl = *(const s8v*)&Al[(m*16+fr)*CROW + fq*8];
        acc[m] = __builtin_amdgcn_mfma_f32_16x16x32_bf16(afl, bfh, acc[m], 0,0,0);
      }
    }
  }
  float* dst = ccpart + ((size_t)chunk*1024 + mt*64)*64;
#pragma unroll
  for(int m=0;m<4;m++)
#pragma unroll
    for(int r=0;r<4;r++)
      dst[(size_t)(m*16+fq*4+r)*64 + wv*16 + fr] = acc[m][r];
}

// ---------------- reduce partials + bias + gelu -> kc split bf16, vc^T bf16 ----------------
__global__ __launch_bounds__(256) void compress_fin(
    const float* __restrict__ ccpart, const float* __restrict__ bcp,
    unsigned short* __restrict__ kch, unsigned short* __restrict__ kcl,
    unsigned short* __restrict__ vcth)
{
  int idx = blockIdx.x*256 + threadIdx.x;   // 65536
  int row = idx>>6, col = idx&63;
  float s = 0.f;
#pragma unroll
  for(int c=0;c<8;c++) s += ccpart[(size_t)c*65536 + idx];
  s += bcp[col];
  float g = 0.5f*s*(1.f+erff(s*0.70710678118654752f));
  if(row < 512){
    unsigned short hi = f2bf(g);
    kch[idx] = hi;
    kcl[idx] = f2bf(g - bf2f(hi));
  }else{
    int r = row - 512;
    int h = r>>5, j = r&31;
    vcth[((size_t)h*64 + col)*32 + j] = f2bf(g);
  }
}

// ---------------- compressed attention via MFMA: imp + softmax + comp_out ----------------
// grid (32 qtiles, 16 heads). S^T = kc·Q^T (3-pass split), softmax over 32 keys in regs,
// P via per-wave LDS (no barrier), PV single K=32 MFMA step vs vc^T.
__global__ __launch_bounds__(256) void comp_attn_mfma(
    const unsigned short* __restrict__ qbh, const unsigned short* __restrict__ qbl,
    const unsigned short* __restrict__ kch, const unsigned short* __restrict__ kcl,
    const unsigned short* __restrict__ vcth,
    float* __restrict__ imp, float* __restrict__ comp)
{
  __shared__ unsigned short Pl[4*16*40];
  int tid = threadIdx.x;
  int wave = __builtin_amdgcn_readfirstlane(tid>>6);
  int ln = tid&63;
  int fr = ln&15, fq = ln>>4;
  int i = blockIdx.x, h = blockIdx.y;

  const unsigned short* qrh = qbh + ((size_t)h*TT + i*64 + wave*16 + fr)*HD + fq*8;
  const unsigned short* qrl = qbl + ((size_t)h*TT + i*64 + wave*16 + fr)*HD + fq*8;
  s8v bh0 = *(const s8v*)(qrh);
  s8v bh1 = *(const s8v*)(qrh + 32);
  s8v bl0 = *(const s8v*)(qrl);
  s8v bl1 = *(const s8v*)(qrl + 32);

  f4v sv[2] = {};
#pragma unroll
  for(int mt=0;mt<2;mt++){
    const unsigned short* ar = kch + ((size_t)h*32 + mt*16 + fr)*HD + fq*8;
    const unsigned short* al = kcl + ((size_t)h*32 + mt*16 + fr)*HD + fq*8;
    s8v ah0 = *(const s8v*)(ar);
    s8v ah1 = *(const s8v*)(ar + 32);
    s8v al0 = *(const s8v*)(al);
    s8v al1 = *(const s8v*)(al + 32);
    sv[mt] = __builtin_amdgcn_mfma_f32_16x16x32_bf16(ah0, bh0, sv[mt], 0,0,0);
    sv[mt] = __builtin_amdgcn_mfma_f32_16x16x32_bf16(ah1, bh1, sv[mt], 0,0,0);
    sv[mt] = __builtin_amdgcn_mfma_f32_16x16x32_bf16(al0, bh0, sv[mt], 0,0,0);
    sv[mt] = __builtin_amdgcn_mfma_f32_16x16x32_bf16(al1, bh1, sv[mt], 0,0,0);
    sv[mt] = __builtin_amdgcn_mfma_f32_16x16x32_bf16(ah0, bl0, sv[mt], 0,0,0);
    sv[mt] = __builtin_amdgcn_mfma_f32_16x16x32_bf16(ah1, bl1, sv[mt], 0,0,0);
  }
  int t = i*64 + wave*16 + fr;
  float* impr = imp + ((size_t)h*TT + t)*NB;
  float mx = -3.4e38f;
#pragma unroll
  for(int mt=0;mt<2;mt++)
#pragma unroll
    for(int r=0;r<4;r++){
      float s = sv[mt][r]*0.125f;
      sv[mt][r] = s;
      impr[mt*16 + fq*4 + r] = s;
      mx = fmaxf(mx, s);
    }
  mx = fmaxf(mx, __shfl_xor(mx,16,64));
  mx = fmaxf(mx, __shfl_xor(mx,32,64));
  unsigned short* Pw = Pl + wave*16*40;
  float es = 0.f;
#pragma unroll
  for(int mt=0;mt<2;mt++)
#pragma unroll
    for(int r=0;r<4;r++){
      float p = __expf(sv[mt][r] - mx);
      es += p;
      Pw[fr*40 + mt*16 + fq*4 + r] = f2bf(p);
    }
  es += __shfl_xor(es,16,64);
  es += __shfl_xor(es,32,64);

  s8v ap = *(const s8v*)&Pw[fr*40 + fq*8];
  f4v acc[4] = {};
#pragma unroll
  for(int nt=0;nt<4;nt++){
    s8v bv = *(const s8v*)(vcth + ((size_t)h*64 + nt*16 + fr)*32 + fq*8);
    acc[nt] = __builtin_amdgcn_mfma_f32_16x16x32_bf16(ap, bv, acc[nt], 0,0,0);
  }
  float lv[4];
#pragma unroll
  for(int r=0;r<4;r++) lv[r] = __shfl(es, fq*4+r, 64);
#pragma unroll
  for(int nt=0;nt<4;nt++)
#pragma unroll
    for(int r=0;r<4;r++){
      int tq = i*64 + wave*16 + fq*4 + r;
      comp[((size_t)h*TT + tq)*HD + nt*16 + fr] = acc[nt][r]/lv[r];
    }
}

// ---------------- output projection MFMA GEMM ----------------
__global__ __launch_bounds__(256) void mfma_proj_k(
    const unsigned short* __restrict__ ahg, const unsigned short* __restrict__ bhg,
    float* __restrict__ C)
{
  __shared__ unsigned short Ah[128*LROW], Bh[128*LROW];
  int tid = threadIdx.x;
  int bn = blockIdx.x*128, bm = blockIdx.y*128;
  int sr = tid>>2, skg = tid&3;
  const unsigned short* gA = ahg + (size_t)(bm+sr)*HIDDEN + skg*8;
  const unsigned short* gB = bhg + (size_t)(bn+sr)*HIDDEN + skg*8;
  int wv = tid>>6, ln = tid&63;
  int wm = (wv&1)*64, wn = (wv>>1)*64;
  int fr = ln&15, fq = ln>>4;
  int wlds = sr*LROW + skg*8;
  f4v acc[4][4] = {};
  for(int k0=0;k0<HIDDEN;k0+=32){
    s8v a0 = *(const s8v*)(gA + k0);
    s8v a1 = *(const s8v*)(gA + 65536 + k0);
    s8v b0 = *(const s8v*)(gB + k0);
    s8v b1 = *(const s8v*)(gB + 65536 + k0);
    __syncthreads();
    *(s8v*)&Ah[wlds] = a0; *(s8v*)&Ah[wlds + 64*LROW] = a1;
    *(s8v*)&Bh[wlds] = b0; *(s8v*)&Bh[wlds + 64*LROW] = b1;
    __syncthreads();
    s8v af[4], bf[4];
#pragma unroll
    for(int i=0;i<4;i++) af[i] = *(const s8v*)&Ah[(wm+i*16+fr)*LROW + fq*8];
#pragma unroll
    for(int i=0;i<4;i++) bf[i] = *(const s8v*)&Bh[(wn+i*16+fr)*LROW + fq*8];
#pragma unroll
    for(int i=0;i<4;i++)
#pragma unroll
      for(int j=0;j<4;j++)
        acc[i][j] = __builtin_amdgcn_mfma_f32_16x16x32_bf16(af[i], bf[j], acc[i][j], 0,0,0);
  }
#pragma unroll
  for(int i=0;i<4;i++){
    int mb = bm + wm + i*16 + fq*4;
#pragma unroll
    for(int j=0;j<4;j++){
      int n = bn + wn + j*16 + fr;
      float* dst = C + (size_t)mb*HIDDEN + n;
#pragma unroll
      for(int r=0;r<4;r++) dst[(size_t)r*HIDDEN] = acc[i][j][r];
    }
  }
}

// ---------------- gate: sigmoid(hs @ Wg + bg), (2048 x 48) ----------------
__global__ __launch_bounds__(256) void gate_kernel(
    const float* __restrict__ hs, const float* __restrict__ Wg, const float* __restrict__ bg,
    float* __restrict__ gatep)
{
  int t = blockIdx.x;
  __shared__ float row[1024];
  __shared__ float red[4][64];
  int tid = threadIdx.x;
  *(float4*)(row + tid*4) = *(const float4*)(hs + (size_t)t*HIDDEN + tid*4);
  __syncthreads();
  int n = tid & 63, part = tid>>6;
  float s = 0.f;
  if(n < 48){
    const float* w = Wg + n;
    for(int kx = part*256; kx < part*256+256; kx++)
      s += row[kx]*w[(size_t)kx*48];
  }
  red[part][n] = s;
  __syncthreads();
  if(part==0 && n<48){
    float x = red[0][n]+red[1][n]+red[2][n]+red[3][n] + bg[n];
    gatep[(size_t)t*48 + n] = 1.f/(1.f+expf(-x));
  }
}

// ---------------- block scores -> entropy -> dynamic_k -> top-k mask ----------------
__global__ __launch_bounds__(256) void block_stats(
    const float* __restrict__ imp, const float* __restrict__ ksc, const float* __restrict__ kbi,
    unsigned* __restrict__ maskb, float* __restrict__ dkf,
    float* __restrict__ out_kratio, float* __restrict__ out_nent)
{
  int hb = blockIdx.x; int h = hb>>5, i = hb&31;
  int tid = threadIdx.x; int j = tid&31, p = tid>>5;
  const float* base = imp + ((size_t)h*TT + i*64)*NB;
  float s = 0.f;
  for(int t2=p*8; t2<p*8+8; t2++) s += base[(size_t)t2*NB + j];
  __shared__ float red[8][32];
  red[p][j] = s;
  __syncthreads();
  if(tid < 32){
    float bs = 0.f;
#pragma unroll
    for(int pp=0; pp<8; pp++) bs += red[pp][j];
    bs *= (1.f/64.f);
    float m = rmax32(bs);
    float e = expf(bs - m);
    float se = rsum32(e);
    float prob = e/se;
    float ent = rsum32(-prob * logf(prob + 1e-9f));
    float nent = ent / (3.4657359027997265f + 1e-9f);
    float kl = ksc[h]*nent + kbi[h];
    float kr = 1.f/(1.f + expf(-kl));
    float dkfl = fminf(fmaxf(8.f*kr, 1.f), 8.f);
    int dk = (int)dkfl;
    unsigned sel = 0u;
    for(int r=0;r<dk;r++){
      bool unpicked = ((sel>>j)&1u)==0u;
      float cand = unpicked ? bs : -3.4e38f;
      float mx = rmax32(cand);
      unsigned long long b = __ballot(cand == mx);
      int idxsel = __ffsll(b & 0xffffffffull) - 1;
      sel |= (1u<<idxsel);
    }
    sel |= (1u<<i);
    if(j==0){
      maskb[hb] = sel;
      dkf[hb] = (float)dk;
      out_kratio[hb] = kr;
      out_nent[hb] = nent;
    }
  }
}

// ---------------- avg_k reduction ----------------
__global__ __launch_bounds__(256) void avgk_kernel(const float* __restrict__ dkf, float* __restrict__ outp){
  __shared__ float red[256];
  int tid=threadIdx.x;
  red[tid] = dkf[tid] + dkf[tid+256];
  __syncthreads();
  for(int s=128;s>0;s>>=1){ if(tid<s) red[tid]+=red[tid+s]; __syncthreads(); }
  if(tid==0) outp[0] = red[0] * (1.f/512.f);
}

// ---------------- MFMA block-sparse flash attention ----------------
__global__ __launch_bounds__(256) void attn_mfma(
    const unsigned short* __restrict__ qbh, const unsigned short* __restrict__ kbh,
    const unsigned short* __restrict__ vth,
    const unsigned* __restrict__ maskb, float* __restrict__ outp, int causal_local)
{
  __shared__ unsigned short Kb[64*72];
  __shared__ unsigned short Vt[64*72];
  __shared__ unsigned short Pl[4*16*72];
  int tid = threadIdx.x;
  int wave = __builtin_amdgcn_readfirstlane(tid>>6);
  int ln = tid & 63;
  int fr = ln & 15, fq = ln >> 4;
  int hb = blockIdx.x; int h = hb>>5, i = hb&31;
  unsigned mb = causal_local ? ((1u<<i) | (i ? (1u<<(i-1)) : 0u)) : maskb[hb];

  const unsigned short* qrow = qbh + ((size_t)h*TT + i*64 + wave*16 + fr)*HD + fq*8;
  s8v bq0 = *(const s8v*)(qrow);
  s8v bq1 = *(const s8v*)(qrow + 32);

  f4v acc_o[4] = {};
  float m_run = -3.4e38f;
  float l_run = 0.f;

  int srow = tid>>2, sg = (tid&3)*16;
  unsigned short* Pw = Pl + wave*16*72;

  for(int j=0;j<NB;j++){
    if(!((mb>>j)&1u)) continue;
    __syncthreads();
    {
      const unsigned short* ks_ = kbh + ((size_t)h*TT + j*64 + srow)*HD + sg;
      *(s8v*)&Kb[srow*72 + sg]     = *(const s8v*)(ks_);
      *(s8v*)&Kb[srow*72 + sg + 8] = *(const s8v*)(ks_ + 8);
      const unsigned short* vs_ = vth + ((size_t)h*HD + srow)*TT + j*64 + sg;
      *(s8v*)&Vt[srow*72 + sg]     = *(const s8v*)(vs_);
      *(s8v*)&Vt[srow*72 + sg + 8] = *(const s8v*)(vs_ + 8);
    }
    __syncthreads();

    f4v sv[4] = {};
#pragma unroll
    for(int mt=0;mt<4;mt++){
      s8v ak0 = *(const s8v*)&Kb[(mt*16+fr)*72 + fq*8];
      s8v ak1 = *(const s8v*)&Kb[(mt*16+fr)*72 + fq*8 + 32];
      sv[mt] = __builtin_amdgcn_mfma_f32_16x16x32_bf16(ak0, bq0, sv[mt], 0,0,0);
      sv[mt] = __builtin_amdgcn_mfma_f32_16x16x32_bf16(ak1, bq1, sv[mt], 0,0,0);
    }
    bool diag = (causal_local!=0) && (j==i);
    int qpos = wave*16 + fr;
#pragma unroll
    for(int mt=0;mt<4;mt++){
#pragma unroll
      for(int r=0;r<4;r++){
        float s = sv[mt][r]*0.125f;
        if(diag && (mt*16 + fq*4 + r) > qpos) s = -3.4e38f;
        sv[mt][r] = s;
      }
    }
    float mx = -3.4e38f;
#pragma unroll
    for(int mt=0;mt<4;mt++)
#pragma unroll
      for(int r=0;r<4;r++) mx = fmaxf(mx, sv[mt][r]);
    mx = fmaxf(mx, __shfl_xor(mx,16,64));
    mx = fmaxf(mx, __shfl_xor(mx,32,64));
    float mnew = fmaxf(m_run, mx);
    float es = 0.f;
#pragma unroll
    for(int mt=0;mt<4;mt++)
#pragma unroll
      for(int r=0;r<4;r++){
        float p = __expf(sv[mt][r] - mnew);
        es += p;
        Pw[fr*72 + mt*16 + fq*4 + r] = f2bf(p);
      }
    es += __shfl_xor(es,16,64);
    es += __shfl_xor(es,32,64);
    float alpha = __expf(m_run - mnew);
    l_run = l_run*alpha + es;
    m_run = mnew;
    float av[4];
#pragma unroll
    for(int r=0;r<4;r++) av[r] = __shfl(alpha, fq*4+r, 64);
#pragma unroll
    for(int nt=0;nt<4;nt++)
#pragma unroll
      for(int r=0;r<4;r++) acc_o[nt][r] *= av[r];
    __syncthreads();

    s8v ap0 = *(const s8v*)&Pw[fr*72 + fq*8];
    s8v ap1 = *(const s8v*)&Pw[fr*72 + fq*8 + 32];
#pragma unroll
    for(int nt=0;nt<4;nt++){
      s8v bv0 = *(const s8v*)&Vt[(nt*16+fr)*72 + fq*8];
      s8v bv1 = *(const s8v*)&Vt[(nt*16+fr)*72 + fq*8 + 32];
      acc_o[nt] = __builtin_amdgcn_mfma_f32_16x16x32_bf16(ap0, bv0, acc_o[nt], 0,0,0);
      acc_o[nt] = __builtin_amdgcn_mfma_f32_16x16x32_bf16(ap1, bv1, acc_o[nt], 0,0,0);
    }
  }
  float lv[4];
#pragma unroll
  for(int r=0;r<4;r++) lv[r] = __shfl(l_run, fq*4+r, 64);
#pragma unroll
  for(int nt=0;nt<4;nt++){
#pragma unroll
    for(int r=0;r<4;r++){
      int t = i*64 + wave*16 + fq*4 + r;
      int d = nt*16 + fr;
      outp[((size_t)h*TT + t)*HD + d] = acc_o[nt][r] / lv[r];
    }
  }
}

// ---------------- gated combine -> merged bf16 (t, h*64+d) ----------------
__global__ __launch_bounds__(256) void combine_kernel(
    const float* __restrict__ swo, const float* __restrict__ comp, const float* __restrict__ fino,
    const float* __restrict__ gatep, unsigned short* __restrict__ mergedh)
{
  int idx = blockIdx.x*256 + threadIdx.x;
  int t = idx>>10, c = idx & 1023;
  int h = c>>6, d = c&63;
  const float* g = gatep + (size_t)t*48 + h*3;
  size_t a = ((size_t)h*TT + t)*HD + d;
  mergedh[idx] = f2bf(g[0]*swo[a] + g[1]*comp[a] + g[2]*fino[a]);
}

extern "C" void kernel_launch(void* const* d_in, const int* in_sizes, int n_in,
                              void* d_out, int out_size, void* d_ws, size_t ws_size,
                              hipStream_t stream) {
  (void)in_sizes; (void)n_in; (void)out_size; (void)ws_size;
  const float* hs  = (const float*)d_in[0];
  const float* Wq  = (const float*)d_in[1];
  const float* Wk  = (const float*)d_in[2];
  const float* Wv  = (const float*)d_in[3];
  const float* Wo  = (const float*)d_in[4];
  const float* Wc  = (const float*)d_in[5];
  const float* bcp = (const float*)d_in[6];
  const float* ksc = (const float*)d_in[7];
  const float* kbi = (const float*)d_in[8];
  const float* Wg  = (const float*)d_in[9];
  const float* bg  = (const float*)d_in[10];
  float* out = (float*)d_out;

  float* ws = (float*)d_ws;
  float* qb     = ws;                   // 2097152
  float* kb     = qb + 2097152;
  float* vb     = kb + 2097152;
  float* gatep  = vb + 2097152;         // 98304
  // compressed k/v (bf16): reuse old kc/vc slot (65536 floats)
  unsigned short* kch  = (unsigned short*)(gatep + 98304);       // 32768 shorts
  unsigned short* kcl  = kch + 32768;                            // 32768 shorts
  unsigned short* vcth = kcl + 32768;                            // 32768 shorts
  float* imp    = gatep + 98304 + 65536;      // 1048576
  float* comp   = imp + 1048576;              // 2097152 (hsh/hsl alias)
  float* swo    = comp + 2097152;             // 2097152 (wth alias)
  float* fino   = swo + 2097152;              // 2097152 (wtl alias)
  unsigned short* mergedh = (unsigned short*)(fino + 2097152);   // 1048576 floats
  float* dkf    = fino + 2097152 + 1048576;   // 512
  unsigned* maskb = (unsigned*)(dkf + 512);   // 512
  unsigned short* woth = (unsigned short*)(dkf + 1024);          // 524288 floats
  unsigned short* qbh = (unsigned short*)(dkf + 1024 + 524288);  // 1048576 f
  unsigned short* kbh = qbh + 2097152;                           // 1048576 f
  unsigned short* vth = kbh + 2097152;                           // 1048576 f
  unsigned short* qbl = vth + 2097152;                           // 1048576 f
  unsigned short* kbl = qbl + 2097152;                           // 1048576 f
  unsigned short* vbh = kbl + 2097152;                           // 1048576 f
  unsigned short* wcth = vbh + 2097152;                          // 131072 f
  unsigned short* wctl = wcth + 262144;                          // 131072 f
  float* ccpart = (float*)(wctl + 262144);                       // 524288 f

  unsigned short* hsh = (unsigned short*)comp;
  unsigned short* hsl = (unsigned short*)(comp + 1048576);
  unsigned short* wth = (unsigned short*)swo;
  unsigned short* wtl = (unsigned short*)(swo + 1572864);

  float* out_avgk   = out + 2097152;
  float* out_kratio = out + 2097153;
  float* out_nent   = out + 2097665;

  split_hs_k<<<dim3(2048), 256, 0, stream>>>(hs, hsh, hsl);
  prep_w_k<<<dim3(16,16,4), 256, 0, stream>>>(Wq, Wk, Wv, Wo, wth, wtl, woth);
  prep_wc_k<<<dim3(64), 256, 0, stream>>>(Wc, wcth, wctl);
  mfma_qkv_k<<<dim3(24,16), 256, 0, stream>>>(hsh, hsl, wth, wtl, qb, kb, vb);
  conv_qkv<<<dim3(1024,3), 256, 0, stream>>>(qb, kb, vb, qbh, qbl, kbh, kbl, vbh);
  conv_vt<<<dim3(32,16), 256, 0, stream>>>(vb, vth);
  gate_kernel<<<dim3(2048), 256, 0, stream>>>(hs, Wg, bg, gatep);
  mfma_compress_k<<<dim3(8,16), 256, 0, stream>>>(kbh, kbl, vbh, wcth, wctl, ccpart);
  compress_fin<<<dim3(256), 256, 0, stream>>>(ccpart, bcp, kch, kcl, vcth);
  comp_attn_mfma<<<dim3(32,16), 256, 0, stream>>>(qbh, qbl, kch, kcl, vcth, imp, comp);
  block_stats<<<dim3(512), 256, 0, stream>>>(imp, ksc, kbi, maskb, dkf, out_kratio, out_nent);
  avgk_kernel<<<dim3(1), 256, 0, stream>>>(dkf, out_avgk);
  attn_mfma<<<dim3(512), 256, 0, stream>>>(qbh, kbh, vth, maskb, swo, 1);
  attn_mfma<<<dim3(512), 256, 0, stream>>>(qbh, kbh, vth, maskb, fino, 0);
  combine_kernel<<<dim3(8192), 256, 0, stream>>>(swo, comp, fino, gatep, mergedh);
  mfma_proj_k<<<dim3(8,16), 256, 0, stream>>>(mergedh, woth, out);
}

// Round 5
// 236.493 us; speedup vs baseline: 2.8614x; 1.0965x over previous
//
#include <hip/hip_runtime.h>
#include <math.h>

#define TT 2048
#define NH 16
#define HD 64
#define NB 32
#define HIDDEN 1024

typedef short s8v __attribute__((ext_vector_type(8)));
typedef float f4v __attribute__((ext_vector_type(4)));

// ---------------- bf16 helpers (header-independent, RNE) ----------------
__device__ __forceinline__ unsigned short f2bf(float x){
  unsigned u = __float_as_uint(x);
  unsigned r = (u + 0x7fffu + ((u>>16)&1u)) >> 16;
  return (unsigned short)r;
}
__device__ __forceinline__ float bf2f(unsigned short b){
  return __uint_as_float(((unsigned)b)<<16);
}
__device__ __forceinline__ void bsplit(float x, unsigned short& h, unsigned short& l){
  h = f2bf(x);
  l = f2bf(x - bf2f(h));
}

// ---------------- wave reductions ----------------
__device__ __forceinline__ float rmax32(float v){
#pragma unroll
  for(int o=16;o>0;o>>=1) v = fmaxf(v, __shfl_xor(v,o,32));
  return v;
}
__device__ __forceinline__ float rsum32(float v){
#pragma unroll
  for(int o=16;o>0;o>>=1) v += __shfl_xor(v,o,32);
  return v;
}

// ---------------- fused prep: split hs + transpose/split Wq/Wk/Wv/Wo + Wc ----------------
__global__ __launch_bounds__(256) void prep_all(
    const float* __restrict__ hs,
    const float* __restrict__ Wq, const float* __restrict__ Wk,
    const float* __restrict__ Wv, const float* __restrict__ Wo,
    const float* __restrict__ Wc,
    unsigned short* __restrict__ hh, unsigned short* __restrict__ hl,
    unsigned short* __restrict__ wth, unsigned short* __restrict__ wtl,
    unsigned short* __restrict__ woth,
    unsigned short* __restrict__ wcth, unsigned short* __restrict__ wctl)
{
  __shared__ float L[64][68];
  int bx = blockIdx.x;
  int t = threadIdx.x;
  if(bx < 2048){
    int i = (bx*256 + t)*4;
    float4 x = *(const float4*)(hs + i);
    ushort4 hv, lv;
    bsplit(x.x, hv.x, lv.x); bsplit(x.y, hv.y, lv.y);
    bsplit(x.z, hv.z, lv.z); bsplit(x.w, hv.w, lv.w);
    *(ushort4*)(hh + i) = hv;
    *(ushort4*)(hl + i) = lv;
    return;
  }
  if(bx < 3072){
    int idx = bx - 2048;
    int z = idx>>8, ky = (idx>>4)&15, nx = idx&15;
    const float* W = (z==0)?Wq:((z==1)?Wk:((z==2)?Wv:Wo));
    int k0 = ky*64, n0 = nx*64;
    int rr = t>>2, cg = t&3;
    const float* src = W + (size_t)(k0+rr)*1024 + n0 + cg*16;
    float4 a = *(const float4*)(src);
    float4 b = *(const float4*)(src+4);
    float4 c = *(const float4*)(src+8);
    float4 d = *(const float4*)(src+12);
    *(float4*)&L[rr][cg*16+0]  = a;
    *(float4*)&L[rr][cg*16+4]  = b;
    *(float4*)&L[rr][cg*16+8]  = c;
    *(float4*)&L[rr][cg*16+12] = d;
    __syncthreads();
    int nr = t>>2, kg = t&3;
    unsigned short hb[16], lb[16];
#pragma unroll
    for(int j=0;j<16;j++){
      float v = L[kg*16+j][nr];
      bsplit(v, hb[j], lb[j]);
    }
    if(z<3){
      size_t orow = ((size_t)z*1024 + n0 + nr)*1024 + k0 + kg*16;
      *(ushort4*)(wth+orow+0)  = make_ushort4(hb[0],hb[1],hb[2],hb[3]);
      *(ushort4*)(wth+orow+4)  = make_ushort4(hb[4],hb[5],hb[6],hb[7]);
      *(ushort4*)(wth+orow+8)  = make_ushort4(hb[8],hb[9],hb[10],hb[11]);
      *(ushort4*)(wth+orow+12) = make_ushort4(hb[12],hb[13],hb[14],hb[15]);
      *(ushort4*)(wtl+orow+0)  = make_ushort4(lb[0],lb[1],lb[2],lb[3]);
      *(ushort4*)(wtl+orow+4)  = make_ushort4(lb[4],lb[5],lb[6],lb[7]);
      *(ushort4*)(wtl+orow+8)  = make_ushort4(lb[8],lb[9],lb[10],lb[11]);
      *(ushort4*)(wtl+orow+12) = make_ushort4(lb[12],lb[13],lb[14],lb[15]);
    }else{
      size_t orow = ((size_t)n0 + nr)*1024 + k0 + kg*16;
      *(ushort4*)(woth+orow+0)  = make_ushort4(hb[0],hb[1],hb[2],hb[3]);
      *(ushort4*)(woth+orow+4)  = make_ushort4(hb[4],hb[5],hb[6],hb[7]);
      *(ushort4*)(woth+orow+8)  = make_ushort4(hb[8],hb[9],hb[10],hb[11]);
      *(ushort4*)(woth+orow+12) = make_ushort4(hb[12],hb[13],hb[14],hb[15]);
    }
    return;
  }
  {
    int k0 = (bx - 3072)*64;
    int rr = t>>2, cg = t&3;
    const float* src = Wc + (size_t)(k0+rr)*64 + cg*16;
    float4 a = *(const float4*)(src);
    float4 b = *(const float4*)(src+4);
    float4 c = *(const float4*)(src+8);
    float4 d = *(const float4*)(src+12);
    *(float4*)&L[rr][cg*16+0]  = a;
    *(float4*)&L[rr][cg*16+4]  = b;
    *(float4*)&L[rr][cg*16+8]  = c;
    *(float4*)&L[rr][cg*16+12] = d;
    __syncthreads();
    int nr = t>>2, kg = t&3;
    unsigned short hb[16], lb[16];
#pragma unroll
    for(int j=0;j<16;j++){
      float v = L[kg*16+j][nr];
      bsplit(v, hb[j], lb[j]);
    }
    size_t orow = (size_t)nr*4096 + k0 + kg*16;
    *(ushort4*)(wcth+orow+0)  = make_ushort4(hb[0],hb[1],hb[2],hb[3]);
    *(ushort4*)(wcth+orow+4)  = make_ushort4(hb[4],hb[5],hb[6],hb[7]);
    *(ushort4*)(wcth+orow+8)  = make_ushort4(hb[8],hb[9],hb[10],hb[11]);
    *(ushort4*)(wcth+orow+12) = make_ushort4(hb[12],hb[13],hb[14],hb[15]);
    *(ushort4*)(wctl+orow+0)  = make_ushort4(lb[0],lb[1],lb[2],lb[3]);
    *(ushort4*)(wctl+orow+4)  = make_ushort4(lb[4],lb[5],lb[6],lb[7]);
    *(ushort4*)(wctl+orow+8)  = make_ushort4(lb[8],lb[9],lb[10],lb[11]);
    *(ushort4*)(wctl+orow+12) = make_ushort4(lb[12],lb[13],lb[14],lb[15]);
  }
}

// ---------------- QKV MFMA GEMM; epilogue writes bf16 (+lo split for q,k) directly ----------------
#define LROW 40
__global__ __launch_bounds__(256) void mfma_qkv_k(
    const unsigned short* __restrict__ ahg, const unsigned short* __restrict__ alg,
    const unsigned short* __restrict__ bhg, const unsigned short* __restrict__ blg,
    unsigned short* __restrict__ qbh, unsigned short* __restrict__ qbl,
    unsigned short* __restrict__ kbh, unsigned short* __restrict__ kbl,
    unsigned short* __restrict__ vbh)
{
  __shared__ unsigned short Ah[128*LROW], Al[128*LROW], Bh[128*LROW], Bl[128*LROW];
  int tid = threadIdx.x;
  int bn = blockIdx.x*128, bm = blockIdx.y*128;
  bool tp = (blockIdx.x < 16);    // 3-pass for Q and K columns
  int sr = tid>>2, skg = tid&3;
  const unsigned short* gA  = ahg + (size_t)(bm+sr)*HIDDEN + skg*8;
  const unsigned short* gAl = alg + (size_t)(bm+sr)*HIDDEN + skg*8;
  const unsigned short* gB  = bhg + (size_t)(bn+sr)*HIDDEN + skg*8;
  const unsigned short* gBl = blg + (size_t)(bn+sr)*HIDDEN + skg*8;
  int wv = tid>>6, ln = tid&63;
  int wm = (wv&1)*64, wn = (wv>>1)*64;
  int fr = ln&15, fq = ln>>4;
  int wlds = sr*LROW + skg*8;
  f4v acc[4][4] = {};
  for(int k0=0;k0<HIDDEN;k0+=32){
    s8v a0 = *(const s8v*)(gA + k0);
    s8v a1 = *(const s8v*)(gA + 65536 + k0);
    s8v b0 = *(const s8v*)(gB + k0);
    s8v b1 = *(const s8v*)(gB + 65536 + k0);
    s8v a0l, a1l, b0l, b1l;
    if(tp){
      a0l = *(const s8v*)(gAl + k0);
      a1l = *(const s8v*)(gAl + 65536 + k0);
      b0l = *(const s8v*)(gBl + k0);
      b1l = *(const s8v*)(gBl + 65536 + k0);
    }
    __syncthreads();
    *(s8v*)&Ah[wlds] = a0; *(s8v*)&Ah[wlds + 64*LROW] = a1;
    *(s8v*)&Bh[wlds] = b0; *(s8v*)&Bh[wlds + 64*LROW] = b1;
    if(tp){
      *(s8v*)&Al[wlds] = a0l; *(s8v*)&Al[wlds + 64*LROW] = a1l;
      *(s8v*)&Bl[wlds] = b0l; *(s8v*)&Bl[wlds + 64*LROW] = b1l;
    }
    __syncthreads();
    s8v af[4], bf[4], tf;
#pragma unroll
    for(int i=0;i<4;i++) af[i] = *(const s8v*)&Ah[(wm+i*16+fr)*LROW + fq*8];
#pragma unroll
    for(int i=0;i<4;i++) bf[i] = *(const s8v*)&Bh[(wn+i*16+fr)*LROW + fq*8];
#pragma unroll
    for(int i=0;i<4;i++)
#pragma unroll
      for(int j=0;j<4;j++)
        acc[i][j] = __builtin_amdgcn_mfma_f32_16x16x32_bf16(af[i], bf[j], acc[i][j], 0,0,0);
    if(tp){
#pragma unroll
      for(int i=0;i<4;i++){
        tf = *(const s8v*)&Al[(wm+i*16+fr)*LROW + fq*8];
#pragma unroll
        for(int j=0;j<4;j++)
          acc[i][j] = __builtin_amdgcn_mfma_f32_16x16x32_bf16(tf, bf[j], acc[i][j], 0,0,0);
      }
#pragma unroll
      for(int j=0;j<4;j++){
        tf = *(const s8v*)&Bl[(wn+j*16+fr)*LROW + fq*8];
#pragma unroll
        for(int i=0;i<4;i++)
          acc[i][j] = __builtin_amdgcn_mfma_f32_16x16x32_bf16(af[i], tf, acc[i][j], 0,0,0);
      }
    }
  }
  int z = bn >> 10;
#pragma unroll
  for(int i=0;i<4;i++){
    int mb = bm + wm + i*16 + fq*4;
#pragma unroll
    for(int j=0;j<4;j++){
      int n = bn + wn + j*16 + fr;
      int n1 = n & 1023, hd = n1>>6, d = n1&63;
      size_t base = ((size_t)hd*TT + mb)*HD + d;
#pragma unroll
      for(int r=0;r<4;r++){
        float v = acc[i][j][r];
        size_t a = base + (size_t)r*HD;
        if(z==0){
          unsigned short hi = f2bf(v);
          qbh[a] = hi; qbl[a] = f2bf(v - bf2f(hi));
        }else if(z==1){
          unsigned short hi = f2bf(v);
          kbh[a] = hi; kbl[a] = f2bf(v - bf2f(hi));
        }else{
          vbh[a] = f2bf(v);
        }
      }
    }
  }
}

// ---------------- bf16 v [h][t][d] -> bf16 v^T [h][d][t] ----------------
__global__ __launch_bounds__(256) void conv_vt(
    const unsigned short* __restrict__ vbh, unsigned short* __restrict__ vth)
{
  int tt = blockIdx.x, h = blockIdx.y;
  __shared__ unsigned short L[64][72];
  int t = threadIdx.x;
  int row = t>>2, dg = (t&3)*16;
  const unsigned short* src = vbh + ((size_t)h*TT + tt*64 + row)*HD + dg;
  *(s8v*)&L[row][dg]   = *(const s8v*)(src);
  *(s8v*)&L[row][dg+8] = *(const s8v*)(src+8);
  __syncthreads();
  int d = t>>2, kg = (t&3)*16;
  s8v r0, r1;
#pragma unroll
  for(int u=0;u<8;u++)  r0[u] = (short)L[kg+u][d];
#pragma unroll
  for(int u=0;u<8;u++)  r1[u] = (short)L[kg+8+u][d];
  unsigned short* dst = vth + ((size_t)h*HD + d)*TT + tt*64 + kg;
  *(s8v*)(dst)   = r0;
  *(s8v*)(dst+8) = r1;
}

// ---------------- gate: sigmoid(hs @ Wg + bg), (2048 x 48) ----------------
__global__ __launch_bounds__(256) void gate_kernel(
    const float* __restrict__ hs, const float* __restrict__ Wg, const float* __restrict__ bg,
    float* __restrict__ gatep)
{
  int t = blockIdx.x;
  __shared__ float row[1024];
  __shared__ float red[4][64];
  int tid = threadIdx.x;
  *(float4*)(row + tid*4) = *(const float4*)(hs + (size_t)t*HIDDEN + tid*4);
  __syncthreads();
  int n = tid & 63, part = tid>>6;
  float s = 0.f;
  if(n < 48){
    const float* w = Wg + n;
    for(int kx = part*256; kx < part*256+256; kx++)
      s += row[kx]*w[(size_t)kx*48];
  }
  red[part][n] = s;
  __syncthreads();
  if(part==0 && n<48){
    float x = red[0][n]+red[1][n]+red[2][n]+red[3][n] + bg[n];
    gatep[(size_t)t*48 + n] = 1.f/(1.f+expf(-x));
  }
}

// ---------------- compress MFMA GEMM: [kblk;vblk](1024x4096) @ WcT, split-K ----------------
#define CROW 40
__global__ __launch_bounds__(256) void mfma_compress_k(
    const unsigned short* __restrict__ kbh, const unsigned short* __restrict__ kbl,
    const unsigned short* __restrict__ vbh,
    const unsigned short* __restrict__ wcth, const unsigned short* __restrict__ wctl,
    float* __restrict__ ccpart)
{
  __shared__ unsigned short As[64*CROW], Al[64*CROW], Bs[64*CROW], Bl[64*CROW];
  int chunk = blockIdx.x;
  int mt = blockIdx.y;
  bool isK = (mt < 8);
  const unsigned short* Ag  = isK ? (kbh + (size_t)mt*262144) : (vbh + (size_t)(mt-8)*262144);
  const unsigned short* Agl = kbl + (size_t)(isK ? mt : 0)*262144;
  int tid = threadIdx.x;
  int sr = tid>>2, skg = (tid&3)*8;
  int k0b = chunk*512;
  const unsigned short* gA  = Ag  + (size_t)sr*4096 + k0b + skg;
  const unsigned short* gAl = Agl + (size_t)sr*4096 + k0b + skg;
  const unsigned short* gB  = wcth + (size_t)sr*4096 + k0b + skg;
  const unsigned short* gBl = wctl + (size_t)sr*4096 + k0b + skg;
  int wv = tid>>6, ln = tid&63;
  int fr = ln&15, fq = ln>>4;
  int wlds = sr*CROW + skg;
  f4v acc[4] = {};
  for(int ks=0; ks<512; ks+=32){
    s8v a0 = *(const s8v*)(gA + ks);
    s8v b0 = *(const s8v*)(gB + ks);
    s8v b1 = *(const s8v*)(gBl + ks);
    s8v a1 = {};
    if(isK) a1 = *(const s8v*)(gAl + ks);
    __syncthreads();
    *(s8v*)&As[wlds] = a0;
    *(s8v*)&Bs[wlds] = b0;
    *(s8v*)&Bl[wlds] = b1;
    if(isK) *(s8v*)&Al[wlds] = a1;
    __syncthreads();
    s8v bfh = *(const s8v*)&Bs[(wv*16+fr)*CROW + fq*8];
    s8v bfl = *(const s8v*)&Bl[(wv*16+fr)*CROW + fq*8];
#pragma unroll
    for(int m=0;m<4;m++){
      s8v af = *(const s8v*)&As[(m*16+fr)*CROW + fq*8];
      acc[m] = __builtin_amdgcn_mfma_f32_16x16x32_bf16(af, bfh, acc[m], 0,0,0);
      acc[m] = __builtin_amdgcn_mfma_f32_16x16x32_bf16(af, bfl, acc[m], 0,0,0);
      if(isK){
        s8v afl = *(const s8v*)&Al[(m*16+fr)*CROW + fq*8];
        acc[m] = __builtin_amdgcn_mfma_f32_16x16x32_bf16(afl, bfh, acc[m], 0,0,0);
      }
    }
  }
  float* dst = ccpart + ((size_t)chunk*1024 + mt*64)*64;
#pragma unroll
  for(int m=0;m<4;m++)
#pragma unroll
    for(int r=0;r<4;r++)
      dst[(size_t)(m*16+fq*4+r)*64 + wv*16 + fr] = acc[m][r];
}

// ---------------- reduce partials + bias + gelu -> kc split bf16, vc^T bf16 ----------------
__global__ __launch_bounds__(256) void compress_fin(
    const float* __restrict__ ccpart, const float* __restrict__ bcp,
    unsigned short* __restrict__ kch, unsigned short* __restrict__ kcl,
    unsigned short* __restrict__ vcth)
{
  int idx = blockIdx.x*256 + threadIdx.x;   // 65536
  int row = idx>>6, col = idx&63;
  float s = 0.f;
#pragma unroll
  for(int c=0;c<8;c++) s += ccpart[(size_t)c*65536 + idx];
  s += bcp[col];
  float g = 0.5f*s*(1.f+erff(s*0.70710678118654752f));
  if(row < 512){
    unsigned short hi = f2bf(g);
    kch[idx] = hi;
    kcl[idx] = f2bf(g - bf2f(hi));
  }else{
    int r = row - 512;
    int h = r>>5, j = r&31;
    vcth[((size_t)h*64 + col)*32 + j] = f2bf(g);
  }
}

// ---------------- compressed attention via MFMA: imp + softmax + comp_out ----------------
__global__ __launch_bounds__(256) void comp_attn_mfma(
    const unsigned short* __restrict__ qbh, const unsigned short* __restrict__ qbl,
    const unsigned short* __restrict__ kch, const unsigned short* __restrict__ kcl,
    const unsigned short* __restrict__ vcth,
    float* __restrict__ imp, float* __restrict__ comp)
{
  __shared__ unsigned short Pl[4*16*40];
  int tid = threadIdx.x;
  int wave = __builtin_amdgcn_readfirstlane(tid>>6);
  int ln = tid&63;
  int fr = ln&15, fq = ln>>4;
  int i = blockIdx.x, h = blockIdx.y;

  const unsigned short* qrh = qbh + ((size_t)h*TT + i*64 + wave*16 + fr)*HD + fq*8;
  const unsigned short* qrl = qbl + ((size_t)h*TT + i*64 + wave*16 + fr)*HD + fq*8;
  s8v bh0 = *(const s8v*)(qrh);
  s8v bh1 = *(const s8v*)(qrh + 32);
  s8v bl0 = *(const s8v*)(qrl);
  s8v bl1 = *(const s8v*)(qrl + 32);

  f4v sv[2] = {};
#pragma unroll
  for(int mt=0;mt<2;mt++){
    const unsigned short* ar = kch + ((size_t)h*32 + mt*16 + fr)*HD + fq*8;
    const unsigned short* al = kcl + ((size_t)h*32 + mt*16 + fr)*HD + fq*8;
    s8v ah0 = *(const s8v*)(ar);
    s8v ah1 = *(const s8v*)(ar + 32);
    s8v al0 = *(const s8v*)(al);
    s8v al1 = *(const s8v*)(al + 32);
    sv[mt] = __builtin_amdgcn_mfma_f32_16x16x32_bf16(ah0, bh0, sv[mt], 0,0,0);
    sv[mt] = __builtin_amdgcn_mfma_f32_16x16x32_bf16(ah1, bh1, sv[mt], 0,0,0);
    sv[mt] = __builtin_amdgcn_mfma_f32_16x16x32_bf16(al0, bh0, sv[mt], 0,0,0);
    sv[mt] = __builtin_amdgcn_mfma_f32_16x16x32_bf16(al1, bh1, sv[mt], 0,0,0);
    sv[mt] = __builtin_amdgcn_mfma_f32_16x16x32_bf16(ah0, bl0, sv[mt], 0,0,0);
    sv[mt] = __builtin_amdgcn_mfma_f32_16x16x32_bf16(ah1, bl1, sv[mt], 0,0,0);
  }
  int t = i*64 + wave*16 + fr;
  float* impr = imp + ((size_t)h*TT + t)*NB;
  float mx = -3.4e38f;
#pragma unroll
  for(int mt=0;mt<2;mt++)
#pragma unroll
    for(int r=0;r<4;r++){
      float s = sv[mt][r]*0.125f;
      sv[mt][r] = s;
      impr[mt*16 + fq*4 + r] = s;
      mx = fmaxf(mx, s);
    }
  mx = fmaxf(mx, __shfl_xor(mx,16,64));
  mx = fmaxf(mx, __shfl_xor(mx,32,64));
  unsigned short* Pw = Pl + wave*16*40;
  float es = 0.f;
#pragma unroll
  for(int mt=0;mt<2;mt++)
#pragma unroll
    for(int r=0;r<4;r++){
      float p = __expf(sv[mt][r] - mx);
      es += p;
      Pw[fr*40 + mt*16 + fq*4 + r] = f2bf(p);
    }
  es += __shfl_xor(es,16,64);
  es += __shfl_xor(es,32,64);

  s8v ap = *(const s8v*)&Pw[fr*40 + fq*8];
  f4v acc[4] = {};
#pragma unroll
  for(int nt=0;nt<4;nt++){
    s8v bv = *(const s8v*)(vcth + ((size_t)h*64 + nt*16 + fr)*32 + fq*8);
    acc[nt] = __builtin_amdgcn_mfma_f32_16x16x32_bf16(ap, bv, acc[nt], 0,0,0);
  }
  float lv[4];
#pragma unroll
  for(int r=0;r<4;r++) lv[r] = __shfl(es, fq*4+r, 64);
#pragma unroll
  for(int nt=0;nt<4;nt++)
#pragma unroll
    for(int r=0;r<4;r++){
      int tq = i*64 + wave*16 + fq*4 + r;
      comp[((size_t)h*TT + tq)*HD + nt*16 + fr] = acc[nt][r]/lv[r];
    }
}

// ---------------- block scores -> entropy -> dynamic_k -> top-k mask ----------------
__global__ __launch_bounds__(256) void block_stats(
    const float* __restrict__ imp, const float* __restrict__ ksc, const float* __restrict__ kbi,
    unsigned* __restrict__ maskb, float* __restrict__ dkf,
    float* __restrict__ out_kratio, float* __restrict__ out_nent)
{
  int hb = blockIdx.x; int h = hb>>5, i = hb&31;
  int tid = threadIdx.x; int j = tid&31, p = tid>>5;
  const float* base = imp + ((size_t)h*TT + i*64)*NB;
  float s = 0.f;
  for(int t2=p*8; t2<p*8+8; t2++) s += base[(size_t)t2*NB + j];
  __shared__ float red[8][32];
  red[p][j] = s;
  __syncthreads();
  if(tid < 32){
    float bs = 0.f;
#pragma unroll
    for(int pp=0; pp<8; pp++) bs += red[pp][j];
    bs *= (1.f/64.f);
    float m = rmax32(bs);
    float e = expf(bs - m);
    float se = rsum32(e);
    float prob = e/se;
    float ent = rsum32(-prob * logf(prob + 1e-9f));
    float nent = ent / (3.4657359027997265f + 1e-9f);
    float kl = ksc[h]*nent + kbi[h];
    float kr = 1.f/(1.f + expf(-kl));
    float dkfl = fminf(fmaxf(8.f*kr, 1.f), 8.f);
    int dk = (int)dkfl;
    unsigned sel = 0u;
    for(int r=0;r<dk;r++){
      bool unpicked = ((sel>>j)&1u)==0u;
      float cand = unpicked ? bs : -3.4e38f;
      float mx = rmax32(cand);
      unsigned long long b = __ballot(cand == mx);
      int idxsel = __ffsll(b & 0xffffffffull) - 1;
      sel |= (1u<<idxsel);
    }
    sel |= (1u<<i);
    if(j==0){
      maskb[hb] = sel;
      dkf[hb] = (float)dk;
      out_kratio[hb] = kr;
      out_nent[hb] = nent;
    }
  }
}

// ---------------- avg_k reduction ----------------
__global__ __launch_bounds__(256) void avgk_kernel(const float* __restrict__ dkf, float* __restrict__ outp){
  __shared__ float red[256];
  int tid=threadIdx.x;
  red[tid] = dkf[tid] + dkf[tid+256];
  __syncthreads();
  for(int s=128;s>0;s>>=1){ if(tid<s) red[tid]+=red[tid+s]; __syncthreads(); }
  if(tid==0) outp[0] = red[0] * (1.f/512.f);
}

// ---------------- fused sliding-window + fine attention + gated combine ----------------
// Shared S per key-block (identical for both branches); two online-softmax states;
// epilogue applies gate with comp branch and writes merged bf16 directly.
__global__ __launch_bounds__(256) void attn_fused(
    const unsigned short* __restrict__ qbh, const unsigned short* __restrict__ kbh,
    const unsigned short* __restrict__ vth, const unsigned* __restrict__ maskb,
    const float* __restrict__ comp, const float* __restrict__ gatep,
    unsigned short* __restrict__ mergedh)
{
  __shared__ unsigned short Kb[64*72];
  __shared__ unsigned short Vt[64*72];
  __shared__ unsigned short Pf[4*16*72];
  __shared__ unsigned short Ps[4*16*72];
  int tid = threadIdx.x;
  int wave = __builtin_amdgcn_readfirstlane(tid>>6);
  int ln = tid & 63;
  int fr = ln & 15, fq = ln >> 4;
  int hb = blockIdx.x; int h = hb>>5, i = hb&31;
  unsigned mb_s = (1u<<i) | (i ? (1u<<(i-1)) : 0u);
  unsigned mb_f = maskb[hb];
  unsigned mb = mb_s | mb_f;

  const unsigned short* qrow = qbh + ((size_t)h*TT + i*64 + wave*16 + fr)*HD + fq*8;
  s8v bq0 = *(const s8v*)(qrow);
  s8v bq1 = *(const s8v*)(qrow + 32);

  f4v acc_f[4] = {}, acc_s[4] = {};
  float mf = -3.4e38f, lf = 0.f, ms = -3.4e38f, ls = 0.f;

  int srow = tid>>2, sg = (tid&3)*16;
  unsigned short* Pfw = Pf + wave*16*72;
  unsigned short* Psw = Ps + wave*16*72;
  int qpos = wave*16 + fr;

  for(int j=0;j<NB;j++){
    if(!((mb>>j)&1u)) continue;
    __syncthreads();
    {
      const unsigned short* ks_ = kbh + ((size_t)h*TT + j*64 + srow)*HD + sg;
      *(s8v*)&Kb[srow*72 + sg]     = *(const s8v*)(ks_);
      *(s8v*)&Kb[srow*72 + sg + 8] = *(const s8v*)(ks_ + 8);
      const unsigned short* vs_ = vth + ((size_t)h*HD + srow)*TT + j*64 + sg;
      *(s8v*)&Vt[srow*72 + sg]     = *(const s8v*)(vs_);
      *(s8v*)&Vt[srow*72 + sg + 8] = *(const s8v*)(vs_ + 8);
    }
    __syncthreads();

    f4v sv[4] = {};
#pragma unroll
    for(int mt=0;mt<4;mt++){
      s8v ak0 = *(const s8v*)&Kb[(mt*16+fr)*72 + fq*8];
      s8v ak1 = *(const s8v*)&Kb[(mt*16+fr)*72 + fq*8 + 32];
      sv[mt] = __builtin_amdgcn_mfma_f32_16x16x32_bf16(ak0, bq0, sv[mt], 0,0,0);
      sv[mt] = __builtin_amdgcn_mfma_f32_16x16x32_bf16(ak1, bq1, sv[mt], 0,0,0);
    }
#pragma unroll
    for(int mt=0;mt<4;mt++)
#pragma unroll
      for(int r=0;r<4;r++) sv[mt][r] *= 0.125f;

    bool in_f = ((mb_f>>j)&1u) != 0u;
    bool in_s = (j==i) || (j+1==i);

    if(in_f){
      float mx = -3.4e38f;
#pragma unroll
      for(int mt=0;mt<4;mt++)
#pragma unroll
        for(int r=0;r<4;r++) mx = fmaxf(mx, sv[mt][r]);
      mx = fmaxf(mx, __shfl_xor(mx,16,64));
      mx = fmaxf(mx, __shfl_xor(mx,32,64));
      float mnew = fmaxf(mf, mx);
      float es = 0.f;
#pragma unroll
      for(int mt=0;mt<4;mt++)
#pragma unroll
        for(int r=0;r<4;r++){
          float p = __expf(sv[mt][r] - mnew);
          es += p;
          Pfw[fr*72 + mt*16 + fq*4 + r] = f2bf(p);
        }
      es += __shfl_xor(es,16,64);
      es += __shfl_xor(es,32,64);
      float alpha = __expf(mf - mnew);
      lf = lf*alpha + es;
      mf = mnew;
      float av[4];
#pragma unroll
      for(int r=0;r<4;r++) av[r] = __shfl(alpha, fq*4+r, 64);
#pragma unroll
      for(int nt=0;nt<4;nt++)
#pragma unroll
        for(int r=0;r<4;r++) acc_f[nt][r] *= av[r];
    }
    if(in_s){
      if(j==i){
#pragma unroll
        for(int mt=0;mt<4;mt++)
#pragma unroll
          for(int r=0;r<4;r++)
            if((mt*16 + fq*4 + r) > qpos) sv[mt][r] = -3.4e38f;
      }
      float mx = -3.4e38f;
#pragma unroll
      for(int mt=0;mt<4;mt++)
#pragma unroll
        for(int r=0;r<4;r++) mx = fmaxf(mx, sv[mt][r]);
      mx = fmaxf(mx, __shfl_xor(mx,16,64));
      mx = fmaxf(mx, __shfl_xor(mx,32,64));
      float mnew = fmaxf(ms, mx);
      float es = 0.f;
#pragma unroll
      for(int mt=0;mt<4;mt++)
#pragma unroll
        for(int r=0;r<4;r++){
          float p = __expf(sv[mt][r] - mnew);
          es += p;
          Psw[fr*72 + mt*16 + fq*4 + r] = f2bf(p);
        }
      es += __shfl_xor(es,16,64);
      es += __shfl_xor(es,32,64);
      float alpha = __expf(ms - mnew);
      ls = ls*alpha + es;
      ms = mnew;
      float av[4];
#pragma unroll
      for(int r=0;r<4;r++) av[r] = __shfl(alpha, fq*4+r, 64);
#pragma unroll
      for(int nt=0;nt<4;nt++)
#pragma unroll
        for(int r=0;r<4;r++) acc_s[nt][r] *= av[r];
    }

    if(in_f){
      s8v ap0 = *(const s8v*)&Pfw[fr*72 + fq*8];
      s8v ap1 = *(const s8v*)&Pfw[fr*72 + fq*8 + 32];
#pragma unroll
      for(int nt=0;nt<4;nt++){
        s8v bv0 = *(const s8v*)&Vt[(nt*16+fr)*72 + fq*8];
        s8v bv1 = *(const s8v*)&Vt[(nt*16+fr)*72 + fq*8 + 32];
        acc_f[nt] = __builtin_amdgcn_mfma_f32_16x16x32_bf16(ap0, bv0, acc_f[nt], 0,0,0);
        acc_f[nt] = __builtin_amdgcn_mfma_f32_16x16x32_bf16(ap1, bv1, acc_f[nt], 0,0,0);
      }
    }
    if(in_s){
      s8v ap0 = *(const s8v*)&Psw[fr*72 + fq*8];
      s8v ap1 = *(const s8v*)&Psw[fr*72 + fq*8 + 32];
#pragma unroll
      for(int nt=0;nt<4;nt++){
        s8v bv0 = *(const s8v*)&Vt[(nt*16+fr)*72 + fq*8];
        s8v bv1 = *(const s8v*)&Vt[(nt*16+fr)*72 + fq*8 + 32];
        acc_s[nt] = __builtin_amdgcn_mfma_f32_16x16x32_bf16(ap0, bv0, acc_s[nt], 0,0,0);
        acc_s[nt] = __builtin_amdgcn_mfma_f32_16x16x32_bf16(ap1, bv1, acc_s[nt], 0,0,0);
      }
    }
  }

  float lvf[4], lvs[4], g0[4], g1[4], g2[4];
#pragma unroll
  for(int r=0;r<4;r++){
    lvf[r] = __shfl(lf, fq*4+r, 64);
    lvs[r] = __shfl(ls, fq*4+r, 64);
    int t = i*64 + wave*16 + fq*4 + r;
    const float* g = gatep + (size_t)t*48 + h*3;
    g0[r] = g[0]; g1[r] = g[1]; g2[r] = g[2];
  }
#pragma unroll
  for(int nt=0;nt<4;nt++){
#pragma unroll
    for(int r=0;r<4;r++){
      int t = i*64 + wave*16 + fq*4 + r;
      int d = nt*16 + fr;
      float of = acc_f[nt][r] / lvf[r];
      float os = acc_s[nt][r] / lvs[r];
      float cp = comp[((size_t)h*TT + t)*HD + d];
      mergedh[(size_t)t*1024 + h*64 + d] = f2bf(g0[r]*os + g1[r]*cp + g2[r]*of);
    }
  }
}

// ---------------- output projection MFMA GEMM ----------------
__global__ __launch_bounds__(256) void mfma_proj_k(
    const unsigned short* __restrict__ ahg, const unsigned short* __restrict__ bhg,
    float* __restrict__ C)
{
  __shared__ unsigned short Ah[128*LROW], Bh[128*LROW];
  int tid = threadIdx.x;
  int bn = blockIdx.x*128, bm = blockIdx.y*128;
  int sr = tid>>2, skg = tid&3;
  const unsigned short* gA = ahg + (size_t)(bm+sr)*HIDDEN + skg*8;
  const unsigned short* gB = bhg + (size_t)(bn+sr)*HIDDEN + skg*8;
  int wv = tid>>6, ln = tid&63;
  int wm = (wv&1)*64, wn = (wv>>1)*64;
  int fr = ln&15, fq = ln>>4;
  int wlds = sr*LROW + skg*8;
  f4v acc[4][4] = {};
  for(int k0=0;k0<HIDDEN;k0+=32){
    s8v a0 = *(const s8v*)(gA + k0);
    s8v a1 = *(const s8v*)(gA + 65536 + k0);
    s8v b0 = *(const s8v*)(gB + k0);
    s8v b1 = *(const s8v*)(gB + 65536 + k0);
    __syncthreads();
    *(s8v*)&Ah[wlds] = a0; *(s8v*)&Ah[wlds + 64*LROW] = a1;
    *(s8v*)&Bh[wlds] = b0; *(s8v*)&Bh[wlds + 64*LROW] = b1;
    __syncthreads();
    s8v af[4], bf[4];
#pragma unroll
    for(int i=0;i<4;i++) af[i] = *(const s8v*)&Ah[(wm+i*16+fr)*LROW + fq*8];
#pragma unroll
    for(int i=0;i<4;i++) bf[i] = *(const s8v*)&Bh[(wn+i*16+fr)*LROW + fq*8];
#pragma unroll
    for(int i=0;i<4;i++)
#pragma unroll
      for(int j=0;j<4;j++)
        acc[i][j] = __builtin_amdgcn_mfma_f32_16x16x32_bf16(af[i], bf[j], acc[i][j], 0,0,0);
  }
#pragma unroll
  for(int i=0;i<4;i++){
    int mb = bm + wm + i*16 + fq*4;
#pragma unroll
    for(int j=0;j<4;j++){
      int n = bn + wn + j*16 + fr;
      float* dst = C + (size_t)mb*HIDDEN + n;
#pragma unroll
      for(int r=0;r<4;r++) dst[(size_t)r*HIDDEN] = acc[i][j][r];
    }
  }
}

extern "C" void kernel_launch(void* const* d_in, const int* in_sizes, int n_in,
                              void* d_out, int out_size, void* d_ws, size_t ws_size,
                              hipStream_t stream) {
  (void)in_sizes; (void)n_in; (void)out_size; (void)ws_size;
  const float* hs  = (const float*)d_in[0];
  const float* Wq  = (const float*)d_in[1];
  const float* Wk  = (const float*)d_in[2];
  const float* Wv  = (const float*)d_in[3];
  const float* Wo  = (const float*)d_in[4];
  const float* Wc  = (const float*)d_in[5];
  const float* bcp = (const float*)d_in[6];
  const float* ksc = (const float*)d_in[7];
  const float* kbi = (const float*)d_in[8];
  const float* Wg  = (const float*)d_in[9];
  const float* bg  = (const float*)d_in[10];
  float* out = (float*)d_out;

  float* ws = (float*)d_ws;
  float* gatep  = ws;                         // 98304
  unsigned short* kch  = (unsigned short*)(gatep + 98304);   // 32768 shorts
  unsigned short* kcl  = kch + 32768;
  unsigned short* vcth = kcl + 32768;
  float* imp    = gatep + 98304 + 65536;      // 1048576
  float* comp   = imp + 1048576;              // 2097152 (hsh/hsl alias)
  float* wthf   = comp + 2097152;             // 1572864 (wth region)
  float* wtlf   = wthf + 1572864;             // 1572864 (wtl region)
  unsigned short* mergedh = (unsigned short*)(wtlf + 1572864);  // 1048576 floats
  float* dkf    = wtlf + 1572864 + 1048576;   // 512
  unsigned* maskb = (unsigned*)(dkf + 512);   // 512
  unsigned short* woth = (unsigned short*)(dkf + 1024);         // 524288 floats
  unsigned short* qbh  = (unsigned short*)(dkf + 1024 + 524288);// 1048576 f each:
  unsigned short* qbl  = qbh + 2097152;
  unsigned short* kbh  = qbl + 2097152;
  unsigned short* kbl  = kbh + 2097152;
  unsigned short* vbh  = kbl + 2097152;
  unsigned short* vth  = vbh + 2097152;
  unsigned short* wcth = vth + 2097152;                         // 131072 f
  unsigned short* wctl = wcth + 262144;                         // 131072 f
  float* ccpart = (float*)(wctl + 262144);                      // 524288 f

  unsigned short* hsh = (unsigned short*)comp;
  unsigned short* hsl = (unsigned short*)(comp + 1048576);
  unsigned short* wth = (unsigned short*)wthf;
  unsigned short* wtl = (unsigned short*)wtlf;

  float* out_avgk   = out + 2097152;
  float* out_kratio = out + 2097153;
  float* out_nent   = out + 2097665;

  prep_all<<<dim3(3136), 256, 0, stream>>>(hs, Wq, Wk, Wv, Wo, Wc,
                                           hsh, hsl, wth, wtl, woth, wcth, wctl);
  mfma_qkv_k<<<dim3(24,16), 256, 0, stream>>>(hsh, hsl, wth, wtl,
                                              qbh, qbl, kbh, kbl, vbh);
  conv_vt<<<dim3(32,16), 256, 0, stream>>>(vbh, vth);
  gate_kernel<<<dim3(2048), 256, 0, stream>>>(hs, Wg, bg, gatep);
  mfma_compress_k<<<dim3(8,16), 256, 0, stream>>>(kbh, kbl, vbh, wcth, wctl, ccpart);
  compress_fin<<<dim3(256), 256, 0, stream>>>(ccpart, bcp, kch, kcl, vcth);
  comp_attn_mfma<<<dim3(32,16), 256, 0, stream>>>(qbh, qbl, kch, kcl, vcth, imp, comp);
  block_stats<<<dim3(512), 256, 0, stream>>>(imp, ksc, kbi, maskb, dkf, out_kratio, out_nent);
  avgk_kernel<<<dim3(1), 256, 0, stream>>>(dkf, out_avgk);
  attn_fused<<<dim3(512), 256, 0, stream>>>(qbh, kbh, vth, maskb, comp, gatep, mergedh);
  mfma_proj_k<<<dim3(8,16), 256, 0, stream>>>(mergedh, woth, out);
}

// Round 6
// 223.668 us; speedup vs baseline: 3.0255x; 1.0573x over previous
//
#include <hip/hip_runtime.h>
#include <math.h>

#define TT 2048
#define NH 16
#define HD 64
#define NB 32
#define HIDDEN 1024

typedef short s8v __attribute__((ext_vector_type(8)));
typedef float f4v __attribute__((ext_vector_type(4)));

// ---------------- bf16 helpers (header-independent, RNE) ----------------
__device__ __forceinline__ unsigned short f2bf(float x){
  unsigned u = __float_as_uint(x);
  unsigned r = (u + 0x7fffu + ((u>>16)&1u)) >> 16;
  return (unsigned short)r;
}
__device__ __forceinline__ float bf2f(unsigned short b){
  return __uint_as_float(((unsigned)b)<<16);
}
__device__ __forceinline__ void bsplit(float x, unsigned short& h, unsigned short& l){
  h = f2bf(x);
  l = f2bf(x - bf2f(h));
}

// ---------------- wave reductions ----------------
__device__ __forceinline__ float rmax32(float v){
#pragma unroll
  for(int o=16;o>0;o>>=1) v = fmaxf(v, __shfl_xor(v,o,32));
  return v;
}
__device__ __forceinline__ float rsum32(float v){
#pragma unroll
  for(int o=16;o>0;o>>=1) v += __shfl_xor(v,o,32);
  return v;
}

// ---------------- fused prep: split hs + transpose/split W* + Wc + gate ----------------
__global__ __launch_bounds__(256) void prep_all(
    const float* __restrict__ hs,
    const float* __restrict__ Wq, const float* __restrict__ Wk,
    const float* __restrict__ Wv, const float* __restrict__ Wo,
    const float* __restrict__ Wc,
    const float* __restrict__ Wg, const float* __restrict__ bg,
    unsigned short* __restrict__ hh, unsigned short* __restrict__ hl,
    unsigned short* __restrict__ wth, unsigned short* __restrict__ wtl,
    unsigned short* __restrict__ woth,
    unsigned short* __restrict__ wcth, unsigned short* __restrict__ wctl,
    float* __restrict__ gatep)
{
  __shared__ float SL[64*68];   // 17408 B, aliased per-branch
  int bx = blockIdx.x;
  int t = threadIdx.x;
  if(bx < 2048){
    int i = (bx*256 + t)*4;
    float4 x = *(const float4*)(hs + i);
    ushort4 hv, lv;
    bsplit(x.x, hv.x, lv.x); bsplit(x.y, hv.y, lv.y);
    bsplit(x.z, hv.z, lv.z); bsplit(x.w, hv.w, lv.w);
    *(ushort4*)(hh + i) = hv;
    *(ushort4*)(hl + i) = lv;
    return;
  }
  if(bx < 3072){
    float (*L)[68] = (float(*)[68])SL;
    int idx = bx - 2048;
    int z = idx>>8, ky = (idx>>4)&15, nx = idx&15;
    const float* W = (z==0)?Wq:((z==1)?Wk:((z==2)?Wv:Wo));
    int k0 = ky*64, n0 = nx*64;
    int rr = t>>2, cg = t&3;
    const float* src = W + (size_t)(k0+rr)*1024 + n0 + cg*16;
    float4 a = *(const float4*)(src);
    float4 b = *(const float4*)(src+4);
    float4 c = *(const float4*)(src+8);
    float4 d = *(const float4*)(src+12);
    *(float4*)&L[rr][cg*16+0]  = a;
    *(float4*)&L[rr][cg*16+4]  = b;
    *(float4*)&L[rr][cg*16+8]  = c;
    *(float4*)&L[rr][cg*16+12] = d;
    __syncthreads();
    int nr = t>>2, kg = t&3;
    unsigned short hb[16], lb[16];
#pragma unroll
    for(int j=0;j<16;j++){
      float v = L[kg*16+j][nr];
      bsplit(v, hb[j], lb[j]);
    }
    if(z<3){
      size_t orow = ((size_t)z*1024 + n0 + nr)*1024 + k0 + kg*16;
      *(ushort4*)(wth+orow+0)  = make_ushort4(hb[0],hb[1],hb[2],hb[3]);
      *(ushort4*)(wth+orow+4)  = make_ushort4(hb[4],hb[5],hb[6],hb[7]);
      *(ushort4*)(wth+orow+8)  = make_ushort4(hb[8],hb[9],hb[10],hb[11]);
      *(ushort4*)(wth+orow+12) = make_ushort4(hb[12],hb[13],hb[14],hb[15]);
      *(ushort4*)(wtl+orow+0)  = make_ushort4(lb[0],lb[1],lb[2],lb[3]);
      *(ushort4*)(wtl+orow+4)  = make_ushort4(lb[4],lb[5],lb[6],lb[7]);
      *(ushort4*)(wtl+orow+8)  = make_ushort4(lb[8],lb[9],lb[10],lb[11]);
      *(ushort4*)(wtl+orow+12) = make_ushort4(lb[12],lb[13],lb[14],lb[15]);
    }else{
      size_t orow = ((size_t)n0 + nr)*1024 + k0 + kg*16;
      *(ushort4*)(woth+orow+0)  = make_ushort4(hb[0],hb[1],hb[2],hb[3]);
      *(ushort4*)(woth+orow+4)  = make_ushort4(hb[4],hb[5],hb[6],hb[7]);
      *(ushort4*)(woth+orow+8)  = make_ushort4(hb[8],hb[9],hb[10],hb[11]);
      *(ushort4*)(woth+orow+12) = make_ushort4(hb[12],hb[13],hb[14],hb[15]);
    }
    return;
  }
  if(bx < 3136){
    float (*L)[68] = (float(*)[68])SL;
    int k0 = (bx - 3072)*64;
    int rr = t>>2, cg = t&3;
    const float* src = Wc + (size_t)(k0+rr)*64 + cg*16;
    float4 a = *(const float4*)(src);
    float4 b = *(const float4*)(src+4);
    float4 c = *(const float4*)(src+8);
    float4 d = *(const float4*)(src+12);
    *(float4*)&L[rr][cg*16+0]  = a;
    *(float4*)&L[rr][cg*16+4]  = b;
    *(float4*)&L[rr][cg*16+8]  = c;
    *(float4*)&L[rr][cg*16+12] = d;
    __syncthreads();
    int nr = t>>2, kg = t&3;
    unsigned short hb[16], lb[16];
#pragma unroll
    for(int j=0;j<16;j++){
      float v = L[kg*16+j][nr];
      bsplit(v, hb[j], lb[j]);
    }
    size_t orow = (size_t)nr*4096 + k0 + kg*16;
    *(ushort4*)(wcth+orow+0)  = make_ushort4(hb[0],hb[1],hb[2],hb[3]);
    *(ushort4*)(wcth+orow+4)  = make_ushort4(hb[4],hb[5],hb[6],hb[7]);
    *(ushort4*)(wcth+orow+8)  = make_ushort4(hb[8],hb[9],hb[10],hb[11]);
    *(ushort4*)(wcth+orow+12) = make_ushort4(hb[12],hb[13],hb[14],hb[15]);
    *(ushort4*)(wctl+orow+0)  = make_ushort4(lb[0],lb[1],lb[2],lb[3]);
    *(ushort4*)(wctl+orow+4)  = make_ushort4(lb[4],lb[5],lb[6],lb[7]);
    *(ushort4*)(wctl+orow+8)  = make_ushort4(lb[8],lb[9],lb[10],lb[11]);
    *(ushort4*)(wctl+orow+12) = make_ushort4(lb[12],lb[13],lb[14],lb[15]);
    return;
  }
  {
    // gate: sigmoid(hs @ Wg + bg) for one t-row
    float* row = SL;                 // 1024 floats
    float (*red)[64] = (float(*)[64])(SL + 1024);
    int tr = bx - 3136;
    *(float4*)(row + t*4) = *(const float4*)(hs + (size_t)tr*HIDDEN + t*4);
    __syncthreads();
    int n = t & 63, part = t>>6;
    float s = 0.f;
    if(n < 48){
      const float* w = Wg + n;
      for(int kx = part*256; kx < part*256+256; kx++)
        s += row[kx]*w[(size_t)kx*48];
    }
    red[part][n] = s;
    __syncthreads();
    if(part==0 && n<48){
      float x = red[0][n]+red[1][n]+red[2][n]+red[3][n] + bg[n];
      gatep[(size_t)tr*48 + n] = 1.f/(1.f+expf(-x));
    }
  }
}

// ---------------- QKV MFMA GEMM: 128x64 tiles, grid(48,16); LDS-staged coalesced bf16 epilogue ----------------
#define LROW 40
__global__ __launch_bounds__(256) void mfma_qkv_k(
    const unsigned short* __restrict__ ahg, const unsigned short* __restrict__ alg,
    const unsigned short* __restrict__ bhg, const unsigned short* __restrict__ blg,
    unsigned short* __restrict__ qbh, unsigned short* __restrict__ qbl,
    unsigned short* __restrict__ kbh, unsigned short* __restrict__ kbl,
    unsigned short* __restrict__ vbh)
{
  __shared__ unsigned short SH[15360];  // A:0..5119  Al:5120..10239  B:10240..12799  Bl:12800..15359
  unsigned short* SA  = SH;
  unsigned short* SAl = SH + 5120;
  unsigned short* SB  = SH + 10240;
  unsigned short* SBl = SH + 12800;
  int tid = threadIdx.x;
  int bn = blockIdx.x*64, bm = blockIdx.y*128;
  bool tp = (blockIdx.x < 32);       // Q,K columns: 3-pass split
  int aRow = tid>>1, aOff = (tid&1)*16;
  int bRow = tid>>2, bOff = (tid&3)*8;
  const unsigned short* gA  = ahg + (size_t)(bm+aRow)*HIDDEN + aOff;
  const unsigned short* gAl = alg + (size_t)(bm+aRow)*HIDDEN + aOff;
  const unsigned short* gB  = bhg + (size_t)(bn+bRow)*HIDDEN + bOff;
  const unsigned short* gBl = blg + (size_t)(bn+bRow)*HIDDEN + bOff;
  int wlA = aRow*LROW + aOff;
  int wlB = bRow*LROW + bOff;
  int wv = tid>>6, ln = tid&63;
  int wm = (wv&1)*64, wn = (wv>>1)*32;
  int fr = ln&15, fq = ln>>4;
  f4v acc[4][2] = {};
  for(int k0=0;k0<HIDDEN;k0+=32){
    s8v a0 = *(const s8v*)(gA + k0);
    s8v a1 = *(const s8v*)(gA + k0 + 8);
    s8v b0 = *(const s8v*)(gB + k0);
    s8v a0l, a1l, b0l;
    if(tp){
      a0l = *(const s8v*)(gAl + k0);
      a1l = *(const s8v*)(gAl + k0 + 8);
      b0l = *(const s8v*)(gBl + k0);
    }
    __syncthreads();
    *(s8v*)&SA[wlA] = a0; *(s8v*)&SA[wlA+8] = a1;
    *(s8v*)&SB[wlB] = b0;
    if(tp){
      *(s8v*)&SAl[wlA] = a0l; *(s8v*)&SAl[wlA+8] = a1l;
      *(s8v*)&SBl[wlB] = b0l;
    }
    __syncthreads();
    s8v af[4], bf[2], tf;
#pragma unroll
    for(int i=0;i<4;i++) af[i] = *(const s8v*)&SA[(wm+i*16+fr)*LROW + fq*8];
#pragma unroll
    for(int j=0;j<2;j++) bf[j] = *(const s8v*)&SB[(wn+j*16+fr)*LROW + fq*8];
#pragma unroll
    for(int i=0;i<4;i++)
#pragma unroll
      for(int j=0;j<2;j++)
        acc[i][j] = __builtin_amdgcn_mfma_f32_16x16x32_bf16(af[i], bf[j], acc[i][j], 0,0,0);
    if(tp){
#pragma unroll
      for(int i=0;i<4;i++){
        tf = *(const s8v*)&SAl[(wm+i*16+fr)*LROW + fq*8];
#pragma unroll
        for(int j=0;j<2;j++)
          acc[i][j] = __builtin_amdgcn_mfma_f32_16x16x32_bf16(tf, bf[j], acc[i][j], 0,0,0);
      }
#pragma unroll
      for(int j=0;j<2;j++){
        tf = *(const s8v*)&SBl[(wn+j*16+fr)*LROW + fq*8];
#pragma unroll
        for(int i=0;i<4;i++)
          acc[i][j] = __builtin_amdgcn_mfma_f32_16x16x32_bf16(af[i], tf, acc[i][j], 0,0,0);
      }
    }
  }
  // epilogue: one head per n-tile; LDS-stage [t_loc][d] then coalesced dwordx4 stores
  int z = bn >> 10;
  int head = (bn & 1023) >> 6;
  unsigned short* Cs = SH;           // 8192 shorts
  unsigned short* dsth = (z==0)?qbh:((z==1)?kbh:vbh);
  size_t obase = ((size_t)head*TT + bm)*HD;
  __syncthreads();                   // main-loop LDS reads complete
#pragma unroll
  for(int i=0;i<4;i++)
#pragma unroll
    for(int j=0;j<2;j++)
#pragma unroll
      for(int r=0;r<4;r++)
        Cs[(wm+i*16+fq*4+r)*64 + wn+j*16+fr] = f2bf(acc[i][j][r]);
  __syncthreads();
#pragma unroll
  for(int u=0;u<4;u++){
    int c = u*256 + tid;             // 1024 chunks of 8 shorts
    *(s8v*)(dsth + obase + c*8) = *(const s8v*)&Cs[c*8];
  }
  if(z<2){
    unsigned short* dstl = (z==0)?qbl:kbl;
    __syncthreads();
#pragma unroll
    for(int i=0;i<4;i++)
#pragma unroll
      for(int j=0;j<2;j++)
#pragma unroll
        for(int r=0;r<4;r++){
          float v = acc[i][j][r];
          Cs[(wm+i*16+fq*4+r)*64 + wn+j*16+fr] = f2bf(v - bf2f(f2bf(v)));
        }
    __syncthreads();
#pragma unroll
    for(int u=0;u<4;u++){
      int c = u*256 + tid;
      *(s8v*)(dstl + obase + c*8) = *(const s8v*)&Cs[c*8];
    }
  }
}

// ---------------- bf16 v [h][t][d] -> bf16 v^T [h][d][t] ----------------
__global__ __launch_bounds__(256) void conv_vt(
    const unsigned short* __restrict__ vbh, unsigned short* __restrict__ vth)
{
  int tt = blockIdx.x, h = blockIdx.y;
  __shared__ unsigned short L[64][72];
  int t = threadIdx.x;
  int row = t>>2, dg = (t&3)*16;
  const unsigned short* src = vbh + ((size_t)h*TT + tt*64 + row)*HD + dg;
  *(s8v*)&L[row][dg]   = *(const s8v*)(src);
  *(s8v*)&L[row][dg+8] = *(const s8v*)(src+8);
  __syncthreads();
  int d = t>>2, kg = (t&3)*16;
  s8v r0, r1;
#pragma unroll
  for(int u=0;u<8;u++)  r0[u] = (short)L[kg+u][d];
#pragma unroll
  for(int u=0;u<8;u++)  r1[u] = (short)L[kg+8+u][d];
  unsigned short* dst = vth + ((size_t)h*HD + d)*TT + tt*64 + kg;
  *(s8v*)(dst)   = r0;
  *(s8v*)(dst+8) = r1;
}

// ---------------- compress MFMA GEMM: [kblk;vblk](1024x4096) @ WcT, split-K ----------------
#define CROW 40
__global__ __launch_bounds__(256) void mfma_compress_k(
    const unsigned short* __restrict__ kbh, const unsigned short* __restrict__ kbl,
    const unsigned short* __restrict__ vbh,
    const unsigned short* __restrict__ wcth, const unsigned short* __restrict__ wctl,
    float* __restrict__ ccpart)
{
  __shared__ unsigned short As[64*CROW], Al[64*CROW], Bs[64*CROW], Bl[64*CROW];
  int chunk = blockIdx.x;
  int mt = blockIdx.y;
  bool isK = (mt < 8);
  const unsigned short* Ag  = isK ? (kbh + (size_t)mt*262144) : (vbh + (size_t)(mt-8)*262144);
  const unsigned short* Agl = kbl + (size_t)(isK ? mt : 0)*262144;
  int tid = threadIdx.x;
  int sr = tid>>2, skg = (tid&3)*8;
  int k0b = chunk*512;
  const unsigned short* gA  = Ag  + (size_t)sr*4096 + k0b + skg;
  const unsigned short* gAl = Agl + (size_t)sr*4096 + k0b + skg;
  const unsigned short* gB  = wcth + (size_t)sr*4096 + k0b + skg;
  const unsigned short* gBl = wctl + (size_t)sr*4096 + k0b + skg;
  int wv = tid>>6, ln = tid&63;
  int fr = ln&15, fq = ln>>4;
  int wlds = sr*CROW + skg;
  f4v acc[4] = {};
  for(int ks=0; ks<512; ks+=32){
    s8v a0 = *(const s8v*)(gA + ks);
    s8v b0 = *(const s8v*)(gB + ks);
    s8v b1 = *(const s8v*)(gBl + ks);
    s8v a1 = {};
    if(isK) a1 = *(const s8v*)(gAl + ks);
    __syncthreads();
    *(s8v*)&As[wlds] = a0;
    *(s8v*)&Bs[wlds] = b0;
    *(s8v*)&Bl[wlds] = b1;
    if(isK) *(s8v*)&Al[wlds] = a1;
    __syncthreads();
    s8v bfh = *(const s8v*)&Bs[(wv*16+fr)*CROW + fq*8];
    s8v bfl = *(const s8v*)&Bl[(wv*16+fr)*CROW + fq*8];
#pragma unroll
    for(int m=0;m<4;m++){
      s8v af = *(const s8v*)&As[(m*16+fr)*CROW + fq*8];
      acc[m] = __builtin_amdgcn_mfma_f32_16x16x32_bf16(af, bfh, acc[m], 0,0,0);
      acc[m] = __builtin_amdgcn_mfma_f32_16x16x32_bf16(af, bfl, acc[m], 0,0,0);
      if(isK){
        s8v afl = *(const s8v*)&Al[(m*16+fr)*CROW + fq*8];
        acc[m] = __builtin_amdgcn_mfma_f32_16x16x32_bf16(afl, bfh, acc[m], 0,0,0);
      }
    }
  }
  float* dst = ccpart + ((size_t)chunk*1024 + mt*64)*64;
#pragma unroll
  for(int m=0;m<4;m++)
#pragma unroll
    for(int r=0;r<4;r++)
      dst[(size_t)(m*16+fq*4+r)*64 + wv*16 + fr] = acc[m][r];
}

// ---------------- reduce partials + bias + gelu -> kc split bf16, vc^T bf16 ----------------
__global__ __launch_bounds__(256) void compress_fin(
    const float* __restrict__ ccpart, const float* __restrict__ bcp,
    unsigned short* __restrict__ kch, unsigned short* __restrict__ kcl,
    unsigned short* __restrict__ vcth)
{
  int idx = blockIdx.x*256 + threadIdx.x;   // 65536
  int row = idx>>6, col = idx&63;
  float s = 0.f;
#pragma unroll
  for(int c=0;c<8;c++) s += ccpart[(size_t)c*65536 + idx];
  s += bcp[col];
  float g = 0.5f*s*(1.f+erff(s*0.70710678118654752f));
  if(row < 512){
    unsigned short hi = f2bf(g);
    kch[idx] = hi;
    kcl[idx] = f2bf(g - bf2f(hi));
  }else{
    int r = row - 512;
    int h = r>>5, j = r&31;
    vcth[((size_t)h*64 + col)*32 + j] = f2bf(g);
  }
}

// ---------------- compressed attention via MFMA: imp + softmax + comp_out ----------------
__global__ __launch_bounds__(256) void comp_attn_mfma(
    const unsigned short* __restrict__ qbh, const unsigned short* __restrict__ qbl,
    const unsigned short* __restrict__ kch, const unsigned short* __restrict__ kcl,
    const unsigned short* __restrict__ vcth,
    float* __restrict__ imp, float* __restrict__ comp)
{
  __shared__ unsigned short Pl[4*16*40];
  int tid = threadIdx.x;
  int wave = __builtin_amdgcn_readfirstlane(tid>>6);
  int ln = tid&63;
  int fr = ln&15, fq = ln>>4;
  int i = blockIdx.x, h = blockIdx.y;

  const unsigned short* qrh = qbh + ((size_t)h*TT + i*64 + wave*16 + fr)*HD + fq*8;
  const unsigned short* qrl = qbl + ((size_t)h*TT + i*64 + wave*16 + fr)*HD + fq*8;
  s8v bh0 = *(const s8v*)(qrh);
  s8v bh1 = *(const s8v*)(qrh + 32);
  s8v bl0 = *(const s8v*)(qrl);
  s8v bl1 = *(const s8v*)(qrl + 32);

  f4v sv[2] = {};
#pragma unroll
  for(int mt=0;mt<2;mt++){
    const unsigned short* ar = kch + ((size_t)h*32 + mt*16 + fr)*HD + fq*8;
    const unsigned short* al = kcl + ((size_t)h*32 + mt*16 + fr)*HD + fq*8;
    s8v ah0 = *(const s8v*)(ar);
    s8v ah1 = *(const s8v*)(ar + 32);
    s8v al0 = *(const s8v*)(al);
    s8v al1 = *(const s8v*)(al + 32);
    sv[mt] = __builtin_amdgcn_mfma_f32_16x16x32_bf16(ah0, bh0, sv[mt], 0,0,0);
    sv[mt] = __builtin_amdgcn_mfma_f32_16x16x32_bf16(ah1, bh1, sv[mt], 0,0,0);
    sv[mt] = __builtin_amdgcn_mfma_f32_16x16x32_bf16(al0, bh0, sv[mt], 0,0,0);
    sv[mt] = __builtin_amdgcn_mfma_f32_16x16x32_bf16(al1, bh1, sv[mt], 0,0,0);
    sv[mt] = __builtin_amdgcn_mfma_f32_16x16x32_bf16(ah0, bl0, sv[mt], 0,0,0);
    sv[mt] = __builtin_amdgcn_mfma_f32_16x16x32_bf16(ah1, bl1, sv[mt], 0,0,0);
  }
  int t = i*64 + wave*16 + fr;
  float* impr = imp + ((size_t)h*TT + t)*NB;
  float mx = -3.4e38f;
#pragma unroll
  for(int mt=0;mt<2;mt++)
#pragma unroll
    for(int r=0;r<4;r++){
      float s = sv[mt][r]*0.125f;
      sv[mt][r] = s;
      impr[mt*16 + fq*4 + r] = s;
      mx = fmaxf(mx, s);
    }
  mx = fmaxf(mx, __shfl_xor(mx,16,64));
  mx = fmaxf(mx, __shfl_xor(mx,32,64));
  unsigned short* Pw = Pl + wave*16*40;
  float es = 0.f;
#pragma unroll
  for(int mt=0;mt<2;mt++)
#pragma unroll
    for(int r=0;r<4;r++){
      float p = __expf(sv[mt][r] - mx);
      es += p;
      Pw[fr*40 + mt*16 + fq*4 + r] = f2bf(p);
    }
  es += __shfl_xor(es,16,64);
  es += __shfl_xor(es,32,64);

  s8v ap = *(const s8v*)&Pw[fr*40 + fq*8];
  f4v acc[4] = {};
#pragma unroll
  for(int nt=0;nt<4;nt++){
    s8v bv = *(const s8v*)(vcth + ((size_t)h*64 + nt*16 + fr)*32 + fq*8);
    acc[nt] = __builtin_amdgcn_mfma_f32_16x16x32_bf16(ap, bv, acc[nt], 0,0,0);
  }
  float lv[4];
#pragma unroll
  for(int r=0;r<4;r++) lv[r] = __shfl(es, fq*4+r, 64);
#pragma unroll
  for(int nt=0;nt<4;nt++)
#pragma unroll
    for(int r=0;r<4;r++){
      int tq = i*64 + wave*16 + fq*4 + r;
      comp[((size_t)h*TT + tq)*HD + nt*16 + fr] = acc[nt][r]/lv[r];
    }
}

// ---------------- block scores -> entropy -> dynamic_k -> top-k mask ----------------
__global__ __launch_bounds__(256) void block_stats(
    const float* __restrict__ imp, const float* __restrict__ ksc, const float* __restrict__ kbi,
    unsigned* __restrict__ maskb, float* __restrict__ dkf,
    float* __restrict__ out_kratio, float* __restrict__ out_nent)
{
  int hb = blockIdx.x; int h = hb>>5, i = hb&31;
  int tid = threadIdx.x; int j = tid&31, p = tid>>5;
  const float* base = imp + ((size_t)h*TT + i*64)*NB;
  float s = 0.f;
  for(int t2=p*8; t2<p*8+8; t2++) s += base[(size_t)t2*NB + j];
  __shared__ float red[8][32];
  red[p][j] = s;
  __syncthreads();
  if(tid < 32){
    float bs = 0.f;
#pragma unroll
    for(int pp=0; pp<8; pp++) bs += red[pp][j];
    bs *= (1.f/64.f);
    float m = rmax32(bs);
    float e = expf(bs - m);
    float se = rsum32(e);
    float prob = e/se;
    float ent = rsum32(-prob * logf(prob + 1e-9f));
    float nent = ent / (3.4657359027997265f + 1e-9f);
    float kl = ksc[h]*nent + kbi[h];
    float kr = 1.f/(1.f + expf(-kl));
    float dkfl = fminf(fmaxf(8.f*kr, 1.f), 8.f);
    int dk = (int)dkfl;
    unsigned sel = 0u;
    for(int r=0;r<dk;r++){
      bool unpicked = ((sel>>j)&1u)==0u;
      float cand = unpicked ? bs : -3.4e38f;
      float mx = rmax32(cand);
      unsigned long long b = __ballot(cand == mx);
      int idxsel = __ffsll(b & 0xffffffffull) - 1;
      sel |= (1u<<idxsel);
    }
    sel |= (1u<<i);
    if(j==0){
      maskb[hb] = sel;
      dkf[hb] = (float)dk;
      out_kratio[hb] = kr;
      out_nent[hb] = nent;
    }
  }
}

// ---------------- avg_k reduction ----------------
__global__ __launch_bounds__(256) void avgk_kernel(const float* __restrict__ dkf, float* __restrict__ outp){
  __shared__ float red[256];
  int tid=threadIdx.x;
  red[tid] = dkf[tid] + dkf[tid+256];
  __syncthreads();
  for(int s=128;s>0;s>>=1){ if(tid<s) red[tid]+=red[tid+s]; __syncthreads(); }
  if(tid==0) outp[0] = red[0] * (1.f/512.f);
}

// ---------------- fused sliding-window + fine attention + gated combine ----------------
__global__ __launch_bounds__(256) void attn_fused(
    const unsigned short* __restrict__ qbh, const unsigned short* __restrict__ kbh,
    const unsigned short* __restrict__ vth, const unsigned* __restrict__ maskb,
    const float* __restrict__ comp, const float* __restrict__ gatep,
    unsigned short* __restrict__ mergedh)
{
  __shared__ unsigned short Kb[64*72];
  __shared__ unsigned short Vt[64*72];
  __shared__ unsigned short Pf[4*16*72];
  __shared__ unsigned short Ps[4*16*72];
  int tid = threadIdx.x;
  int wave = __builtin_amdgcn_readfirstlane(tid>>6);
  int ln = tid & 63;
  int fr = ln & 15, fq = ln >> 4;
  int hb = blockIdx.x; int h = hb>>5, i = hb&31;
  unsigned mb_s = (1u<<i) | (i ? (1u<<(i-1)) : 0u);
  unsigned mb_f = maskb[hb];
  unsigned mb = mb_s | mb_f;

  const unsigned short* qrow = qbh + ((size_t)h*TT + i*64 + wave*16 + fr)*HD + fq*8;
  s8v bq0 = *(const s8v*)(qrow);
  s8v bq1 = *(const s8v*)(qrow + 32);

  f4v acc_f[4] = {}, acc_s[4] = {};
  float mf = -3.4e38f, lf = 0.f, ms = -3.4e38f, ls = 0.f;

  int srow = tid>>2, sg = (tid&3)*16;
  unsigned short* Pfw = Pf + wave*16*72;
  unsigned short* Psw = Ps + wave*16*72;
  int qpos = wave*16 + fr;

  for(int j=0;j<NB;j++){
    if(!((mb>>j)&1u)) continue;
    __syncthreads();
    {
      const unsigned short* ks_ = kbh + ((size_t)h*TT + j*64 + srow)*HD + sg;
      *(s8v*)&Kb[srow*72 + sg]     = *(const s8v*)(ks_);
      *(s8v*)&Kb[srow*72 + sg + 8] = *(const s8v*)(ks_ + 8);
      const unsigned short* vs_ = vth + ((size_t)h*HD + srow)*TT + j*64 + sg;
      *(s8v*)&Vt[srow*72 + sg]     = *(const s8v*)(vs_);
      *(s8v*)&Vt[srow*72 + sg + 8] = *(const s8v*)(vs_ + 8);
    }
    __syncthreads();

    f4v sv[4] = {};
#pragma unroll
    for(int mt=0;mt<4;mt++){
      s8v ak0 = *(const s8v*)&Kb[(mt*16+fr)*72 + fq*8];
      s8v ak1 = *(const s8v*)&Kb[(mt*16+fr)*72 + fq*8 + 32];
      sv[mt] = __builtin_amdgcn_mfma_f32_16x16x32_bf16(ak0, bq0, sv[mt], 0,0,0);
      sv[mt] = __builtin_amdgcn_mfma_f32_16x16x32_bf16(ak1, bq1, sv[mt], 0,0,0);
    }
#pragma unroll
    for(int mt=0;mt<4;mt++)
#pragma unroll
      for(int r=0;r<4;r++) sv[mt][r] *= 0.125f;

    bool in_f = ((mb_f>>j)&1u) != 0u;
    bool in_s = (j==i) || (j+1==i);

    if(in_f){
      float mx = -3.4e38f;
#pragma unroll
      for(int mt=0;mt<4;mt++)
#pragma unroll
        for(int r=0;r<4;r++) mx = fmaxf(mx, sv[mt][r]);
      mx = fmaxf(mx, __shfl_xor(mx,16,64));
      mx = fmaxf(mx, __shfl_xor(mx,32,64));
      float mnew = fmaxf(mf, mx);
      float es = 0.f;
#pragma unroll
      for(int mt=0;mt<4;mt++)
#pragma unroll
        for(int r=0;r<4;r++){
          float p = __expf(sv[mt][r] - mnew);
          es += p;
          Pfw[fr*72 + mt*16 + fq*4 + r] = f2bf(p);
        }
      es += __shfl_xor(es,16,64);
      es += __shfl_xor(es,32,64);
      float alpha = __expf(mf - mnew);
      lf = lf*alpha + es;
      mf = mnew;
      float av[4];
#pragma unroll
      for(int r=0;r<4;r++) av[r] = __shfl(alpha, fq*4+r, 64);
#pragma unroll
      for(int nt=0;nt<4;nt++)
#pragma unroll
        for(int r=0;r<4;r++) acc_f[nt][r] *= av[r];
    }
    if(in_s){
      if(j==i){
#pragma unroll
        for(int mt=0;mt<4;mt++)
#pragma unroll
          for(int r=0;r<4;r++)
            if((mt*16 + fq*4 + r) > qpos) sv[mt][r] = -3.4e38f;
      }
      float mx = -3.4e38f;
#pragma unroll
      for(int mt=0;mt<4;mt++)
#pragma unroll
        for(int r=0;r<4;r++) mx = fmaxf(mx, sv[mt][r]);
      mx = fmaxf(mx, __shfl_xor(mx,16,64));
      mx = fmaxf(mx, __shfl_xor(mx,32,64));
      float mnew = fmaxf(ms, mx);
      float es = 0.f;
#pragma unroll
      for(int mt=0;mt<4;mt++)
#pragma unroll
        for(int r=0;r<4;r++){
          float p = __expf(sv[mt][r] - mnew);
          es += p;
          Psw[fr*72 + mt*16 + fq*4 + r] = f2bf(p);
        }
      es += __shfl_xor(es,16,64);
      es += __shfl_xor(es,32,64);
      float alpha = __expf(ms - mnew);
      ls = ls*alpha + es;
      ms = mnew;
      float av[4];
#pragma unroll
      for(int r=0;r<4;r++) av[r] = __shfl(alpha, fq*4+r, 64);
#pragma unroll
      for(int nt=0;nt<4;nt++)
#pragma unroll
        for(int r=0;r<4;r++) acc_s[nt][r] *= av[r];
    }

    if(in_f){
      s8v ap0 = *(const s8v*)&Pfw[fr*72 + fq*8];
      s8v ap1 = *(const s8v*)&Pfw[fr*72 + fq*8 + 32];
#pragma unroll
      for(int nt=0;nt<4;nt++){
        s8v bv0 = *(const s8v*)&Vt[(nt*16+fr)*72 + fq*8];
        s8v bv1 = *(const s8v*)&Vt[(nt*16+fr)*72 + fq*8 + 32];
        acc_f[nt] = __builtin_amdgcn_mfma_f32_16x16x32_bf16(ap0, bv0, acc_f[nt], 0,0,0);
        acc_f[nt] = __builtin_amdgcn_mfma_f32_16x16x32_bf16(ap1, bv1, acc_f[nt], 0,0,0);
      }
    }
    if(in_s){
      s8v ap0 = *(const s8v*)&Psw[fr*72 + fq*8];
      s8v ap1 = *(const s8v*)&Psw[fr*72 + fq*8 + 32];
#pragma unroll
      for(int nt=0;nt<4;nt++){
        s8v bv0 = *(const s8v*)&Vt[(nt*16+fr)*72 + fq*8];
        s8v bv1 = *(const s8v*)&Vt[(nt*16+fr)*72 + fq*8 + 32];
        acc_s[nt] = __builtin_amdgcn_mfma_f32_16x16x32_bf16(ap0, bv0, acc_s[nt], 0,0,0);
        acc_s[nt] = __builtin_amdgcn_mfma_f32_16x16x32_bf16(ap1, bv1, acc_s[nt], 0,0,0);
      }
    }
  }

  float lvf[4], lvs[4], g0[4], g1[4], g2[4];
#pragma unroll
  for(int r=0;r<4;r++){
    lvf[r] = __shfl(lf, fq*4+r, 64);
    lvs[r] = __shfl(ls, fq*4+r, 64);
    int t = i*64 + wave*16 + fq*4 + r;
    const float* g = gatep + (size_t)t*48 + h*3;
    g0[r] = g[0]; g1[r] = g[1]; g2[r] = g[2];
  }
#pragma unroll
  for(int nt=0;nt<4;nt++){
#pragma unroll
    for(int r=0;r<4;r++){
      int t = i*64 + wave*16 + fq*4 + r;
      int d = nt*16 + fr;
      float of = acc_f[nt][r] / lvf[r];
      float os = acc_s[nt][r] / lvs[r];
      float cp = comp[((size_t)h*TT + t)*HD + d];
      mergedh[(size_t)t*1024 + h*64 + d] = f2bf(g0[r]*os + g1[r]*cp + g2[r]*of);
    }
  }
}

// ---------------- output projection MFMA GEMM: 128x64 tiles, grid(16,16) ----------------
__global__ __launch_bounds__(256) void mfma_proj_k(
    const unsigned short* __restrict__ ahg, const unsigned short* __restrict__ bhg,
    float* __restrict__ C)
{
  __shared__ unsigned short SA[128*LROW], SB[64*LROW];
  int tid = threadIdx.x;
  int bn = blockIdx.x*64, bm = blockIdx.y*128;
  int aRow = tid>>1, aOff = (tid&1)*16;
  int bRow = tid>>2, bOff = (tid&3)*8;
  const unsigned short* gA = ahg + (size_t)(bm+aRow)*HIDDEN + aOff;
  const unsigned short* gB = bhg + (size_t)(bn+bRow)*HIDDEN + bOff;
  int wlA = aRow*LROW + aOff;
  int wlB = bRow*LROW + bOff;
  int wv = tid>>6, ln = tid&63;
  int wm = (wv&1)*64, wn = (wv>>1)*32;
  int fr = ln&15, fq = ln>>4;
  f4v acc[4][2] = {};
  for(int k0=0;k0<HIDDEN;k0+=32){
    s8v a0 = *(const s8v*)(gA + k0);
    s8v a1 = *(const s8v*)(gA + k0 + 8);
    s8v b0 = *(const s8v*)(gB + k0);
    __syncthreads();
    *(s8v*)&SA[wlA] = a0; *(s8v*)&SA[wlA+8] = a1;
    *(s8v*)&SB[wlB] = b0;
    __syncthreads();
    s8v af[4], bf[2];
#pragma unroll
    for(int i=0;i<4;i++) af[i] = *(const s8v*)&SA[(wm+i*16+fr)*LROW + fq*8];
#pragma unroll
    for(int j=0;j<2;j++) bf[j] = *(const s8v*)&SB[(wn+j*16+fr)*LROW + fq*8];
#pragma unroll
    for(int i=0;i<4;i++)
#pragma unroll
      for(int j=0;j<2;j++)
        acc[i][j] = __builtin_amdgcn_mfma_f32_16x16x32_bf16(af[i], bf[j], acc[i][j], 0,0,0);
  }
#pragma unroll
  for(int i=0;i<4;i++){
    int mb = bm + wm + i*16 + fq*4;
#pragma unroll
    for(int j=0;j<2;j++){
      int n = bn + wn + j*16 + fr;
      float* dst = C + (size_t)mb*HIDDEN + n;
#pragma unroll
      for(int r=0;r<4;r++) dst[(size_t)r*HIDDEN] = acc[i][j][r];
    }
  }
}

extern "C" void kernel_launch(void* const* d_in, const int* in_sizes, int n_in,
                              void* d_out, int out_size, void* d_ws, size_t ws_size,
                              hipStream_t stream) {
  (void)in_sizes; (void)n_in; (void)out_size; (void)ws_size;
  const float* hs  = (const float*)d_in[0];
  const float* Wq  = (const float*)d_in[1];
  const float* Wk  = (const float*)d_in[2];
  const float* Wv  = (const float*)d_in[3];
  const float* Wo  = (const float*)d_in[4];
  const float* Wc  = (const float*)d_in[5];
  const float* bcp = (const float*)d_in[6];
  const float* ksc = (const float*)d_in[7];
  const float* kbi = (const float*)d_in[8];
  const float* Wg  = (const float*)d_in[9];
  const float* bg  = (const float*)d_in[10];
  float* out = (float*)d_out;

  float* ws = (float*)d_ws;
  float* gatep  = ws;                         // 98304
  unsigned short* kch  = (unsigned short*)(gatep + 98304);   // 32768 shorts
  unsigned short* kcl  = kch + 32768;
  unsigned short* vcth = kcl + 32768;
  float* imp    = gatep + 98304 + 65536;      // 1048576
  float* comp   = imp + 1048576;              // 2097152 (hsh/hsl alias)
  float* wthf   = comp + 2097152;             // 1572864 (wth region)
  float* wtlf   = wthf + 1572864;             // 1572864 (wtl region)
  unsigned short* mergedh = (unsigned short*)(wtlf + 1572864);  // 1048576 floats
  float* dkf    = wtlf + 1572864 + 1048576;   // 512
  unsigned* maskb = (unsigned*)(dkf + 512);   // 512
  unsigned short* woth = (unsigned short*)(dkf + 1024);         // 524288 floats
  unsigned short* qbh  = (unsigned short*)(dkf + 1024 + 524288);// 1048576 f each:
  unsigned short* qbl  = qbh + 2097152;
  unsigned short* kbh  = qbl + 2097152;
  unsigned short* kbl  = kbh + 2097152;
  unsigned short* vbh  = kbl + 2097152;
  unsigned short* vth  = vbh + 2097152;
  unsigned short* wcth = vth + 2097152;                         // 131072 f
  unsigned short* wctl = wcth + 262144;                         // 131072 f
  float* ccpart = (float*)(wctl + 262144);                      // 524288 f

  unsigned short* hsh = (unsigned short*)comp;
  unsigned short* hsl = (unsigned short*)(comp + 1048576);
  unsigned short* wth = (unsigned short*)wthf;
  unsigned short* wtl = (unsigned short*)wtlf;

  float* out_avgk   = out + 2097152;
  float* out_kratio = out + 2097153;
  float* out_nent   = out + 2097665;

  prep_all<<<dim3(5184), 256, 0, stream>>>(hs, Wq, Wk, Wv, Wo, Wc, Wg, bg,
                                           hsh, hsl, wth, wtl, woth, wcth, wctl, gatep);
  mfma_qkv_k<<<dim3(48,16), 256, 0, stream>>>(hsh, hsl, wth, wtl,
                                              qbh, qbl, kbh, kbl, vbh);
  conv_vt<<<dim3(32,16), 256, 0, stream>>>(vbh, vth);
  mfma_compress_k<<<dim3(8,16), 256, 0, stream>>>(kbh, kbl, vbh, wcth, wctl, ccpart);
  compress_fin<<<dim3(256), 256, 0, stream>>>(ccpart, bcp, kch, kcl, vcth);
  comp_attn_mfma<<<dim3(32,16), 256, 0, stream>>>(qbh, qbl, kch, kcl, vcth, imp, comp);
  block_stats<<<dim3(512), 256, 0, stream>>>(imp, ksc, kbi, maskb, dkf, out_kratio, out_nent);
  avgk_kernel<<<dim3(1), 256, 0, stream>>>(dkf, out_avgk);
  attn_fused<<<dim3(512), 256, 0, stream>>>(qbh, kbh, vth, maskb, comp, gatep, mergedh);
  mfma_proj_k<<<dim3(16,16), 256, 0, stream>>>(mergedh, woth, out);
}

// Round 7
// 219.411 us; speedup vs baseline: 3.0842x; 1.0194x over previous
//
#include <hip/hip_runtime.h>
#include <math.h>

#define TT 2048
#define NH 16
#define HD 64
#define NB 32
#define HIDDEN 1024

typedef short s8v __attribute__((ext_vector_type(8)));
typedef float f4v __attribute__((ext_vector_type(4)));

// ---------------- bf16 helpers (header-independent, RNE) ----------------
__device__ __forceinline__ unsigned short f2bf(float x){
  unsigned u = __float_as_uint(x);
  unsigned r = (u + 0x7fffu + ((u>>16)&1u)) >> 16;
  return (unsigned short)r;
}
__device__ __forceinline__ float bf2f(unsigned short b){
  return __uint_as_float(((unsigned)b)<<16);
}
__device__ __forceinline__ void bsplit(float x, unsigned short& h, unsigned short& l){
  h = f2bf(x);
  l = f2bf(x - bf2f(h));
}

// ---------------- wave reductions ----------------
__device__ __forceinline__ float rmax32(float v){
#pragma unroll
  for(int o=16;o>0;o>>=1) v = fmaxf(v, __shfl_xor(v,o,32));
  return v;
}
__device__ __forceinline__ float rsum32(float v){
#pragma unroll
  for(int o=16;o>0;o>>=1) v += __shfl_xor(v,o,32);
  return v;
}

// ---------------- fused prep: split hs + transpose/split W* + Wc + gate + zero avgk ----------------
__global__ __launch_bounds__(256) void prep_all(
    const float* __restrict__ hs,
    const float* __restrict__ Wq, const float* __restrict__ Wk,
    const float* __restrict__ Wv, const float* __restrict__ Wo,
    const float* __restrict__ Wc,
    const float* __restrict__ Wg, const float* __restrict__ bg,
    unsigned short* __restrict__ hh, unsigned short* __restrict__ hl,
    unsigned short* __restrict__ wth, unsigned short* __restrict__ wtl,
    unsigned short* __restrict__ woth,
    unsigned short* __restrict__ wcth, unsigned short* __restrict__ wctl,
    float* __restrict__ gatep, float* __restrict__ out_avgk)
{
  __shared__ float SL[64*68];
  int bx = blockIdx.x;
  int t = threadIdx.x;
  if(bx==0 && t==0) out_avgk[0] = 0.f;
  if(bx < 2048){
    int i = (bx*256 + t)*4;
    float4 x = *(const float4*)(hs + i);
    ushort4 hv, lv;
    bsplit(x.x, hv.x, lv.x); bsplit(x.y, hv.y, lv.y);
    bsplit(x.z, hv.z, lv.z); bsplit(x.w, hv.w, lv.w);
    *(ushort4*)(hh + i) = hv;
    *(ushort4*)(hl + i) = lv;
    return;
  }
  if(bx < 3072){
    float (*L)[68] = (float(*)[68])SL;
    int idx = bx - 2048;
    int z = idx>>8, ky = (idx>>4)&15, nx = idx&15;
    const float* W = (z==0)?Wq:((z==1)?Wk:((z==2)?Wv:Wo));
    int k0 = ky*64, n0 = nx*64;
    int rr = t>>2, cg = t&3;
    const float* src = W + (size_t)(k0+rr)*1024 + n0 + cg*16;
    float4 a = *(const float4*)(src);
    float4 b = *(const float4*)(src+4);
    float4 c = *(const float4*)(src+8);
    float4 d = *(const float4*)(src+12);
    *(float4*)&L[rr][cg*16+0]  = a;
    *(float4*)&L[rr][cg*16+4]  = b;
    *(float4*)&L[rr][cg*16+8]  = c;
    *(float4*)&L[rr][cg*16+12] = d;
    __syncthreads();
    int nr = t>>2, kg = t&3;
    unsigned short hb[16], lb[16];
#pragma unroll
    for(int j=0;j<16;j++){
      float v = L[kg*16+j][nr];
      bsplit(v, hb[j], lb[j]);
    }
    if(z<3){
      size_t orow = ((size_t)z*1024 + n0 + nr)*1024 + k0 + kg*16;
      *(ushort4*)(wth+orow+0)  = make_ushort4(hb[0],hb[1],hb[2],hb[3]);
      *(ushort4*)(wth+orow+4)  = make_ushort4(hb[4],hb[5],hb[6],hb[7]);
      *(ushort4*)(wth+orow+8)  = make_ushort4(hb[8],hb[9],hb[10],hb[11]);
      *(ushort4*)(wth+orow+12) = make_ushort4(hb[12],hb[13],hb[14],hb[15]);
      *(ushort4*)(wtl+orow+0)  = make_ushort4(lb[0],lb[1],lb[2],lb[3]);
      *(ushort4*)(wtl+orow+4)  = make_ushort4(lb[4],lb[5],lb[6],lb[7]);
      *(ushort4*)(wtl+orow+8)  = make_ushort4(lb[8],lb[9],lb[10],lb[11]);
      *(ushort4*)(wtl+orow+12) = make_ushort4(lb[12],lb[13],lb[14],lb[15]);
    }else{
      size_t orow = ((size_t)n0 + nr)*1024 + k0 + kg*16;
      *(ushort4*)(woth+orow+0)  = make_ushort4(hb[0],hb[1],hb[2],hb[3]);
      *(ushort4*)(woth+orow+4)  = make_ushort4(hb[4],hb[5],hb[6],hb[7]);
      *(ushort4*)(woth+orow+8)  = make_ushort4(hb[8],hb[9],hb[10],hb[11]);
      *(ushort4*)(woth+orow+12) = make_ushort4(hb[12],hb[13],hb[14],hb[15]);
    }
    return;
  }
  if(bx < 3136){
    float (*L)[68] = (float(*)[68])SL;
    int k0 = (bx - 3072)*64;
    int rr = t>>2, cg = t&3;
    const float* src = Wc + (size_t)(k0+rr)*64 + cg*16;
    float4 a = *(const float4*)(src);
    float4 b = *(const float4*)(src+4);
    float4 c = *(const float4*)(src+8);
    float4 d = *(const float4*)(src+12);
    *(float4*)&L[rr][cg*16+0]  = a;
    *(float4*)&L[rr][cg*16+4]  = b;
    *(float4*)&L[rr][cg*16+8]  = c;
    *(float4*)&L[rr][cg*16+12] = d;
    __syncthreads();
    int nr = t>>2, kg = t&3;
    unsigned short hb[16], lb[16];
#pragma unroll
    for(int j=0;j<16;j++){
      float v = L[kg*16+j][nr];
      bsplit(v, hb[j], lb[j]);
    }
    size_t orow = (size_t)nr*4096 + k0 + kg*16;
    *(ushort4*)(wcth+orow+0)  = make_ushort4(hb[0],hb[1],hb[2],hb[3]);
    *(ushort4*)(wcth+orow+4)  = make_ushort4(hb[4],hb[5],hb[6],hb[7]);
    *(ushort4*)(wcth+orow+8)  = make_ushort4(hb[8],hb[9],hb[10],hb[11]);
    *(ushort4*)(wcth+orow+12) = make_ushort4(hb[12],hb[13],hb[14],hb[15]);
    *(ushort4*)(wctl+orow+0)  = make_ushort4(lb[0],lb[1],lb[2],lb[3]);
    *(ushort4*)(wctl+orow+4)  = make_ushort4(lb[4],lb[5],lb[6],lb[7]);
    *(ushort4*)(wctl+orow+8)  = make_ushort4(lb[8],lb[9],lb[10],lb[11]);
    *(ushort4*)(wctl+orow+12) = make_ushort4(lb[12],lb[13],lb[14],lb[15]);
    return;
  }
  {
    // gate: sigmoid(hs @ Wg + bg) for one t-row
    float* row = SL;
    float (*red)[64] = (float(*)[64])(SL + 1024);
    int tr = bx - 3136;
    *(float4*)(row + t*4) = *(const float4*)(hs + (size_t)tr*HIDDEN + t*4);
    __syncthreads();
    int n = t & 63, part = t>>6;
    float s = 0.f;
    if(n < 48){
      const float* w = Wg + n;
      for(int kx = part*256; kx < part*256+256; kx++)
        s += row[kx]*w[(size_t)kx*48];
    }
    red[part][n] = s;
    __syncthreads();
    if(part==0 && n<48){
      float x = red[0][n]+red[1][n]+red[2][n]+red[3][n] + bg[n];
      gatep[(size_t)tr*48 + n] = 1.f/(1.f+expf(-x));
    }
  }
}

// ---------------- QKV MFMA GEMM: 128x64 tiles, grid(48,16); conflict-free LDS; fused vth ----------------
// LROW=48 shorts (24 words): staging writes (sr=tid>>2, 8-short groups) and fragment reads
// both spread to exactly 8 words/bank -> conflict-free. Cs epilogue stride 72 (2-way = free).
#define LROW 48
__global__ __launch_bounds__(256) void mfma_qkv_k(
    const unsigned short* __restrict__ ahg, const unsigned short* __restrict__ alg,
    const unsigned short* __restrict__ bhg, const unsigned short* __restrict__ blg,
    unsigned short* __restrict__ qbh, unsigned short* __restrict__ qbl,
    unsigned short* __restrict__ kbh, unsigned short* __restrict__ kbl,
    unsigned short* __restrict__ vbh, unsigned short* __restrict__ vth)
{
  __shared__ unsigned short SH[18432];  // SA 6144 | SAl 6144 | SB 3072 | SBl 3072
  unsigned short* SA  = SH;
  unsigned short* SAl = SH + 6144;
  unsigned short* SB  = SH + 12288;
  unsigned short* SBl = SH + 15360;
  int tid = threadIdx.x;
  int bn = blockIdx.x*64, bm = blockIdx.y*128;
  bool tp = (blockIdx.x < 32);       // Q,K columns: 3-pass split
  int sr = tid>>2, skg = (tid&3)*8;
  const unsigned short* gA  = ahg + (size_t)(bm+sr)*HIDDEN + skg;
  const unsigned short* gAl = alg + (size_t)(bm+sr)*HIDDEN + skg;
  const unsigned short* gB  = bhg + (size_t)(bn+sr)*HIDDEN + skg;
  const unsigned short* gBl = blg + (size_t)(bn+sr)*HIDDEN + skg;
  int wlds = sr*LROW + skg;
  int wv = tid>>6, ln = tid&63;
  int wm = (wv&1)*64, wn = (wv>>1)*32;
  int fr = ln&15, fq = ln>>4;
  f4v acc[4][2] = {};
  for(int k0=0;k0<HIDDEN;k0+=32){
    s8v a0 = *(const s8v*)(gA + k0);
    s8v a1 = *(const s8v*)(gA + 65536 + k0);     // +64 rows
    s8v b0 = *(const s8v*)(gB + k0);
    s8v a0l, a1l, b0l;
    if(tp){
      a0l = *(const s8v*)(gAl + k0);
      a1l = *(const s8v*)(gAl + 65536 + k0);
      b0l = *(const s8v*)(gBl + k0);
    }
    __syncthreads();
    *(s8v*)&SA[wlds] = a0; *(s8v*)&SA[wlds + 64*LROW] = a1;
    *(s8v*)&SB[wlds] = b0;
    if(tp){
      *(s8v*)&SAl[wlds] = a0l; *(s8v*)&SAl[wlds + 64*LROW] = a1l;
      *(s8v*)&SBl[wlds] = b0l;
    }
    __syncthreads();
    s8v af[4], bf[2], tf;
#pragma unroll
    for(int i=0;i<4;i++) af[i] = *(const s8v*)&SA[(wm+i*16+fr)*LROW + fq*8];
#pragma unroll
    for(int j=0;j<2;j++) bf[j] = *(const s8v*)&SB[(wn+j*16+fr)*LROW + fq*8];
#pragma unroll
    for(int i=0;i<4;i++)
#pragma unroll
      for(int j=0;j<2;j++)
        acc[i][j] = __builtin_amdgcn_mfma_f32_16x16x32_bf16(af[i], bf[j], acc[i][j], 0,0,0);
    if(tp){
#pragma unroll
      for(int i=0;i<4;i++){
        tf = *(const s8v*)&SAl[(wm+i*16+fr)*LROW + fq*8];
#pragma unroll
        for(int j=0;j<2;j++)
          acc[i][j] = __builtin_amdgcn_mfma_f32_16x16x32_bf16(tf, bf[j], acc[i][j], 0,0,0);
      }
#pragma unroll
      for(int j=0;j<2;j++){
        tf = *(const s8v*)&SBl[(wn+j*16+fr)*LROW + fq*8];
#pragma unroll
        for(int i=0;i<4;i++)
          acc[i][j] = __builtin_amdgcn_mfma_f32_16x16x32_bf16(af[i], tf, acc[i][j], 0,0,0);
      }
    }
  }
  // epilogue: LDS-stage bf16 [t_loc][d] (stride 72) then coalesced 16B stores
  int z = bn >> 10;
  int head = (bn & 1023) >> 6;
  unsigned short* Cs = SH;          // 128*72 = 9216 shorts
  unsigned short* dsth = (z==0)?qbh:((z==1)?kbh:vbh);
  size_t obase = ((size_t)head*TT + bm)*HD;
  __syncthreads();
#pragma unroll
  for(int i=0;i<4;i++)
#pragma unroll
    for(int j=0;j<2;j++)
#pragma unroll
      for(int r=0;r<4;r++)
        Cs[(wm+i*16+fq*4+r)*72 + wn+j*16+fr] = f2bf(acc[i][j][r]);
  __syncthreads();
#pragma unroll
  for(int u=0;u<4;u++){
    int c = u*256 + tid;            // row=c>>3, colgroup=c&7
    *(s8v*)(dsth + obase + c*8) = *(const s8v*)&Cs[(c>>3)*72 + (c&7)*8];
  }
  if(z<2){
    unsigned short* dstl = (z==0)?qbl:kbl;
    __syncthreads();
#pragma unroll
    for(int i=0;i<4;i++)
#pragma unroll
      for(int j=0;j<2;j++)
#pragma unroll
        for(int r=0;r<4;r++){
          float v = acc[i][j][r];
          Cs[(wm+i*16+fq*4+r)*72 + wn+j*16+fr] = f2bf(v - bf2f(f2bf(v)));
        }
    __syncthreads();
#pragma unroll
    for(int u=0;u<4;u++){
      int c = u*256 + tid;
      *(s8v*)(dstl + obase + c*8) = *(const s8v*)&Cs[(c>>3)*72 + (c&7)*8];
    }
  }else{
    // fused conv_vt: Cs still holds V hi tile [t_loc][d] -> write v^T [h][d][t]
    int d = tid>>2, tg = (tid&3)*32;
    s8v r0,r1,r2,r3;
#pragma unroll
    for(int u=0;u<8;u++){
      r0[u] = (short)Cs[(tg+u)*72 + d];
      r1[u] = (short)Cs[(tg+8+u)*72 + d];
      r2[u] = (short)Cs[(tg+16+u)*72 + d];
      r3[u] = (short)Cs[(tg+24+u)*72 + d];
    }
    unsigned short* dv = vth + ((size_t)head*HD + d)*TT + bm + tg;
    *(s8v*)(dv)    = r0;
    *(s8v*)(dv+8)  = r1;
    *(s8v*)(dv+16) = r2;
    *(s8v*)(dv+24) = r3;
  }
}

// ---------------- compress MFMA GEMM: [kblk;vblk](1024x4096) @ WcT, split-K ----------------
#define CROW 48
__global__ __launch_bounds__(256) void mfma_compress_k(
    const unsigned short* __restrict__ kbh, const unsigned short* __restrict__ kbl,
    const unsigned short* __restrict__ vbh,
    const unsigned short* __restrict__ wcth, const unsigned short* __restrict__ wctl,
    float* __restrict__ ccpart)
{
  __shared__ unsigned short As[64*CROW], Al[64*CROW], Bs[64*CROW], Bl[64*CROW];
  int chunk = blockIdx.x;
  int mt = blockIdx.y;
  bool isK = (mt < 8);
  const unsigned short* Ag  = isK ? (kbh + (size_t)mt*262144) : (vbh + (size_t)(mt-8)*262144);
  const unsigned short* Agl = kbl + (size_t)(isK ? mt : 0)*262144;
  int tid = threadIdx.x;
  int sr = tid>>2, skg = (tid&3)*8;
  int k0b = chunk*512;
  const unsigned short* gA  = Ag  + (size_t)sr*4096 + k0b + skg;
  const unsigned short* gAl = Agl + (size_t)sr*4096 + k0b + skg;
  const unsigned short* gB  = wcth + (size_t)sr*4096 + k0b + skg;
  const unsigned short* gBl = wctl + (size_t)sr*4096 + k0b + skg;
  int wv = tid>>6, ln = tid&63;
  int fr = ln&15, fq = ln>>4;
  int wlds = sr*CROW + skg;
  f4v acc[4] = {};
  for(int ks=0; ks<512; ks+=32){
    s8v a0 = *(const s8v*)(gA + ks);
    s8v b0 = *(const s8v*)(gB + ks);
    s8v b1 = *(const s8v*)(gBl + ks);
    s8v a1 = {};
    if(isK) a1 = *(const s8v*)(gAl + ks);
    __syncthreads();
    *(s8v*)&As[wlds] = a0;
    *(s8v*)&Bs[wlds] = b0;
    *(s8v*)&Bl[wlds] = b1;
    if(isK) *(s8v*)&Al[wlds] = a1;
    __syncthreads();
    s8v bfh = *(const s8v*)&Bs[(wv*16+fr)*CROW + fq*8];
    s8v bfl = *(const s8v*)&Bl[(wv*16+fr)*CROW + fq*8];
#pragma unroll
    for(int m=0;m<4;m++){
      s8v af = *(const s8v*)&As[(m*16+fr)*CROW + fq*8];
      acc[m] = __builtin_amdgcn_mfma_f32_16x16x32_bf16(af, bfh, acc[m], 0,0,0);
      acc[m] = __builtin_amdgcn_mfma_f32_16x16x32_bf16(af, bfl, acc[m], 0,0,0);
      if(isK){
        s8v afl = *(const s8v*)&Al[(m*16+fr)*CROW + fq*8];
        acc[m] = __builtin_amdgcn_mfma_f32_16x16x32_bf16(afl, bfh, acc[m], 0,0,0);
      }
    }
  }
  float* dst = ccpart + ((size_t)chunk*1024 + mt*64)*64;
#pragma unroll
  for(int m=0;m<4;m++)
#pragma unroll
    for(int r=0;r<4;r++)
      dst[(size_t)(m*16+fq*4+r)*64 + wv*16 + fr] = acc[m][r];
}

// ---------------- reduce partials + bias + gelu -> kc split bf16, vc^T bf16 ----------------
__global__ __launch_bounds__(256) void compress_fin(
    const float* __restrict__ ccpart, const float* __restrict__ bcp,
    unsigned short* __restrict__ kch, unsigned short* __restrict__ kcl,
    unsigned short* __restrict__ vcth)
{
  int idx = blockIdx.x*256 + threadIdx.x;   // 65536
  int row = idx>>6, col = idx&63;
  float s = 0.f;
#pragma unroll
  for(int c=0;c<8;c++) s += ccpart[(size_t)c*65536 + idx];
  s += bcp[col];
  float g = 0.5f*s*(1.f+erff(s*0.70710678118654752f));
  if(row < 512){
    unsigned short hi = f2bf(g);
    kch[idx] = hi;
    kcl[idx] = f2bf(g - bf2f(hi));
  }else{
    int r = row - 512;
    int h = r>>5, j = r&31;
    vcth[((size_t)h*64 + col)*32 + j] = f2bf(g);
  }
}

// ---------------- compressed attention + block stats + top-k + avg_k (fused) ----------------
__global__ __launch_bounds__(256) void comp_attn_mfma(
    const unsigned short* __restrict__ qbh, const unsigned short* __restrict__ qbl,
    const unsigned short* __restrict__ kch, const unsigned short* __restrict__ kcl,
    const unsigned short* __restrict__ vcth,
    const float* __restrict__ ksc, const float* __restrict__ kbi,
    float* __restrict__ comp, unsigned* __restrict__ maskb,
    float* __restrict__ out_avgk, float* __restrict__ out_kratio, float* __restrict__ out_nent)
{
  __shared__ unsigned short Pl[4*16*40];
  __shared__ float colsum[4][32];
  int tid = threadIdx.x;
  int wave = __builtin_amdgcn_readfirstlane(tid>>6);
  int ln = tid&63;
  int fr = ln&15, fq = ln>>4;
  int i = blockIdx.x, h = blockIdx.y;

  const unsigned short* qrh = qbh + ((size_t)h*TT + i*64 + wave*16 + fr)*HD + fq*8;
  const unsigned short* qrl = qbl + ((size_t)h*TT + i*64 + wave*16 + fr)*HD + fq*8;
  s8v bh0 = *(const s8v*)(qrh);
  s8v bh1 = *(const s8v*)(qrh + 32);
  s8v bl0 = *(const s8v*)(qrl);
  s8v bl1 = *(const s8v*)(qrl + 32);

  f4v sv[2] = {};
#pragma unroll
  for(int mt=0;mt<2;mt++){
    const unsigned short* ar = kch + ((size_t)h*32 + mt*16 + fr)*HD + fq*8;
    const unsigned short* al = kcl + ((size_t)h*32 + mt*16 + fr)*HD + fq*8;
    s8v ah0 = *(const s8v*)(ar);
    s8v ah1 = *(const s8v*)(ar + 32);
    s8v al0 = *(const s8v*)(al);
    s8v al1 = *(const s8v*)(al + 32);
    sv[mt] = __builtin_amdgcn_mfma_f32_16x16x32_bf16(ah0, bh0, sv[mt], 0,0,0);
    sv[mt] = __builtin_amdgcn_mfma_f32_16x16x32_bf16(ah1, bh1, sv[mt], 0,0,0);
    sv[mt] = __builtin_amdgcn_mfma_f32_16x16x32_bf16(al0, bh0, sv[mt], 0,0,0);
    sv[mt] = __builtin_amdgcn_mfma_f32_16x16x32_bf16(al1, bh1, sv[mt], 0,0,0);
    sv[mt] = __builtin_amdgcn_mfma_f32_16x16x32_bf16(ah0, bl0, sv[mt], 0,0,0);
    sv[mt] = __builtin_amdgcn_mfma_f32_16x16x32_bf16(ah1, bl1, sv[mt], 0,0,0);
  }
#pragma unroll
  for(int mt=0;mt<2;mt++)
#pragma unroll
    for(int r=0;r<4;r++) sv[mt][r] *= 0.125f;

  // ---- block-stats reduction: column sums over the 64 queries of this block ----
  float cs[8];
#pragma unroll
  for(int mt=0;mt<2;mt++)
#pragma unroll
    for(int r=0;r<4;r++) cs[mt*4+r] = sv[mt][r];
#pragma unroll
  for(int o=1;o<16;o<<=1)
#pragma unroll
    for(int u=0;u<8;u++) cs[u] += __shfl_xor(cs[u], o, 64);
  if(fr==0){
#pragma unroll
    for(int mt=0;mt<2;mt++)
#pragma unroll
      for(int r=0;r<4;r++) colsum[wave][mt*16 + fq*4 + r] = cs[mt*4+r];
  }
  __syncthreads();
  if(wave==0 && ln<32){
    int j = ln;
    float bs = (colsum[0][j]+colsum[1][j]+colsum[2][j]+colsum[3][j]) * (1.f/64.f);
    float m = rmax32(bs);
    float e = expf(bs - m);
    float se = rsum32(e);
    float prob = e/se;
    float ent = rsum32(-prob * logf(prob + 1e-9f));
    float nent = ent / (3.4657359027997265f + 1e-9f);   // log(32)
    float kl = ksc[h]*nent + kbi[h];
    float kr = 1.f/(1.f + expf(-kl));
    float dkfl = fminf(fmaxf(8.f*kr, 1.f), 8.f);
    int dk = (int)dkfl;
    unsigned sel = 0u;
    for(int r=0;r<dk;r++){
      bool unpicked = ((sel>>j)&1u)==0u;
      float cand = unpicked ? bs : -3.4e38f;
      float mx = rmax32(cand);
      unsigned long long b = __ballot(cand == mx);
      int idxsel = __ffsll(b & 0xffffffffull) - 1;
      sel |= (1u<<idxsel);
    }
    sel |= (1u<<i);
    if(j==0){
      int hb = h*32 + i;
      maskb[hb] = sel;
      out_kratio[hb] = kr;
      out_nent[hb] = nent;
      atomicAdd(out_avgk, (float)dk * (1.f/512.f));   // exact: multiples of 2^-9
    }
  }

  // ---- softmax + PV ----
  float mx = -3.4e38f;
#pragma unroll
  for(int mt=0;mt<2;mt++)
#pragma unroll
    for(int r=0;r<4;r++) mx = fmaxf(mx, sv[mt][r]);
  mx = fmaxf(mx, __shfl_xor(mx,16,64));
  mx = fmaxf(mx, __shfl_xor(mx,32,64));
  unsigned short* Pw = Pl + wave*16*40;
  float es = 0.f;
#pragma unroll
  for(int mt=0;mt<2;mt++)
#pragma unroll
    for(int r=0;r<4;r++){
      float p = __expf(sv[mt][r] - mx);
      es += p;
      Pw[fr*40 + mt*16 + fq*4 + r] = f2bf(p);
    }
  es += __shfl_xor(es,16,64);
  es += __shfl_xor(es,32,64);

  s8v ap = *(const s8v*)&Pw[fr*40 + fq*8];
  f4v acc[4] = {};
#pragma unroll
  for(int nt=0;nt<4;nt++){
    s8v bv = *(const s8v*)(vcth + ((size_t)h*64 + nt*16 + fr)*32 + fq*8);
    acc[nt] = __builtin_amdgcn_mfma_f32_16x16x32_bf16(ap, bv, acc[nt], 0,0,0);
  }
  float lv[4];
#pragma unroll
  for(int r=0;r<4;r++) lv[r] = __shfl(es, fq*4+r, 64);
#pragma unroll
  for(int nt=0;nt<4;nt++)
#pragma unroll
    for(int r=0;r<4;r++){
      int tq = i*64 + wave*16 + fq*4 + r;
      comp[((size_t)h*TT + tq)*HD + nt*16 + fr] = acc[nt][r]/lv[r];
    }
}

// ---------------- fused sliding-window + fine attention + gated combine ----------------
__global__ __launch_bounds__(256) void attn_fused(
    const unsigned short* __restrict__ qbh, const unsigned short* __restrict__ kbh,
    const unsigned short* __restrict__ vth, const unsigned* __restrict__ maskb,
    const float* __restrict__ comp, const float* __restrict__ gatep,
    unsigned short* __restrict__ mergedh)
{
  __shared__ unsigned short Kb[64*72];
  __shared__ unsigned short Vt[64*72];
  __shared__ unsigned short Pf[4*16*72];
  __shared__ unsigned short Ps[4*16*72];
  int tid = threadIdx.x;
  int wave = __builtin_amdgcn_readfirstlane(tid>>6);
  int ln = tid & 63;
  int fr = ln & 15, fq = ln >> 4;
  int hb = blockIdx.x; int h = hb>>5, i = hb&31;
  unsigned mb_s = (1u<<i) | (i ? (1u<<(i-1)) : 0u);
  unsigned mb_f = maskb[hb];
  unsigned mb = mb_s | mb_f;

  const unsigned short* qrow = qbh + ((size_t)h*TT + i*64 + wave*16 + fr)*HD + fq*8;
  s8v bq0 = *(const s8v*)(qrow);
  s8v bq1 = *(const s8v*)(qrow + 32);

  f4v acc_f[4] = {}, acc_s[4] = {};
  float mf = -3.4e38f, lf = 0.f, ms = -3.4e38f, ls = 0.f;

  int srow = tid>>2, sg = (tid&3)*16;
  unsigned short* Pfw = Pf + wave*16*72;
  unsigned short* Psw = Ps + wave*16*72;
  int qpos = wave*16 + fr;

  for(int j=0;j<NB;j++){
    if(!((mb>>j)&1u)) continue;
    __syncthreads();
    {
      const unsigned short* ks_ = kbh + ((size_t)h*TT + j*64 + srow)*HD + sg;
      *(s8v*)&Kb[srow*72 + sg]     = *(const s8v*)(ks_);
      *(s8v*)&Kb[srow*72 + sg + 8] = *(const s8v*)(ks_ + 8);
      const unsigned short* vs_ = vth + ((size_t)h*HD + srow)*TT + j*64 + sg;
      *(s8v*)&Vt[srow*72 + sg]     = *(const s8v*)(vs_);
      *(s8v*)&Vt[srow*72 + sg + 8] = *(const s8v*)(vs_ + 8);
    }
    __syncthreads();

    f4v sv[4] = {};
#pragma unroll
    for(int mt=0;mt<4;mt++){
      s8v ak0 = *(const s8v*)&Kb[(mt*16+fr)*72 + fq*8];
      s8v ak1 = *(const s8v*)&Kb[(mt*16+fr)*72 + fq*8 + 32];
      sv[mt] = __builtin_amdgcn_mfma_f32_16x16x32_bf16(ak0, bq0, sv[mt], 0,0,0);
      sv[mt] = __builtin_amdgcn_mfma_f32_16x16x32_bf16(ak1, bq1, sv[mt], 0,0,0);
    }
#pragma unroll
    for(int mt=0;mt<4;mt++)
#pragma unroll
      for(int r=0;r<4;r++) sv[mt][r] *= 0.125f;

    bool in_f = ((mb_f>>j)&1u) != 0u;
    bool in_s = (j==i) || (j+1==i);

    if(in_f){
      float mx = -3.4e38f;
#pragma unroll
      for(int mt=0;mt<4;mt++)
#pragma unroll
        for(int r=0;r<4;r++) mx = fmaxf(mx, sv[mt][r]);
      mx = fmaxf(mx, __shfl_xor(mx,16,64));
      mx = fmaxf(mx, __shfl_xor(mx,32,64));
      float mnew = fmaxf(mf, mx);
      float es = 0.f;
#pragma unroll
      for(int mt=0;mt<4;mt++)
#pragma unroll
        for(int r=0;r<4;r++){
          float p = __expf(sv[mt][r] - mnew);
          es += p;
          Pfw[fr*72 + mt*16 + fq*4 + r] = f2bf(p);
        }
      es += __shfl_xor(es,16,64);
      es += __shfl_xor(es,32,64);
      float alpha = __expf(mf - mnew);
      lf = lf*alpha + es;
      mf = mnew;
      float av[4];
#pragma unroll
      for(int r=0;r<4;r++) av[r] = __shfl(alpha, fq*4+r, 64);
#pragma unroll
      for(int nt=0;nt<4;nt++)
#pragma unroll
        for(int r=0;r<4;r++) acc_f[nt][r] *= av[r];
    }
    if(in_s){
      if(j==i){
#pragma unroll
        for(int mt=0;mt<4;mt++)
#pragma unroll
          for(int r=0;r<4;r++)
            if((mt*16 + fq*4 + r) > qpos) sv[mt][r] = -3.4e38f;
      }
      float mx = -3.4e38f;
#pragma unroll
      for(int mt=0;mt<4;mt++)
#pragma unroll
        for(int r=0;r<4;r++) mx = fmaxf(mx, sv[mt][r]);
      mx = fmaxf(mx, __shfl_xor(mx,16,64));
      mx = fmaxf(mx, __shfl_xor(mx,32,64));
      float mnew = fmaxf(ms, mx);
      float es = 0.f;
#pragma unroll
      for(int mt=0;mt<4;mt++)
#pragma unroll
        for(int r=0;r<4;r++){
          float p = __expf(sv[mt][r] - mnew);
          es += p;
          Psw[fr*72 + mt*16 + fq*4 + r] = f2bf(p);
        }
      es += __shfl_xor(es,16,64);
      es += __shfl_xor(es,32,64);
      float alpha = __expf(ms - mnew);
      ls = ls*alpha + es;
      ms = mnew;
      float av[4];
#pragma unroll
      for(int r=0;r<4;r++) av[r] = __shfl(alpha, fq*4+r, 64);
#pragma unroll
      for(int nt=0;nt<4;nt++)
#pragma unroll
        for(int r=0;r<4;r++) acc_s[nt][r] *= av[r];
    }

    if(in_f){
      s8v ap0 = *(const s8v*)&Pfw[fr*72 + fq*8];
      s8v ap1 = *(const s8v*)&Pfw[fr*72 + fq*8 + 32];
#pragma unroll
      for(int nt=0;nt<4;nt++){
        s8v bv0 = *(const s8v*)&Vt[(nt*16+fr)*72 + fq*8];
        s8v bv1 = *(const s8v*)&Vt[(nt*16+fr)*72 + fq*8 + 32];
        acc_f[nt] = __builtin_amdgcn_mfma_f32_16x16x32_bf16(ap0, bv0, acc_f[nt], 0,0,0);
        acc_f[nt] = __builtin_amdgcn_mfma_f32_16x16x32_bf16(ap1, bv1, acc_f[nt], 0,0,0);
      }
    }
    if(in_s){
      s8v ap0 = *(const s8v*)&Psw[fr*72 + fq*8];
      s8v ap1 = *(const s8v*)&Psw[fr*72 + fq*8 + 32];
#pragma unroll
      for(int nt=0;nt<4;nt++){
        s8v bv0 = *(const s8v*)&Vt[(nt*16+fr)*72 + fq*8];
        s8v bv1 = *(const s8v*)&Vt[(nt*16+fr)*72 + fq*8 + 32];
        acc_s[nt] = __builtin_amdgcn_mfma_f32_16x16x32_bf16(ap0, bv0, acc_s[nt], 0,0,0);
        acc_s[nt] = __builtin_amdgcn_mfma_f32_16x16x32_bf16(ap1, bv1, acc_s[nt], 0,0,0);
      }
    }
  }

  float lvf[4], lvs[4], g0[4], g1[4], g2[4];
#pragma unroll
  for(int r=0;r<4;r++){
    lvf[r] = __shfl(lf, fq*4+r, 64);
    lvs[r] = __shfl(ls, fq*4+r, 64);
    int t = i*64 + wave*16 + fq*4 + r;
    const float* g = gatep + (size_t)t*48 + h*3;
    g0[r] = g[0]; g1[r] = g[1]; g2[r] = g[2];
  }
#pragma unroll
  for(int nt=0;nt<4;nt++){
#pragma unroll
    for(int r=0;r<4;r++){
      int t = i*64 + wave*16 + fq*4 + r;
      int d = nt*16 + fr;
      float of = acc_f[nt][r] / lvf[r];
      float os = acc_s[nt][r] / lvs[r];
      float cp = comp[((size_t)h*TT + t)*HD + d];
      mergedh[(size_t)t*1024 + h*64 + d] = f2bf(g0[r]*os + g1[r]*cp + g2[r]*of);
    }
  }
}

// ---------------- output projection MFMA GEMM: 128x64 tiles, grid(16,16) ----------------
__global__ __launch_bounds__(256) void mfma_proj_k(
    const unsigned short* __restrict__ ahg, const unsigned short* __restrict__ bhg,
    float* __restrict__ C)
{
  __shared__ unsigned short SA[128*LROW], SB[64*LROW];
  int tid = threadIdx.x;
  int bn = blockIdx.x*64, bm = blockIdx.y*128;
  int sr = tid>>2, skg = (tid&3)*8;
  const unsigned short* gA = ahg + (size_t)(bm+sr)*HIDDEN + skg;
  const unsigned short* gB = bhg + (size_t)(bn+sr)*HIDDEN + skg;
  int wlds = sr*LROW + skg;
  int wv = tid>>6, ln = tid&63;
  int wm = (wv&1)*64, wn = (wv>>1)*32;
  int fr = ln&15, fq = ln>>4;
  f4v acc[4][2] = {};
  for(int k0=0;k0<HIDDEN;k0+=32){
    s8v a0 = *(const s8v*)(gA + k0);
    s8v a1 = *(const s8v*)(gA + 65536 + k0);
    s8v b0 = *(const s8v*)(gB + k0);
    __syncthreads();
    *(s8v*)&SA[wlds] = a0; *(s8v*)&SA[wlds + 64*LROW] = a1;
    *(s8v*)&SB[wlds] = b0;
    __syncthreads();
    s8v af[4], bf[2];
#pragma unroll
    for(int i=0;i<4;i++) af[i] = *(const s8v*)&SA[(wm+i*16+fr)*LROW + fq*8];
#pragma unroll
    for(int j=0;j<2;j++) bf[j] = *(const s8v*)&SB[(wn+j*16+fr)*LROW + fq*8];
#pragma unroll
    for(int i=0;i<4;i++)
#pragma unroll
      for(int j=0;j<2;j++)
        acc[i][j] = __builtin_amdgcn_mfma_f32_16x16x32_bf16(af[i], bf[j], acc[i][j], 0,0,0);
  }
#pragma unroll
  for(int i=0;i<4;i++){
    int mb = bm + wm + i*16 + fq*4;
#pragma unroll
    for(int j=0;j<2;j++){
      int n = bn + wn + j*16 + fr;
      float* dst = C + (size_t)mb*HIDDEN + n;
#pragma unroll
      for(int r=0;r<4;r++) dst[(size_t)r*HIDDEN] = acc[i][j][r];
    }
  }
}

extern "C" void kernel_launch(void* const* d_in, const int* in_sizes, int n_in,
                              void* d_out, int out_size, void* d_ws, size_t ws_size,
                              hipStream_t stream) {
  (void)in_sizes; (void)n_in; (void)out_size; (void)ws_size;
  const float* hs  = (const float*)d_in[0];
  const float* Wq  = (const float*)d_in[1];
  const float* Wk  = (const float*)d_in[2];
  const float* Wv  = (const float*)d_in[3];
  const float* Wo  = (const float*)d_in[4];
  const float* Wc  = (const float*)d_in[5];
  const float* bcp = (const float*)d_in[6];
  const float* ksc = (const float*)d_in[7];
  const float* kbi = (const float*)d_in[8];
  const float* Wg  = (const float*)d_in[9];
  const float* bg  = (const float*)d_in[10];
  float* out = (float*)d_out;

  float* ws = (float*)d_ws;
  float* gatep  = ws;                         // 98304
  unsigned short* kch  = (unsigned short*)(gatep + 98304);   // 32768 shorts
  unsigned short* kcl  = kch + 32768;
  unsigned short* vcth = kcl + 32768;
  float* comp   = gatep + 98304 + 65536;      // 2097152 (hsh/hsl alias)
  float* wthf   = comp + 2097152;             // 1572864 (wth region)
  float* wtlf   = wthf + 1572864;             // 1572864 (wtl region)
  unsigned short* mergedh = (unsigned short*)(wtlf + 1572864);  // 1048576 floats
  unsigned* maskb = (unsigned*)(wtlf + 1572864 + 1048576);      // 512
  unsigned short* woth = (unsigned short*)(wtlf + 1572864 + 1048576 + 512);   // 524288 f
  unsigned short* qbh  = woth + 1048576;      // each 2097152 shorts = 1048576 f:
  unsigned short* qbl  = qbh + 2097152;
  unsigned short* kbh  = qbl + 2097152;
  unsigned short* kbl  = kbh + 2097152;
  unsigned short* vbh  = kbl + 2097152;
  unsigned short* vth  = vbh + 2097152;
  unsigned short* wcth = vth + 2097152;       // 262144 shorts
  unsigned short* wctl = wcth + 262144;
  float* ccpart = (float*)(wctl + 262144);    // 524288 f

  unsigned short* hsh = (unsigned short*)comp;
  unsigned short* hsl = (unsigned short*)(comp + 1048576);
  unsigned short* wth = (unsigned short*)wthf;
  unsigned short* wtl = (unsigned short*)wtlf;

  float* out_avgk   = out + 2097152;
  float* out_kratio = out + 2097153;
  float* out_nent   = out + 2097665;

  prep_all<<<dim3(5184), 256, 0, stream>>>(hs, Wq, Wk, Wv, Wo, Wc, Wg, bg,
                                           hsh, hsl, wth, wtl, woth, wcth, wctl,
                                           gatep, out_avgk);
  mfma_qkv_k<<<dim3(48,16), 256, 0, stream>>>(hsh, hsl, wth, wtl,
                                              qbh, qbl, kbh, kbl, vbh, vth);
  mfma_compress_k<<<dim3(8,16), 256, 0, stream>>>(kbh, kbl, vbh, wcth, wctl, ccpart);
  compress_fin<<<dim3(256), 256, 0, stream>>>(ccpart, bcp, kch, kcl, vcth);
  comp_attn_mfma<<<dim3(32,16), 256, 0, stream>>>(qbh, qbl, kch, kcl, vcth,
                                                  ksc, kbi, comp, maskb,
                                                  out_avgk, out_kratio, out_nent);
  attn_fused<<<dim3(512), 256, 0, stream>>>(qbh, kbh, vth, maskb, comp, gatep, mergedh);
  mfma_proj_k<<<dim3(16,16), 256, 0, stream>>>(mergedh, woth, out);
}